// Round 5
// baseline (720.813 us; speedup 1.0000x reference)
//
#include <hip/hip_runtime.h>
#include <stdint.h>

#define HMAP   (1u << 19)
#define HMASK  (HMAP - 1u)

typedef short bf16x8 __attribute__((ext_vector_type(8)));
typedef float f32x4  __attribute__((ext_vector_type(4)));
typedef float f32x2  __attribute__((ext_vector_type(2)));
typedef unsigned u32x2 __attribute__((ext_vector_type(2)));

// resolutions: ceil(16 * 2^(7l/15)); dense (R^3 <= 2^19) for levels 0..4
__device__ __constant__ const int c_res[16] = {16, 23, 31, 43, 59, 81, 112, 154, 213, 295, 407, 562, 777, 1073, 1483, 2048};

__device__ __forceinline__ unsigned short f2bf(float f) {
    unsigned u = __float_as_uint(f);
    u += 0x7fffu + ((u >> 16) & 1u);           // round-to-nearest-even
    return (unsigned short)(u >> 16);
}

// Exactly matches where(100v>20, v, log1p(exp(100v))/100):
__device__ __forceinline__ float softplus100(float v) {
    return fmaxf(v, 0.f) + 0.01f * __logf(1.f + __expf(-100.f * fabsf(v)));
}

__device__ __forceinline__ bf16x8 cvt8(const float* __restrict__ p) {
    f32x4 a = *(const f32x4*)p;
    f32x4 b = *(const f32x4*)(p + 4);
    bf16x8 r;
    r[0] = f2bf(a[0]); r[1] = f2bf(a[1]); r[2] = f2bf(a[2]); r[3] = f2bf(a[3]);
    r[4] = f2bf(b[0]); r[5] = f2bf(b[1]); r[6] = f2bf(b[2]); r[7] = f2bf(b[3]);
    return r;
}

__device__ __forceinline__ float2 upk(unsigned v) {   // bf16 pair -> f32 pair (exact)
    return make_float2(__uint_as_float(v << 16), __uint_as_float(v & 0xffff0000u));
}

// Single-point trilinear gather on f32 tables (dense levels + fallbacks).
__device__ __forceinline__ float2 gather_level(const float* __restrict__ tab, int R,
                                               float x0, float x1, float x2) {
    const float Rm1 = (float)(R - 1);
    float px = x0 * Rm1, py = x1 * Rm1, pz = x2 * Rm1;
    float fx = floorf(px), fy = floorf(py), fz = floorf(pz);
    float wx = px - fx, wy = py - fy, wz = pz - fz;
    int ix = (int)fx, iy = (int)fy, iz = (int)fz;
    ix = max(0, min(ix, R - 1)); iy = max(0, min(iy, R - 1)); iz = max(0, min(iz, R - 1));
    int jx = min(ix + 1, R - 1), jy = min(iy + 1, R - 1), jz = min(iz + 1, R - 1);
    float ax = 1.f - wx, ay = 1.f - wy, az = 1.f - wz;
    float wyz0 = ay * az, wyz1 = wy * az, wyz2 = ay * wz, wyz3 = wy * wz;
    float2 lo[4], hi[4];
    const bool adj = (jx == ix + 1);
    if ((long long)R * R * R <= (long long)HMAP) {   // dense
        unsigned sy = (unsigned)R, sz = (unsigned)(R * R);
        unsigned bases[4] = {(unsigned)iy * sy + (unsigned)iz * sz,
                             (unsigned)jy * sy + (unsigned)iz * sz,
                             (unsigned)iy * sy + (unsigned)jz * sz,
                             (unsigned)jy * sy + (unsigned)jz * sz};
        const float2* t2 = (const float2*)tab;
        #pragma unroll
        for (int k = 0; k < 4; ++k) {
            unsigned i0 = bases[k] + (unsigned)ix;
            if (adj && !(i0 & 1u)) {
                f32x4 q = *(const f32x4*)(tab + ((size_t)i0 << 1));
                lo[k] = make_float2(q[0], q[1]);
                hi[k] = make_float2(q[2], q[3]);
            } else {
                lo[k] = t2[i0];
                hi[k] = t2[bases[k] + (unsigned)jx];
            }
        }
    } else {                                          // hashed
        unsigned hy0 = (unsigned)iy * 2654435761u, hy1 = (unsigned)jy * 2654435761u;
        unsigned hz0 = (unsigned)iz * 805459861u,  hz1 = (unsigned)jz * 805459861u;
        unsigned ms[4] = {hy0 ^ hz0, hy1 ^ hz0, hy0 ^ hz1, hy1 ^ hz1};
        if (adj && ((ix & 1) == 0)) {
            #pragma unroll
            for (int k = 0; k < 4; ++k) {
                unsigned h = ((unsigned)ix ^ ms[k]) & HMASK;
                f32x4 q = *(const f32x4*)(tab + ((size_t)(h & ~1u) << 1));
                float2 e0 = make_float2(q[0], q[1]);
                float2 e1 = make_float2(q[2], q[3]);
                bool sw = (h & 1u) != 0;
                lo[k] = sw ? e1 : e0;
                hi[k] = sw ? e0 : e1;
            }
        } else {
            const float2* t2 = (const float2*)tab;
            #pragma unroll
            for (int k = 0; k < 4; ++k) {
                unsigned hl = ((unsigned)ix ^ ms[k]) & HMASK;
                unsigned hh = ((unsigned)jx ^ ms[k]) & HMASK;
                lo[k] = t2[hl];
                hi[k] = t2[hh];
            }
        }
    }
    float2 r = make_float2(0.f, 0.f);
    float wyz[4] = {wyz0, wyz1, wyz2, wyz3};
    #pragma unroll
    for (int k = 0; k < 4; ++k) {
        float wl = ax * wyz[k], wh = wx * wyz[k];
        r.x += wl * lo[k].x + wh * hi[k].x;
        r.y += wl * lo[k].y + wh * hi[k].y;
    }
    return r;
}

// Two-point gather on f32 tables (path-B fallback K1).
__device__ __forceinline__ void gather2(const float* __restrict__ tab, int R,
                                        float x0A, float x1A, float x2A,
                                        float x0B, float x1B, float x2B,
                                        float2& rA, float2& rB) {
    const float Rm1 = (float)(R - 1);
    float wxv[2], axv[2];
    float wyz[2][4];
    float2 lo[2][4], hi[2][4];
    int ixv[2], jxv[2];
    unsigned basev[2][4];
    const bool dense = (long long)R * R * R <= (long long)HMAP;
    #pragma unroll
    for (int t = 0; t < 2; ++t) {
        const float X0 = t ? x0B : x0A, X1 = t ? x1B : x1A, X2 = t ? x2B : x2A;
        float px = X0 * Rm1, py = X1 * Rm1, pz = X2 * Rm1;
        float fx = floorf(px), fy = floorf(py), fz = floorf(pz);
        float wx = px - fx, wy = py - fy, wz = pz - fz;
        int ix = (int)fx, iy = (int)fy, iz = (int)fz;
        ix = max(0, min(ix, R - 1)); iy = max(0, min(iy, R - 1)); iz = max(0, min(iz, R - 1));
        int jx = min(ix + 1, R - 1), jy = min(iy + 1, R - 1), jz = min(iz + 1, R - 1);
        float ax = 1.f - wx, ay = 1.f - wy, az = 1.f - wz;
        wyz[t][0] = ay * az; wyz[t][1] = wy * az; wyz[t][2] = ay * wz; wyz[t][3] = wy * wz;
        wxv[t] = wx; axv[t] = ax; ixv[t] = ix; jxv[t] = jx;
        if (dense) {
            unsigned sy = (unsigned)R, sz = (unsigned)(R * R);
            basev[t][0] = (unsigned)iy * sy + (unsigned)iz * sz;
            basev[t][1] = (unsigned)jy * sy + (unsigned)iz * sz;
            basev[t][2] = (unsigned)iy * sy + (unsigned)jz * sz;
            basev[t][3] = (unsigned)jy * sy + (unsigned)jz * sz;
        } else {
            unsigned hy0 = (unsigned)iy * 2654435761u, hy1 = (unsigned)jy * 2654435761u;
            unsigned hz0 = (unsigned)iz * 805459861u,  hz1 = (unsigned)jz * 805459861u;
            basev[t][0] = hy0 ^ hz0; basev[t][1] = hy1 ^ hz0;
            basev[t][2] = hy0 ^ hz1; basev[t][3] = hy1 ^ hz1;
        }
    }
    if (dense) {
        const float2* t2 = (const float2*)tab;
        #pragma unroll
        for (int t = 0; t < 2; ++t) {
            const bool adj = (jxv[t] == ixv[t] + 1);
            #pragma unroll
            for (int k = 0; k < 4; ++k) {
                unsigned i0 = basev[t][k] + (unsigned)ixv[t];
                if (adj && !(i0 & 1u)) {
                    f32x4 q = *(const f32x4*)(tab + ((size_t)i0 << 1));
                    lo[t][k] = make_float2(q[0], q[1]);
                    hi[t][k] = make_float2(q[2], q[3]);
                } else {
                    lo[t][k] = t2[i0];
                    hi[t][k] = t2[basev[t][k] + (unsigned)jxv[t]];
                }
            }
        }
    } else {
        const float2* t2 = (const float2*)tab;
        #pragma unroll
        for (int t = 0; t < 2; ++t) {
            const bool adj = (jxv[t] == ixv[t] + 1) && ((ixv[t] & 1) == 0);
            #pragma unroll
            for (int k = 0; k < 4; ++k) {
                if (adj) {
                    unsigned h = ((unsigned)ixv[t] ^ basev[t][k]) & HMASK;
                    f32x4 q = *(const f32x4*)(tab + ((size_t)(h & ~1u) << 1));
                    float2 e0 = make_float2(q[0], q[1]);
                    float2 e1 = make_float2(q[2], q[3]);
                    bool sw = (h & 1u) != 0;
                    lo[t][k] = sw ? e1 : e0;
                    hi[t][k] = sw ? e0 : e1;
                } else {
                    unsigned hl = ((unsigned)ixv[t] ^ basev[t][k]) & HMASK;
                    unsigned hh = ((unsigned)jxv[t] ^ basev[t][k]) & HMASK;
                    lo[t][k] = t2[hl];
                    hi[t][k] = t2[hh];
                }
            }
        }
    }
    float2 res[2];
    #pragma unroll
    for (int t = 0; t < 2; ++t) {
        float2 r = make_float2(0.f, 0.f);
        #pragma unroll
        for (int k = 0; k < 4; ++k) {
            float wl = axv[t] * wyz[t][k], wh = wxv[t] * wyz[t][k];
            r.x += wl * lo[t][k].x + wh * hi[t][k].x;
            r.y += wl * lo[t][k].y + wh * hi[t][k].y;
        }
        res[t] = r;
    }
    rA = res[0]; rB = res[1];
}

// Two-point HASHED gather on bf16-pair (u32) tables.
__device__ __forceinline__ void gather2h(const unsigned* __restrict__ tab, int R,
                                         float x0A, float x1A, float x2A,
                                         float x0B, float x1B, float x2B,
                                         float2& rA, float2& rB) {
    const float Rm1 = (float)(R - 1);
    float wxv[2], axv[2], wyz[2][4];
    int ixv[2], jxv[2];
    bool adjv[2];
    unsigned msv[2][4];
    #pragma unroll
    for (int t = 0; t < 2; ++t) {
        const float X0 = t ? x0B : x0A, X1 = t ? x1B : x1A, X2 = t ? x2B : x2A;
        float px = X0 * Rm1, py = X1 * Rm1, pz = X2 * Rm1;
        float fx = floorf(px), fy = floorf(py), fz = floorf(pz);
        float wx = px - fx, wy = py - fy, wz = pz - fz;
        int ix = (int)fx, iy = (int)fy, iz = (int)fz;
        ix = max(0, min(ix, R - 1)); iy = max(0, min(iy, R - 1)); iz = max(0, min(iz, R - 1));
        int jx = min(ix + 1, R - 1), jy = min(iy + 1, R - 1), jz = min(iz + 1, R - 1);
        float ax = 1.f - wx, ay = 1.f - wy, az = 1.f - wz;
        wyz[t][0] = ay * az; wyz[t][1] = wy * az; wyz[t][2] = ay * wz; wyz[t][3] = wy * wz;
        wxv[t] = wx; axv[t] = ax; ixv[t] = ix; jxv[t] = jx;
        adjv[t] = (jx == ix + 1) && ((ix & 1) == 0);
        unsigned hy0 = (unsigned)iy * 2654435761u, hy1 = (unsigned)jy * 2654435761u;
        unsigned hz0 = (unsigned)iz * 805459861u,  hz1 = (unsigned)jz * 805459861u;
        msv[t][0] = hy0 ^ hz0; msv[t][1] = hy1 ^ hz0;
        msv[t][2] = hy0 ^ hz1; msv[t][3] = hy1 ^ hz1;
    }
    float2 lo[2][4], hi[2][4];
    #pragma unroll
    for (int t = 0; t < 2; ++t) {
        #pragma unroll
        for (int k = 0; k < 4; ++k) {
            if (adjv[t]) {
                unsigned h = ((unsigned)ixv[t] ^ msv[t][k]) & HMASK;
                u32x2 q = *(const u32x2*)(tab + (h & ~1u));   // 8B aligned
                float2 e0 = upk(q[0]), e1 = upk(q[1]);
                bool sw = (h & 1u) != 0;
                lo[t][k] = sw ? e1 : e0;
                hi[t][k] = sw ? e0 : e1;
            } else {
                unsigned hl = ((unsigned)ixv[t] ^ msv[t][k]) & HMASK;
                unsigned hh = ((unsigned)jxv[t] ^ msv[t][k]) & HMASK;
                lo[t][k] = upk(tab[hl]);
                hi[t][k] = upk(tab[hh]);
            }
        }
    }
    float2 res[2];
    #pragma unroll
    for (int t = 0; t < 2; ++t) {
        float2 r = make_float2(0.f, 0.f);
        #pragma unroll
        for (int k = 0; k < 4; ++k) {
            float wl = axv[t] * wyz[t][k], wh = wxv[t] * wyz[t][k];
            r.x += wl * lo[t][k].x + wh * hi[t][k].x;
            r.y += wl * lo[t][k].y + wh * hi[t][k].y;
        }
        res[t] = r;
    }
    rA = res[0]; rB = res[1];
}

// =================== Kernel 0: convert hashed tables (5..15) to bf16 pairs ===================
__global__ __launch_bounds__(256)
void cvt_tables(const float* __restrict__ tables, unsigned* __restrict__ tbf) {
    const size_t i = (size_t)blockIdx.x * 256 + threadIdx.x;   // < 11 * HMAP
    const f32x2* src = (const f32x2*)(tables + (size_t)5 * 2 * HMAP);
    f32x2 f = __builtin_nontemporal_load(src + i);
    unsigned v = (unsigned)f2bf(f[0]) | ((unsigned)f2bf(f[1]) << 16);
    __builtin_nontemporal_store(v, tbf + i);
}

// ======================= Shared MLP geometry =======================
#define NPB       128                     // points per tile
#define SA_STRIDE 104                     // shorts; 208B row stride
#define SW0_OFF   (128 * 104)             // W0 bf16 [64][104], cols 71..95 zero
#define SMEM_SHORTS (SW0_OFF + 64 * 104)  // 39936 B -> 4 blocks/CU

// ======================= Pipelined fused step =======================
// Chunked software pipeline across LAUNCHES (stream order = the only sync):
//   launch s: gather-role blocks stage hashed feats of chunk cg=s while
//             MLP-role blocks consume chunk cm=s-1 (written by launch s-1).
// Roles by blockIdx: XCD j = b%8 (measured: round-robin holds — pinning works),
// slot i = b/8. Slots [0,32): MLP (dispatched first -> CU-resident alongside
// gathers; 1 MLP + ~3 gather blocks per CU). Slots [32,416): gather, pinned:
//   fulls L5+j (256 rows) ; splits L13 on XCD{0,1,2}, L14 on {3,4,5}, L15 on {6,7}.
// Rationale: gather saturates XCD L2 (13.5 req/cy, VALU 16%); MLP uses VALU/MFMA
// with idle L2 -> co-scheduled waves overlap (m114). No spin, no grid.sync.
#define CHUNK     131072                  // 2^17 pts; 8 chunks
#define MLP_SLOTS 32
#define GSLOTS    384
#define FSTEP_GRID (8 * (MLP_SLOTS + GSLOTS))
#define TILES_F   4                       // 512 pts per MLP block

__global__ __launch_bounds__(256, 4)
void fused_step(const float* __restrict__ x, const float* __restrict__ tables,
                const unsigned* __restrict__ tbf, unsigned* __restrict__ feat,
                const float* __restrict__ W0, const float* __restrict__ b0,
                const float* __restrict__ W1, const float* __restrict__ b1,
                const float* __restrict__ W2, const float* __restrict__ b2,
                float* __restrict__ out, int N, int cg, int cm) {
    __shared__ unsigned short smem[SMEM_SHORTS];
    const int j = blockIdx.x & 7;
    const int i = blockIdx.x >> 3;

    if (i >= MLP_SLOTS) {
        // ---------------- gather role ----------------
        if (cg < 0) return;
        const int g = i - MLP_SLOTS;
        int level, row;
        if (g < 256) { level = 5 + j; row = g; }
        else {
            const int r = g - 256;                    // [0,128)
            if (j < 3) {                              // L13: 86/85/85 rows
                const int base = (j == 0) ? 0 : (j == 1 ? 86 : 171);
                const int share = (j == 0) ? 86 : 85;
                if (r >= share) return;
                level = 13; row = base + r;
            } else if (j < 6) {                       // L14: 86/85/85 rows
                const int jj = j - 3;
                const int base = (jj == 0) ? 0 : (jj == 1 ? 86 : 171);
                const int share = (jj == 0) ? 86 : 85;
                if (r >= share) return;
                level = 14; row = base + r;
            } else {                                  // L15: 128/128 rows
                if (r >= 128) return;
                level = 15; row = (j - 6) * 128 + r;
            }
        }
        const size_t p0 = (size_t)cg * CHUNK + (size_t)row * 512 + 2u * threadIdx.x;
        const f32x2* xv = (const f32x2*)(x + 3 * p0);   // 12*p0 B, p0 even -> 8B aligned
        f32x2 u0 = __builtin_nontemporal_load(xv);
        f32x2 u1 = __builtin_nontemporal_load(xv + 1);
        f32x2 u2 = __builtin_nontemporal_load(xv + 2);
        float2 fA, fB;
        gather2h(tbf + (size_t)(level - 5) * HMAP, c_res[level],
                 u0[0], u0[1], u1[0],
                 u1[1], u2[0], u2[1],
                 fA, fB);
        u32x2 v;
        v[0] = (unsigned)f2bf(fA.x) | ((unsigned)f2bf(fA.y) << 16);
        v[1] = (unsigned)f2bf(fB.x) | ((unsigned)f2bf(fB.y) << 16);
        __builtin_nontemporal_store(v, (u32x2*)(feat + (size_t)(level - 5) * N + p0));
        return;
    }

    // ---------------- MLP role ----------------
    if (cm < 0) return;
    const int m = i * 8 + j;                          // 0..255
    const int tid  = threadIdx.x;
    const int wave = tid >> 6, lane = tid & 63;
    const int mhalf = (wave & 1) * 64;
    const int nhalf = (wave >> 1);
    const int lrow = lane & 15, quad = lane >> 4;

    for (int q = tid; q < 64 * 104; q += 256) {
        int n = q / 104, k = q - n * 104;
        smem[SW0_OFF + q] = (k < 71) ? f2bf(W0[n * 71 + k]) : (unsigned short)0;
    }
    for (int q = tid; q < 128 * 25; q += 256) {
        int p = q / 25, k = q - p * 25;
        smem[p * SA_STRIDE + 71 + k] = 0;
    }
    bf16x8 w1f[2][2];
    #pragma unroll
    for (int ks = 0; ks < 2; ++ks)
        #pragma unroll
        for (int nt = 0; nt < 2; ++nt) {
            int n = nhalf * 32 + nt * 16 + lrow;
            w1f[ks][nt] = cvt8(W1 + n * 64 + ks * 32 + quad * 8);
        }
    bf16x8 w2f[2];
    {
        int n2 = nhalf * 16 + lrow;
        #pragma unroll
        for (int ks = 0; ks < 2; ++ks) {
            if (n2 < 17) w2f[ks] = cvt8(W2 + n2 * 64 + ks * 32 + quad * 8);
            else { bf16x8 z = {0,0,0,0,0,0,0,0}; w2f[ks] = z; }
        }
    }
    float b0v[2], b1v[2], b2v;
    #pragma unroll
    for (int nt = 0; nt < 2; ++nt) {
        b0v[nt] = b0[nhalf * 32 + nt * 16 + lrow];
        b1v[nt] = b1[nhalf * 32 + nt * 16 + lrow];
    }
    { int c2 = nhalf * 16 + lrow; b2v = (c2 < 17) ? b2[c2] : 0.f; }
    __syncthreads();

    const size_t pbase0 = (size_t)cm * CHUNK + (size_t)m * (NPB * TILES_F);
    #pragma unroll 1
    for (int t = 0; t < TILES_F; ++t) {
        const size_t pb = pbase0 + (size_t)t * NPB;
        {
            const int p = tid & 127;
            const size_t gp = pb + p;
            unsigned short* row = &smem[p * SA_STRIDE];
            const float x0 = __builtin_nontemporal_load(x + 3 * gp);
            const float x1 = __builtin_nontemporal_load(x + 3 * gp + 1);
            const float x2 = __builtin_nontemporal_load(x + 3 * gp + 2);
            float sa, ca, sb, cb, sc, cc;
            __sincosf(x0, &sa, &ca);
            __sincosf(x1, &sb, &cb);
            __sincosf(x2, &sc, &cc);
            if (tid < 128) {
                row[0] = f2bf(x0); row[1] = f2bf(x1); row[2] = f2bf(x2);
                #pragma unroll
                for (int mm = 0; mm < 6; ++mm) {
                    row[3 + 6 * mm + 0] = f2bf(sa);
                    row[3 + 6 * mm + 1] = f2bf(sb);
                    row[3 + 6 * mm + 2] = f2bf(sc);
                    float nsa = 2.f * sa * ca, nca = 1.f - 2.f * sa * sa;
                    float nsb = 2.f * sb * cb, ncb = 1.f - 2.f * sb * sb;
                    float nsc = 2.f * sc * cc, ncc = 1.f - 2.f * sc * sc;
                    sa = nsa; ca = nca; sb = nsb; cb = ncb; sc = nsc; cc = ncc;
                }
                float2 f;
                f = gather_level(tables,                         16, x0, x1, x2);
                row[39] = f2bf(f.x); row[40] = f2bf(f.y);
                f = gather_level(tables + (size_t)1 * 2 * HMAP,  23, x0, x1, x2);
                row[41] = f2bf(f.x); row[42] = f2bf(f.y);
                f = gather_level(tables + (size_t)2 * 2 * HMAP,  31, x0, x1, x2);
                row[43] = f2bf(f.x); row[44] = f2bf(f.y);
            } else {
                #pragma unroll
                for (int mm = 0; mm < 6; ++mm) {
                    row[3 + 6 * mm + 3] = f2bf(ca);
                    row[3 + 6 * mm + 4] = f2bf(cb);
                    row[3 + 6 * mm + 5] = f2bf(cc);
                    float nsa = 2.f * sa * ca, nca = 1.f - 2.f * sa * sa;
                    float nsb = 2.f * sb * cb, ncb = 1.f - 2.f * sb * sb;
                    float nsc = 2.f * sc * cc, ncc = 1.f - 2.f * sc * sc;
                    sa = nsa; ca = nca; sb = nsb; cb = ncb; sc = nsc; cc = ncc;
                }
                float2 f;
                f = gather_level(tables + (size_t)3 * 2 * HMAP,  43, x0, x1, x2);
                row[45] = f2bf(f.x); row[46] = f2bf(f.y);
                f = gather_level(tables + (size_t)4 * 2 * HMAP,  59, x0, x1, x2);
                row[47] = f2bf(f.x); row[48] = f2bf(f.y);
                #pragma unroll
                for (int li = 0; li < 11; ++li) {
                    unsigned v = __builtin_nontemporal_load(feat + (size_t)li * N + gp);
                    row[49 + 2 * li] = (unsigned short)(v & 0xffffu);
                    row[50 + 2 * li] = (unsigned short)(v >> 16);
                }
            }
        }
        __syncthreads();

        f32x4 acc0[4][2];
        #pragma unroll
        for (int mt = 0; mt < 4; ++mt)
            #pragma unroll
            for (int nt = 0; nt < 2; ++nt) acc0[mt][nt] = (f32x4){0.f, 0.f, 0.f, 0.f};
        #pragma unroll
        for (int ks = 0; ks < 3; ++ks) {
            bf16x8 bfr[2];
            #pragma unroll
            for (int nt = 0; nt < 2; ++nt) {
                int n = nhalf * 32 + nt * 16 + lrow;
                bfr[nt] = *(const bf16x8*)&smem[SW0_OFF + n * 104 + ks * 32 + quad * 8];
            }
            #pragma unroll
            for (int mt = 0; mt < 4; ++mt) {
                int mr = mhalf + mt * 16 + lrow;
                bf16x8 afr = *(const bf16x8*)&smem[mr * SA_STRIDE + ks * 32 + quad * 8];
                #pragma unroll
                for (int nt = 0; nt < 2; ++nt)
                    acc0[mt][nt] = __builtin_amdgcn_mfma_f32_16x16x32_bf16(afr, bfr[nt], acc0[mt][nt], 0, 0, 0);
            }
        }
        __syncthreads();
        #pragma unroll
        for (int mt = 0; mt < 4; ++mt)
            #pragma unroll
            for (int nt = 0; nt < 2; ++nt) {
                int colg = nhalf * 32 + nt * 16 + lrow;
                #pragma unroll
                for (int r = 0; r < 4; ++r) {
                    int rowm = mhalf + mt * 16 + quad * 4 + r;
                    smem[rowm * SA_STRIDE + colg] = f2bf(softplus100(acc0[mt][nt][r] + b0v[nt]));
                }
            }
        __syncthreads();

        f32x4 acc1[4][2];
        #pragma unroll
        for (int mt = 0; mt < 4; ++mt)
            #pragma unroll
            for (int nt = 0; nt < 2; ++nt) acc1[mt][nt] = (f32x4){0.f, 0.f, 0.f, 0.f};
        #pragma unroll
        for (int ks = 0; ks < 2; ++ks) {
            #pragma unroll
            for (int mt = 0; mt < 4; ++mt) {
                int mr = mhalf + mt * 16 + lrow;
                bf16x8 afr = *(const bf16x8*)&smem[mr * SA_STRIDE + ks * 32 + quad * 8];
                #pragma unroll
                for (int nt = 0; nt < 2; ++nt)
                    acc1[mt][nt] = __builtin_amdgcn_mfma_f32_16x16x32_bf16(afr, w1f[ks][nt], acc1[mt][nt], 0, 0, 0);
            }
        }
        __syncthreads();
        #pragma unroll
        for (int mt = 0; mt < 4; ++mt)
            #pragma unroll
            for (int nt = 0; nt < 2; ++nt) {
                int colg = nhalf * 32 + nt * 16 + lrow;
                #pragma unroll
                for (int r = 0; r < 4; ++r) {
                    int rowm = mhalf + mt * 16 + quad * 4 + r;
                    smem[rowm * SA_STRIDE + colg] = f2bf(softplus100(acc1[mt][nt][r] + b1v[nt]));
                }
            }
        __syncthreads();

        f32x4 acc2[4];
        #pragma unroll
        for (int mt = 0; mt < 4; ++mt) acc2[mt] = (f32x4){0.f, 0.f, 0.f, 0.f};
        #pragma unroll
        for (int ks = 0; ks < 2; ++ks) {
            #pragma unroll
            for (int mt = 0; mt < 4; ++mt) {
                int mr = mhalf + mt * 16 + lrow;
                bf16x8 afr = *(const bf16x8*)&smem[mr * SA_STRIDE + ks * 32 + quad * 8];
                acc2[mt] = __builtin_amdgcn_mfma_f32_16x16x32_bf16(afr, w2f[ks], acc2[mt], 0, 0, 0);
            }
        }
        {
            int colg = nhalf * 16 + lrow;
            if (colg < 17) {
                #pragma unroll
                for (int mt = 0; mt < 4; ++mt)
                    #pragma unroll
                    for (int r = 0; r < 4; ++r) {
                        int rowm = mhalf + mt * 16 + quad * 4 + r;
                        __builtin_nontemporal_store(acc2[mt][r] + b2v,
                                                    out + (pb + rowm) * 17 + colg);
                    }
            }
        }
        __syncthreads();
    }
}

// ======================= Path B (verified round-3 kernels) =======================
#define TILES     8
#define PTS_BLK   (NPB * TILES)           // 1024 points per block

__global__ __launch_bounds__(256, 6)
void gather_levels(const float* __restrict__ x, const float* __restrict__ tables,
                   unsigned* __restrict__ feat, int N, int C) {
    const int b = blockIdx.x;
    const int half = 8 * C;
    int r, level;
    if (b < half) { r = b; level = r & 7; }
    else          { r = b - half; level = 15 - (r & 7); }
    const size_t p0 = (size_t)(r >> 3) * 512 + 2u * threadIdx.x;
    const f32x2* xv = (const f32x2*)(x + 3 * p0);
    f32x2 u0 = __builtin_nontemporal_load(xv);
    f32x2 u1 = __builtin_nontemporal_load(xv + 1);
    f32x2 u2 = __builtin_nontemporal_load(xv + 2);
    float2 fA, fB;
    gather2(tables + (size_t)level * (2u * HMAP), c_res[level],
            u0[0], u0[1], u1[0],
            u1[1], u2[0], u2[1],
            fA, fB);
    u32x2 v;
    v[0] = (unsigned)f2bf(fA.x) | ((unsigned)f2bf(fA.y) << 16);
    v[1] = (unsigned)f2bf(fB.x) | ((unsigned)f2bf(fB.y) << 16);
    __builtin_nontemporal_store(v, (u32x2*)(feat + (size_t)level * N + p0));
}

__global__ __launch_bounds__(256, 4)
void mlp_tiled(const float* __restrict__ x, const unsigned* __restrict__ feat,
               const float* __restrict__ W0, const float* __restrict__ b0,
               const float* __restrict__ W1, const float* __restrict__ b1,
               const float* __restrict__ W2, const float* __restrict__ b2,
               float* __restrict__ out, int N) {
    __shared__ unsigned short smem[SMEM_SHORTS];
    const int tid  = threadIdx.x;
    const int blk  = blockIdx.x;
    const int wave = tid >> 6, lane = tid & 63;
    const int mhalf = (wave & 1) * 64;
    const int nhalf = (wave >> 1);
    const int lrow = lane & 15, quad = lane >> 4;

    for (int i = tid; i < 64 * 104; i += 256) {
        int n = i / 104, k = i - n * 104;
        smem[SW0_OFF + i] = (k < 71) ? f2bf(W0[n * 71 + k]) : (unsigned short)0;
    }
    for (int i = tid; i < 128 * 25; i += 256) {
        int p = i / 25, k = i - p * 25;
        smem[p * SA_STRIDE + 71 + k] = 0;
    }
    bf16x8 w1f[2][2];
    #pragma unroll
    for (int ks = 0; ks < 2; ++ks)
        #pragma unroll
        for (int nt = 0; nt < 2; ++nt) {
            int n = nhalf * 32 + nt * 16 + lrow;
            w1f[ks][nt] = cvt8(W1 + n * 64 + ks * 32 + quad * 8);
        }
    bf16x8 w2f[2];
    {
        int n2 = nhalf * 16 + lrow;
        #pragma unroll
        for (int ks = 0; ks < 2; ++ks) {
            if (n2 < 17) w2f[ks] = cvt8(W2 + n2 * 64 + ks * 32 + quad * 8);
            else { bf16x8 z = {0,0,0,0,0,0,0,0}; w2f[ks] = z; }
        }
    }
    float b0v[2], b1v[2], b2v;
    #pragma unroll
    for (int nt = 0; nt < 2; ++nt) {
        b0v[nt] = b0[nhalf * 32 + nt * 16 + lrow];
        b1v[nt] = b1[nhalf * 32 + nt * 16 + lrow];
    }
    { int c2 = nhalf * 16 + lrow; b2v = (c2 < 17) ? b2[c2] : 0.f; }
    __syncthreads();

    const size_t pbase0 = (size_t)blk * PTS_BLK;
    #pragma unroll 1
    for (int t = 0; t < TILES; ++t) {
        const size_t pb = pbase0 + (size_t)t * NPB;
        {
            const int p = tid & 127;
            const size_t gp = pb + p;
            unsigned short* row = &smem[p * SA_STRIDE];
            const float x0 = __builtin_nontemporal_load(x + 3 * gp);
            const float x1 = __builtin_nontemporal_load(x + 3 * gp + 1);
            const float x2 = __builtin_nontemporal_load(x + 3 * gp + 2);
            if (tid < 128) {
                row[0] = f2bf(x0); row[1] = f2bf(x1); row[2] = f2bf(x2);
                float fr = 1.f;
                #pragma unroll
                for (int m = 0; m < 6; ++m) {
                    row[3 + 6 * m + 0] = f2bf(__sinf(x0 * fr));
                    row[3 + 6 * m + 1] = f2bf(__sinf(x1 * fr));
                    row[3 + 6 * m + 2] = f2bf(__sinf(x2 * fr));
                    fr *= 2.f;
                }
            } else {
                float fr = 1.f;
                #pragma unroll
                for (int m = 0; m < 6; ++m) {
                    row[3 + 6 * m + 3] = f2bf(__cosf(x0 * fr));
                    row[3 + 6 * m + 4] = f2bf(__cosf(x1 * fr));
                    row[3 + 6 * m + 5] = f2bf(__cosf(x2 * fr));
                    fr *= 2.f;
                }
                #pragma unroll
                for (int l = 0; l < 16; ++l) {
                    unsigned v = __builtin_nontemporal_load(feat + (size_t)l * N + gp);
                    row[39 + 2 * l] = (unsigned short)(v & 0xffffu);
                    row[40 + 2 * l] = (unsigned short)(v >> 16);
                }
            }
        }
        __syncthreads();

        f32x4 acc0[4][2];
        #pragma unroll
        for (int mt = 0; mt < 4; ++mt)
            #pragma unroll
            for (int nt = 0; nt < 2; ++nt) acc0[mt][nt] = (f32x4){0.f, 0.f, 0.f, 0.f};
        #pragma unroll
        for (int ks = 0; ks < 3; ++ks) {
            bf16x8 bfr[2];
            #pragma unroll
            for (int nt = 0; nt < 2; ++nt) {
                int n = nhalf * 32 + nt * 16 + lrow;
                bfr[nt] = *(const bf16x8*)&smem[SW0_OFF + n * 104 + ks * 32 + quad * 8];
            }
            #pragma unroll
            for (int mt = 0; mt < 4; ++mt) {
                int m = mhalf + mt * 16 + lrow;
                bf16x8 afr = *(const bf16x8*)&smem[m * SA_STRIDE + ks * 32 + quad * 8];
                #pragma unroll
                for (int nt = 0; nt < 2; ++nt)
                    acc0[mt][nt] = __builtin_amdgcn_mfma_f32_16x16x32_bf16(afr, bfr[nt], acc0[mt][nt], 0, 0, 0);
            }
        }
        __syncthreads();
        #pragma unroll
        for (int mt = 0; mt < 4; ++mt)
            #pragma unroll
            for (int nt = 0; nt < 2; ++nt) {
                int colg = nhalf * 32 + nt * 16 + lrow;
                #pragma unroll
                for (int r = 0; r < 4; ++r) {
                    int rowm = mhalf + mt * 16 + quad * 4 + r;
                    smem[rowm * SA_STRIDE + colg] = f2bf(softplus100(acc0[mt][nt][r] + b0v[nt]));
                }
            }
        __syncthreads();

        f32x4 acc1[4][2];
        #pragma unroll
        for (int mt = 0; mt < 4; ++mt)
            #pragma unroll
            for (int nt = 0; nt < 2; ++nt) acc1[mt][nt] = (f32x4){0.f, 0.f, 0.f, 0.f};
        #pragma unroll
        for (int ks = 0; ks < 2; ++ks) {
            #pragma unroll
            for (int mt = 0; mt < 4; ++mt) {
                int m = mhalf + mt * 16 + lrow;
                bf16x8 afr = *(const bf16x8*)&smem[m * SA_STRIDE + ks * 32 + quad * 8];
                #pragma unroll
                for (int nt = 0; nt < 2; ++nt)
                    acc1[mt][nt] = __builtin_amdgcn_mfma_f32_16x16x32_bf16(afr, w1f[ks][nt], acc1[mt][nt], 0, 0, 0);
            }
        }
        __syncthreads();
        #pragma unroll
        for (int mt = 0; mt < 4; ++mt)
            #pragma unroll
            for (int nt = 0; nt < 2; ++nt) {
                int colg = nhalf * 32 + nt * 16 + lrow;
                #pragma unroll
                for (int r = 0; r < 4; ++r) {
                    int rowm = mhalf + mt * 16 + quad * 4 + r;
                    smem[rowm * SA_STRIDE + colg] = f2bf(softplus100(acc1[mt][nt][r] + b1v[nt]));
                }
            }
        __syncthreads();

        f32x4 acc2[4];
        #pragma unroll
        for (int mt = 0; mt < 4; ++mt) acc2[mt] = (f32x4){0.f, 0.f, 0.f, 0.f};
        #pragma unroll
        for (int ks = 0; ks < 2; ++ks) {
            #pragma unroll
            for (int mt = 0; mt < 4; ++mt) {
                int m = mhalf + mt * 16 + lrow;
                bf16x8 afr = *(const bf16x8*)&smem[m * SA_STRIDE + ks * 32 + quad * 8];
                acc2[mt] = __builtin_amdgcn_mfma_f32_16x16x32_bf16(afr, w2f[ks], acc2[mt], 0, 0, 0);
            }
        }
        {
            int colg = nhalf * 16 + lrow;
            if (colg < 17) {
                #pragma unroll
                for (int mt = 0; mt < 4; ++mt)
                    #pragma unroll
                    for (int r = 0; r < 4; ++r) {
                        int rowm = mhalf + mt * 16 + quad * 4 + r;
                        __builtin_nontemporal_store(acc2[mt][r] + b2v,
                                                    out + (pb + rowm) * 17 + colg);
                    }
            }
        }
        __syncthreads();
    }
}

// ======================= Fallback (ws too small): fully fused =======================
__global__ __launch_bounds__(256, 3)
void gn_fused(const float* __restrict__ x, const float* __restrict__ tables,
              const float* __restrict__ W0, const float* __restrict__ b0,
              const float* __restrict__ W1, const float* __restrict__ b1,
              const float* __restrict__ W2, const float* __restrict__ b2,
              float* __restrict__ out) {
    __shared__ unsigned short smem[SMEM_SHORTS];
    const int tid = threadIdx.x;
    const int blk = blockIdx.x;
    const int wave = tid >> 6, lane = tid & 63;
    const int mhalf = (wave & 1) * 64;
    const int nhalf = (wave >> 1);
    const int lrow = lane & 15, quad = lane >> 4;
    for (int i = tid; i < 64 * 104; i += 256) {
        int n = i / 104, k = i - n * 104;
        smem[SW0_OFF + i] = (k < 71) ? f2bf(W0[n * 71 + k]) : (unsigned short)0;
    }
    for (int i = tid; i < 128 * 25; i += 256) {
        int p = i / 25, k = i - p * 25;
        smem[p * SA_STRIDE + 71 + k] = 0;
    }
    bf16x8 w1f[2][2];
    #pragma unroll
    for (int ks = 0; ks < 2; ++ks)
        #pragma unroll
        for (int nt = 0; nt < 2; ++nt) {
            int n = nhalf * 32 + nt * 16 + lrow;
            w1f[ks][nt] = cvt8(W1 + n * 64 + ks * 32 + quad * 8);
        }
    bf16x8 w2f[2];
    {
        int n2 = nhalf * 16 + lrow;
        #pragma unroll
        for (int ks = 0; ks < 2; ++ks) {
            if (n2 < 17) w2f[ks] = cvt8(W2 + n2 * 64 + ks * 32 + quad * 8);
            else { bf16x8 z = {0,0,0,0,0,0,0,0}; w2f[ks] = z; }
        }
    }
    float b0v[2], b1v[2], b2v;
    #pragma unroll
    for (int nt = 0; nt < 2; ++nt) {
        b0v[nt] = b0[nhalf * 32 + nt * 16 + lrow];
        b1v[nt] = b1[nhalf * 32 + nt * 16 + lrow];
    }
    { int c2 = nhalf * 16 + lrow; b2v = (c2 < 17) ? b2[c2] : 0.f; }
    {
        const int p = tid & 127;
        const size_t gp = (size_t)blk * NPB + p;
        const float x0 = x[3 * gp], x1 = x[3 * gp + 1], x2 = x[3 * gp + 2];
        unsigned short* row = &smem[p * SA_STRIDE];
        if (tid < 128) {
            row[0] = f2bf(x0); row[1] = f2bf(x1); row[2] = f2bf(x2);
            float fr = 1.f;
            #pragma unroll
            for (int m = 0; m < 6; ++m) {
                row[3 + 6 * m + 0] = f2bf(__sinf(x0 * fr));
                row[3 + 6 * m + 1] = f2bf(__sinf(x1 * fr));
                row[3 + 6 * m + 2] = f2bf(__sinf(x2 * fr));
                fr *= 2.f;
            }
            #pragma unroll
            for (int li = 0; li < 8; ++li) {
                const int l = 2 * li;
                float2 f = gather_level(tables + (size_t)l * (2u * HMAP), c_res[l], x0, x1, x2);
                row[39 + 2 * l] = f2bf(f.x);
                row[40 + 2 * l] = f2bf(f.y);
            }
        } else {
            float fr = 1.f;
            #pragma unroll
            for (int m = 0; m < 6; ++m) {
                row[3 + 6 * m + 3] = f2bf(__cosf(x0 * fr));
                row[3 + 6 * m + 4] = f2bf(__cosf(x1 * fr));
                row[3 + 6 * m + 5] = f2bf(__cosf(x2 * fr));
                fr *= 2.f;
            }
            #pragma unroll
            for (int li = 0; li < 8; ++li) {
                const int l = 2 * li + 1;
                float2 f = gather_level(tables + (size_t)l * (2u * HMAP), c_res[l], x0, x1, x2);
                row[39 + 2 * l] = f2bf(f.x);
                row[40 + 2 * l] = f2bf(f.y);
            }
        }
    }
    __syncthreads();
    f32x4 acc0[4][2];
    #pragma unroll
    for (int mt = 0; mt < 4; ++mt)
        #pragma unroll
        for (int nt = 0; nt < 2; ++nt) acc0[mt][nt] = (f32x4){0.f, 0.f, 0.f, 0.f};
    #pragma unroll
    for (int ks = 0; ks < 3; ++ks) {
        bf16x8 bfr[2];
        #pragma unroll
        for (int nt = 0; nt < 2; ++nt) {
            int n = nhalf * 32 + nt * 16 + lrow;
            bfr[nt] = *(const bf16x8*)&smem[SW0_OFF + n * 104 + ks * 32 + quad * 8];
        }
        #pragma unroll
        for (int mt = 0; mt < 4; ++mt) {
            int m = mhalf + mt * 16 + lrow;
            bf16x8 afr = *(const bf16x8*)&smem[m * SA_STRIDE + ks * 32 + quad * 8];
            #pragma unroll
            for (int nt = 0; nt < 2; ++nt)
                acc0[mt][nt] = __builtin_amdgcn_mfma_f32_16x16x32_bf16(afr, bfr[nt], acc0[mt][nt], 0, 0, 0);
        }
    }
    __syncthreads();
    #pragma unroll
    for (int mt = 0; mt < 4; ++mt)
        #pragma unroll
        for (int nt = 0; nt < 2; ++nt) {
            int colg = nhalf * 32 + nt * 16 + lrow;
            #pragma unroll
            for (int r = 0; r < 4; ++r) {
                int rowm = mhalf + mt * 16 + quad * 4 + r;
                smem[rowm * SA_STRIDE + colg] = f2bf(softplus100(acc0[mt][nt][r] + b0v[nt]));
            }
        }
    __syncthreads();
    f32x4 acc1[4][2];
    #pragma unroll
    for (int mt = 0; mt < 4; ++mt)
        #pragma unroll
        for (int nt = 0; nt < 2; ++nt) acc1[mt][nt] = (f32x4){0.f, 0.f, 0.f, 0.f};
    #pragma unroll
    for (int ks = 0; ks < 2; ++ks) {
        #pragma unroll
        for (int mt = 0; mt < 4; ++mt) {
            int m = mhalf + mt * 16 + lrow;
            bf16x8 afr = *(const bf16x8*)&smem[m * SA_STRIDE + ks * 32 + quad * 8];
            #pragma unroll
            for (int nt = 0; nt < 2; ++nt)
                acc1[mt][nt] = __builtin_amdgcn_mfma_f32_16x16x32_bf16(afr, w1f[ks][nt], acc1[mt][nt], 0, 0, 0);
        }
    }
    __syncthreads();
    #pragma unroll
    for (int mt = 0; mt < 4; ++mt)
        #pragma unroll
        for (int nt = 0; nt < 2; ++nt) {
            int colg = nhalf * 32 + nt * 16 + lrow;
            #pragma unroll
            for (int r = 0; r < 4; ++r) {
                int rowm = mhalf + mt * 16 + quad * 4 + r;
                smem[rowm * SA_STRIDE + colg] = f2bf(softplus100(acc1[mt][nt][r] + b1v[nt]));
            }
        }
    __syncthreads();
    f32x4 acc2[4];
    #pragma unroll
    for (int mt = 0; mt < 4; ++mt) acc2[mt] = (f32x4){0.f, 0.f, 0.f, 0.f};
    #pragma unroll
    for (int ks = 0; ks < 2; ++ks) {
        #pragma unroll
        for (int mt = 0; mt < 4; ++mt) {
            int m = mhalf + mt * 16 + lrow;
            bf16x8 afr = *(const bf16x8*)&smem[m * SA_STRIDE + ks * 32 + quad * 8];
            acc2[mt] = __builtin_amdgcn_mfma_f32_16x16x32_bf16(afr, w2f[ks], acc2[mt], 0, 0, 0);
        }
    }
    {
        int colg = nhalf * 16 + lrow;
        if (colg < 17) {
            #pragma unroll
            for (int mt = 0; mt < 4; ++mt)
                #pragma unroll
                for (int r = 0; r < 4; ++r) {
                    int rowm = mhalf + mt * 16 + quad * 4 + r;
                    out[((size_t)blk * NPB + rowm) * 17 + colg] = acc2[mt][r] + b2v;
                }
        }
    }
}

extern "C" void kernel_launch(void* const* d_in, const int* in_sizes, int n_in,
                              void* d_out, int out_size, void* d_ws, size_t ws_size,
                              hipStream_t stream) {
    const float* x      = (const float*)d_in[0];
    const float* tables = (const float*)d_in[1];
    const float* W0     = (const float*)d_in[2];
    const float* b0     = (const float*)d_in[3];
    const float* W1     = (const float*)d_in[4];
    const float* b1     = (const float*)d_in[5];
    const float* W2     = (const float*)d_in[6];
    const float* b2     = (const float*)d_in[7];
    float* out = (float*)d_out;
    const int n = in_sizes[0] / 3;                           // 1048576
    const size_t featA_b = (size_t)11 * n * 4;               // 44 MB hashed feat staging
    const size_t tbf_b   = (size_t)11 * HMAP * 4;            // 22 MB bf16 tables
    const size_t wsB     = (size_t)16 * n * 4;               // 64 MB (path B)
    if (n == (1 << 20) && ws_size >= featA_b + tbf_b) {
        unsigned* feat = (unsigned*)d_ws;
        unsigned* tbf  = (unsigned*)((char*)d_ws + featA_b);
        cvt_tables<<<dim3(11 * HMAP / 256), dim3(256), 0, stream>>>(tables, tbf);
        // software pipeline: launch s gathers chunk s while MLPing chunk s-1
        for (int s = 0; s <= 8; ++s) {
            const int cg = (s < 8) ? s : -1;
            const int cm = s - 1;
            fused_step<<<dim3(FSTEP_GRID), dim3(256), 0, stream>>>(
                x, tables, tbf, feat, W0, b0, W1, b1, W2, b2, out, n, cg, cm);
        }
    } else if (ws_size >= wsB) {
        unsigned* feat = (unsigned*)d_ws;
        const int C = n / 512;
        gather_levels<<<dim3(16 * C), dim3(256), 0, stream>>>(x, tables, feat, n, C);
        mlp_tiled<<<dim3(n / PTS_BLK), dim3(256), 0, stream>>>(x, feat, W0, b0, W1, b1, W2, b2, out, n);
    } else {
        gn_fused<<<dim3(n / NPB), dim3(256), 0, stream>>>(x, tables, W0, b0, W1, b1, W2, b2, out);
    }
}

// Round 6
// 615.469 us; speedup vs baseline: 1.1712x; 1.1712x over previous
//
#include <hip/hip_runtime.h>
#include <stdint.h>

#define HMAP   (1u << 19)
#define HMASK  (HMAP - 1u)

typedef short bf16x8 __attribute__((ext_vector_type(8)));
typedef float f32x4  __attribute__((ext_vector_type(4)));
typedef float f32x2  __attribute__((ext_vector_type(2)));
typedef unsigned u32x2 __attribute__((ext_vector_type(2)));

// resolutions: ceil(16 * 2^(7l/15)); dense (R^3 <= 2^19) for levels 0..4
__device__ __constant__ const int c_res[16] = {16, 23, 31, 43, 59, 81, 112, 154, 213, 295, 407, 562, 777, 1073, 1483, 2048};

__device__ __forceinline__ unsigned short f2bf(float f) {
    unsigned u = __float_as_uint(f);
    u += 0x7fffu + ((u >> 16) & 1u);           // round-to-nearest-even
    return (unsigned short)(u >> 16);
}

// Exactly matches where(100v>20, v, log1p(exp(100v))/100):
__device__ __forceinline__ float softplus100(float v) {
    return fmaxf(v, 0.f) + 0.01f * __logf(1.f + __expf(-100.f * fabsf(v)));
}

__device__ __forceinline__ bf16x8 cvt8(const float* __restrict__ p) {
    f32x4 a = *(const f32x4*)p;
    f32x4 b = *(const f32x4*)(p + 4);
    bf16x8 r;
    r[0] = f2bf(a[0]); r[1] = f2bf(a[1]); r[2] = f2bf(a[2]); r[3] = f2bf(a[3]);
    r[4] = f2bf(b[0]); r[5] = f2bf(b[1]); r[6] = f2bf(b[2]); r[7] = f2bf(b[3]);
    return r;
}

__device__ __forceinline__ float2 upk(unsigned v) {   // bf16 pair -> f32 pair (exact)
    return make_float2(__uint_as_float(v << 16), __uint_as_float(v & 0xffff0000u));
}

// Single-point trilinear gather on f32 tables (dense levels + fallbacks).
__device__ __forceinline__ float2 gather_level(const float* __restrict__ tab, int R,
                                               float x0, float x1, float x2) {
    const float Rm1 = (float)(R - 1);
    float px = x0 * Rm1, py = x1 * Rm1, pz = x2 * Rm1;
    float fx = floorf(px), fy = floorf(py), fz = floorf(pz);
    float wx = px - fx, wy = py - fy, wz = pz - fz;
    int ix = (int)fx, iy = (int)fy, iz = (int)fz;
    ix = max(0, min(ix, R - 1)); iy = max(0, min(iy, R - 1)); iz = max(0, min(iz, R - 1));
    int jx = min(ix + 1, R - 1), jy = min(iy + 1, R - 1), jz = min(iz + 1, R - 1);
    float ax = 1.f - wx, ay = 1.f - wy, az = 1.f - wz;
    float wyz0 = ay * az, wyz1 = wy * az, wyz2 = ay * wz, wyz3 = wy * wz;
    float2 lo[4], hi[4];
    const bool adj = (jx == ix + 1);
    if ((long long)R * R * R <= (long long)HMAP) {   // dense
        unsigned sy = (unsigned)R, sz = (unsigned)(R * R);
        unsigned bases[4] = {(unsigned)iy * sy + (unsigned)iz * sz,
                             (unsigned)jy * sy + (unsigned)iz * sz,
                             (unsigned)iy * sy + (unsigned)jz * sz,
                             (unsigned)jy * sy + (unsigned)jz * sz};
        const float2* t2 = (const float2*)tab;
        #pragma unroll
        for (int k = 0; k < 4; ++k) {
            unsigned i0 = bases[k] + (unsigned)ix;
            if (adj && !(i0 & 1u)) {
                f32x4 q = *(const f32x4*)(tab + ((size_t)i0 << 1));
                lo[k] = make_float2(q[0], q[1]);
                hi[k] = make_float2(q[2], q[3]);
            } else {
                lo[k] = t2[i0];
                hi[k] = t2[bases[k] + (unsigned)jx];
            }
        }
    } else {                                          // hashed
        unsigned hy0 = (unsigned)iy * 2654435761u, hy1 = (unsigned)jy * 2654435761u;
        unsigned hz0 = (unsigned)iz * 805459861u,  hz1 = (unsigned)jz * 805459861u;
        unsigned ms[4] = {hy0 ^ hz0, hy1 ^ hz0, hy0 ^ hz1, hy1 ^ hz1};
        if (adj && ((ix & 1) == 0)) {
            #pragma unroll
            for (int k = 0; k < 4; ++k) {
                unsigned h = ((unsigned)ix ^ ms[k]) & HMASK;
                f32x4 q = *(const f32x4*)(tab + ((size_t)(h & ~1u) << 1));
                float2 e0 = make_float2(q[0], q[1]);
                float2 e1 = make_float2(q[2], q[3]);
                bool sw = (h & 1u) != 0;
                lo[k] = sw ? e1 : e0;
                hi[k] = sw ? e0 : e1;
            }
        } else {
            const float2* t2 = (const float2*)tab;
            #pragma unroll
            for (int k = 0; k < 4; ++k) {
                unsigned hl = ((unsigned)ix ^ ms[k]) & HMASK;
                unsigned hh = ((unsigned)jx ^ ms[k]) & HMASK;
                lo[k] = t2[hl];
                hi[k] = t2[hh];
            }
        }
    }
    float2 r = make_float2(0.f, 0.f);
    float wyz[4] = {wyz0, wyz1, wyz2, wyz3};
    #pragma unroll
    for (int k = 0; k < 4; ++k) {
        float wl = ax * wyz[k], wh = wx * wyz[k];
        r.x += wl * lo[k].x + wh * hi[k].x;
        r.y += wl * lo[k].y + wh * hi[k].y;
    }
    return r;
}

// Two-point gather on f32 tables (path-B fallback K1).
__device__ __forceinline__ void gather2(const float* __restrict__ tab, int R,
                                        float x0A, float x1A, float x2A,
                                        float x0B, float x1B, float x2B,
                                        float2& rA, float2& rB) {
    const float Rm1 = (float)(R - 1);
    float wxv[2], axv[2];
    float wyz[2][4];
    float2 lo[2][4], hi[2][4];
    int ixv[2], jxv[2];
    unsigned basev[2][4];
    const bool dense = (long long)R * R * R <= (long long)HMAP;
    #pragma unroll
    for (int t = 0; t < 2; ++t) {
        const float X0 = t ? x0B : x0A, X1 = t ? x1B : x1A, X2 = t ? x2B : x2A;
        float px = X0 * Rm1, py = X1 * Rm1, pz = X2 * Rm1;
        float fx = floorf(px), fy = floorf(py), fz = floorf(pz);
        float wx = px - fx, wy = py - fy, wz = pz - fz;
        int ix = (int)fx, iy = (int)fy, iz = (int)fz;
        ix = max(0, min(ix, R - 1)); iy = max(0, min(iy, R - 1)); iz = max(0, min(iz, R - 1));
        int jx = min(ix + 1, R - 1), jy = min(iy + 1, R - 1), jz = min(iz + 1, R - 1);
        float ax = 1.f - wx, ay = 1.f - wy, az = 1.f - wz;
        wyz[t][0] = ay * az; wyz[t][1] = wy * az; wyz[t][2] = ay * wz; wyz[t][3] = wy * wz;
        wxv[t] = wx; axv[t] = ax; ixv[t] = ix; jxv[t] = jx;
        if (dense) {
            unsigned sy = (unsigned)R, sz = (unsigned)(R * R);
            basev[t][0] = (unsigned)iy * sy + (unsigned)iz * sz;
            basev[t][1] = (unsigned)jy * sy + (unsigned)iz * sz;
            basev[t][2] = (unsigned)iy * sy + (unsigned)jz * sz;
            basev[t][3] = (unsigned)jy * sy + (unsigned)jz * sz;
        } else {
            unsigned hy0 = (unsigned)iy * 2654435761u, hy1 = (unsigned)jy * 2654435761u;
            unsigned hz0 = (unsigned)iz * 805459861u,  hz1 = (unsigned)jz * 805459861u;
            basev[t][0] = hy0 ^ hz0; basev[t][1] = hy1 ^ hz0;
            basev[t][2] = hy0 ^ hz1; basev[t][3] = hy1 ^ hz1;
        }
    }
    if (dense) {
        const float2* t2 = (const float2*)tab;
        #pragma unroll
        for (int t = 0; t < 2; ++t) {
            const bool adj = (jxv[t] == ixv[t] + 1);
            #pragma unroll
            for (int k = 0; k < 4; ++k) {
                unsigned i0 = basev[t][k] + (unsigned)ixv[t];
                if (adj && !(i0 & 1u)) {
                    f32x4 q = *(const f32x4*)(tab + ((size_t)i0 << 1));
                    lo[t][k] = make_float2(q[0], q[1]);
                    hi[t][k] = make_float2(q[2], q[3]);
                } else {
                    lo[t][k] = t2[i0];
                    hi[t][k] = t2[basev[t][k] + (unsigned)jxv[t]];
                }
            }
        }
    } else {
        const float2* t2 = (const float2*)tab;
        #pragma unroll
        for (int t = 0; t < 2; ++t) {
            const bool adj = (jxv[t] == ixv[t] + 1) && ((ixv[t] & 1) == 0);
            #pragma unroll
            for (int k = 0; k < 4; ++k) {
                if (adj) {
                    unsigned h = ((unsigned)ixv[t] ^ basev[t][k]) & HMASK;
                    f32x4 q = *(const f32x4*)(tab + ((size_t)(h & ~1u) << 1));
                    float2 e0 = make_float2(q[0], q[1]);
                    float2 e1 = make_float2(q[2], q[3]);
                    bool sw = (h & 1u) != 0;
                    lo[t][k] = sw ? e1 : e0;
                    hi[t][k] = sw ? e0 : e1;
                } else {
                    unsigned hl = ((unsigned)ixv[t] ^ basev[t][k]) & HMASK;
                    unsigned hh = ((unsigned)jxv[t] ^ basev[t][k]) & HMASK;
                    lo[t][k] = t2[hl];
                    hi[t][k] = t2[hh];
                }
            }
        }
    }
    float2 res[2];
    #pragma unroll
    for (int t = 0; t < 2; ++t) {
        float2 r = make_float2(0.f, 0.f);
        #pragma unroll
        for (int k = 0; k < 4; ++k) {
            float wl = axv[t] * wyz[t][k], wh = wxv[t] * wyz[t][k];
            r.x += wl * lo[t][k].x + wh * hi[t][k].x;
            r.y += wl * lo[t][k].y + wh * hi[t][k].y;
        }
        res[t] = r;
    }
    rA = res[0]; rB = res[1];
}

// Two-point HASHED gather on bf16-pair (u32) tables.
__device__ __forceinline__ void gather2h(const unsigned* __restrict__ tab, int R,
                                         float x0A, float x1A, float x2A,
                                         float x0B, float x1B, float x2B,
                                         float2& rA, float2& rB) {
    const float Rm1 = (float)(R - 1);
    float wxv[2], axv[2], wyz[2][4];
    int ixv[2], jxv[2];
    bool adjv[2];
    unsigned msv[2][4];
    #pragma unroll
    for (int t = 0; t < 2; ++t) {
        const float X0 = t ? x0B : x0A, X1 = t ? x1B : x1A, X2 = t ? x2B : x2A;
        float px = X0 * Rm1, py = X1 * Rm1, pz = X2 * Rm1;
        float fx = floorf(px), fy = floorf(py), fz = floorf(pz);
        float wx = px - fx, wy = py - fy, wz = pz - fz;
        int ix = (int)fx, iy = (int)fy, iz = (int)fz;
        ix = max(0, min(ix, R - 1)); iy = max(0, min(iy, R - 1)); iz = max(0, min(iz, R - 1));
        int jx = min(ix + 1, R - 1), jy = min(iy + 1, R - 1), jz = min(iz + 1, R - 1);
        float ax = 1.f - wx, ay = 1.f - wy, az = 1.f - wz;
        wyz[t][0] = ay * az; wyz[t][1] = wy * az; wyz[t][2] = ay * wz; wyz[t][3] = wy * wz;
        wxv[t] = wx; axv[t] = ax; ixv[t] = ix; jxv[t] = jx;
        adjv[t] = (jx == ix + 1) && ((ix & 1) == 0);
        unsigned hy0 = (unsigned)iy * 2654435761u, hy1 = (unsigned)jy * 2654435761u;
        unsigned hz0 = (unsigned)iz * 805459861u,  hz1 = (unsigned)jz * 805459861u;
        msv[t][0] = hy0 ^ hz0; msv[t][1] = hy1 ^ hz0;
        msv[t][2] = hy0 ^ hz1; msv[t][3] = hy1 ^ hz1;
    }
    float2 lo[2][4], hi[2][4];
    #pragma unroll
    for (int t = 0; t < 2; ++t) {
        #pragma unroll
        for (int k = 0; k < 4; ++k) {
            if (adjv[t]) {
                unsigned h = ((unsigned)ixv[t] ^ msv[t][k]) & HMASK;
                u32x2 q = *(const u32x2*)(tab + (h & ~1u));   // 8B aligned
                float2 e0 = upk(q[0]), e1 = upk(q[1]);
                bool sw = (h & 1u) != 0;
                lo[t][k] = sw ? e1 : e0;
                hi[t][k] = sw ? e0 : e1;
            } else {
                unsigned hl = ((unsigned)ixv[t] ^ msv[t][k]) & HMASK;
                unsigned hh = ((unsigned)jxv[t] ^ msv[t][k]) & HMASK;
                lo[t][k] = upk(tab[hl]);
                hi[t][k] = upk(tab[hh]);
            }
        }
    }
    float2 res[2];
    #pragma unroll
    for (int t = 0; t < 2; ++t) {
        float2 r = make_float2(0.f, 0.f);
        #pragma unroll
        for (int k = 0; k < 4; ++k) {
            float wl = axv[t] * wyz[t][k], wh = wxv[t] * wyz[t][k];
            r.x += wl * lo[t][k].x + wh * hi[t][k].x;
            r.y += wl * lo[t][k].y + wh * hi[t][k].y;
        }
        res[t] = r;
    }
    rA = res[0]; rB = res[1];
}

// =================== Kernel 0: convert hashed tables (5..15) to bf16 pairs ===================
__global__ __launch_bounds__(256)
void cvt_tables(const float* __restrict__ tables, unsigned* __restrict__ tbf) {
    const size_t i = (size_t)blockIdx.x * 256 + threadIdx.x;   // < 11 * HMAP
    const f32x2* src = (const f32x2*)(tables + (size_t)5 * 2 * HMAP);
    f32x2 f = __builtin_nontemporal_load(src + i);
    unsigned v = (unsigned)f2bf(f[0]) | ((unsigned)f2bf(f[1]) << 16);
    __builtin_nontemporal_store(v, tbf + i);
}

// =================== Kernel 1: hashed-level gather, XCD-balanced ===================
// fulls L5..L12 -> XCD 0..7; L13 split over XCD{0,1,2}, L14 over {3,4,5}, L15 over {6,7}
// -> max per-XCD load 1.5 units (verified: 382 -> 277 us vs pairing's 2.0).
// launch_bounds(256,8): round-4 occupancy was CAP-limited at 76% ((256,6) = 24 waves);
// VGPR=28 allows 8 blocks/CU -> 100% occupancy -> more outstanding L2 requests.
__global__ __launch_bounds__(256, 8)
void gather_hashed(const float* __restrict__ x, const unsigned* __restrict__ tbf,
                   unsigned* __restrict__ feat, int N) {
    const int j = blockIdx.x & 7;
    const int i = blockIdx.x >> 3;
    int level, chunk;
    if (i < 2048) {
        level = 5 + j; chunk = i;
    } else {
        const int r = i - 2048;
        if (j < 3) {
            const int share = (j == 2) ? 682 : 683;
            if (r >= share) return;
            level = 13; chunk = j * 683 + r;
        } else if (j < 6) {
            const int jj = j - 3;
            const int share = (jj == 2) ? 682 : 683;
            if (r >= share) return;
            level = 14; chunk = jj * 683 + r;
        } else {
            if (r >= 1024) return;
            level = 15; chunk = (j - 6) * 1024 + r;
        }
    }
    const size_t p0 = (size_t)chunk * 512 + 2u * threadIdx.x;
    const f32x2* xv = (const f32x2*)(x + 3 * p0);     // 12*p0 bytes, p0 even -> 8B aligned
    f32x2 u0 = __builtin_nontemporal_load(xv);
    f32x2 u1 = __builtin_nontemporal_load(xv + 1);
    f32x2 u2 = __builtin_nontemporal_load(xv + 2);
    float2 fA, fB;
    gather2h(tbf + (size_t)(level - 5) * HMAP, c_res[level],
             u0[0], u0[1], u1[0],
             u1[1], u2[0], u2[1],
             fA, fB);
    u32x2 v;
    v[0] = (unsigned)f2bf(fA.x) | ((unsigned)f2bf(fA.y) << 16);
    v[1] = (unsigned)f2bf(fB.x) | ((unsigned)f2bf(fB.y) << 16);
    __builtin_nontemporal_store(v, (u32x2*)(feat + (size_t)(level - 5) * N + p0));
}

// ======================= Kernel 2: tiled embed + dense gathers + MFMA MLP =======================
#define NPB       128                     // points per tile
#define TILES     8
#define PTS_BLK   (NPB * TILES)           // 1024 points per block
#define SA_STRIDE 104                     // shorts; 208B row stride
// mlp_tiled2: W0 lives in REGISTERS (w0f, 24 VGPR) -> LDS = A-tile only (26624 B)
// -> 5 blocks/CU (launch_bounds(256,5), VGPR cap 102) vs 4 before.
#define SA2_SHORTS (128 * 104)            // 26624 B
// path-B kernels keep the old layout:
#define SW0_OFF   (128 * 104)             // W0 bf16 [64][104], cols 71..95 zero
#define SMEM_SHORTS (SW0_OFF + 64 * 104)  // 39936 B -> 4 blocks/CU

__global__ __launch_bounds__(256, 5)
void mlp_tiled2(const float* __restrict__ x, const float* __restrict__ tables,
                const unsigned* __restrict__ feat,
                const float* __restrict__ W0, const float* __restrict__ b0,
                const float* __restrict__ W1, const float* __restrict__ b1,
                const float* __restrict__ W2, const float* __restrict__ b2,
                float* __restrict__ out, int N) {
    __shared__ unsigned short smem[SA2_SHORTS];
    const int tid  = threadIdx.x;
    const int blk  = blockIdx.x;
    const int wave = tid >> 6, lane = tid & 63;
    const int mhalf = (wave & 1) * 64;
    const int nhalf = (wave >> 1);
    const int lrow = lane & 15, quad = lane >> 4;

    // zero the pad columns 71..95 of the A tile once (layer0 reads k<96; embed
    // writes 0..70; activations write 0..63; pads stay zero for all tiles)
    for (int i = tid; i < 128 * 25; i += 256) {
        int p = i / 25, k = i - p * 25;
        smem[p * SA_STRIDE + 71 + k] = 0;
    }
    // W0 fragments in registers: same per-lane pattern as w1f (B-operand of 16x16x32)
    bf16x8 w0f[3][2];
    #pragma unroll
    for (int ks = 0; ks < 3; ++ks)
        #pragma unroll
        for (int nt = 0; nt < 2; ++nt) {
            int n = nhalf * 32 + nt * 16 + lrow;
            bf16x8 r;
            #pragma unroll
            for (int e = 0; e < 8; ++e) {
                int k = ks * 32 + quad * 8 + e;
                r[e] = (k < 71) ? f2bf(W0[n * 71 + k]) : (short)0;
            }
            w0f[ks][nt] = r;
        }
    bf16x8 w1f[2][2];
    #pragma unroll
    for (int ks = 0; ks < 2; ++ks)
        #pragma unroll
        for (int nt = 0; nt < 2; ++nt) {
            int n = nhalf * 32 + nt * 16 + lrow;
            w1f[ks][nt] = cvt8(W1 + n * 64 + ks * 32 + quad * 8);
        }
    bf16x8 w2f[2];
    {
        int n2 = nhalf * 16 + lrow;
        #pragma unroll
        for (int ks = 0; ks < 2; ++ks) {
            if (n2 < 17) w2f[ks] = cvt8(W2 + n2 * 64 + ks * 32 + quad * 8);
            else { bf16x8 z = {0,0,0,0,0,0,0,0}; w2f[ks] = z; }
        }
    }
    float b0v[2], b1v[2], b2v;
    #pragma unroll
    for (int nt = 0; nt < 2; ++nt) {
        b0v[nt] = b0[nhalf * 32 + nt * 16 + lrow];
        b1v[nt] = b1[nhalf * 32 + nt * 16 + lrow];
    }
    { int c2 = nhalf * 16 + lrow; b2v = (c2 < 17) ? b2[c2] : 0.f; }
    __syncthreads();

    const size_t pbase0 = (size_t)blk * PTS_BLK;
    #pragma unroll 1
    for (int t = 0; t < TILES; ++t) {
        const size_t pb = pbase0 + (size_t)t * NPB;
        {
            const int p = tid & 127;
            const size_t gp = pb + p;
            unsigned short* row = &smem[p * SA_STRIDE];
            const float x0 = __builtin_nontemporal_load(x + 3 * gp);
            const float x1 = __builtin_nontemporal_load(x + 3 * gp + 1);
            const float x2 = __builtin_nontemporal_load(x + 3 * gp + 2);
            // sin/cos of x*2^m via one sincos + double-angle recurrence
            float sa, ca, sb, cb, sc, cc;
            __sincosf(x0, &sa, &ca);
            __sincosf(x1, &sb, &cb);
            __sincosf(x2, &sc, &cc);
            if (tid < 128) {
                row[0] = f2bf(x0); row[1] = f2bf(x1); row[2] = f2bf(x2);
                #pragma unroll
                for (int m = 0; m < 6; ++m) {
                    row[3 + 6 * m + 0] = f2bf(sa);
                    row[3 + 6 * m + 1] = f2bf(sb);
                    row[3 + 6 * m + 2] = f2bf(sc);
                    float nsa = 2.f * sa * ca, nca = 1.f - 2.f * sa * sa;
                    float nsb = 2.f * sb * cb, ncb = 1.f - 2.f * sb * sb;
                    float nsc = 2.f * sc * cc, ncc = 1.f - 2.f * sc * sc;
                    sa = nsa; ca = nca; sb = nsb; cb = ncb; sc = nsc; cc = ncc;
                }
                float2 f;
                f = gather_level(tables,                         16, x0, x1, x2);
                row[39] = f2bf(f.x); row[40] = f2bf(f.y);
                f = gather_level(tables + (size_t)1 * 2 * HMAP,  23, x0, x1, x2);
                row[41] = f2bf(f.x); row[42] = f2bf(f.y);
                f = gather_level(tables + (size_t)2 * 2 * HMAP,  31, x0, x1, x2);
                row[43] = f2bf(f.x); row[44] = f2bf(f.y);
            } else {
                #pragma unroll
                for (int m = 0; m < 6; ++m) {
                    row[3 + 6 * m + 3] = f2bf(ca);
                    row[3 + 6 * m + 4] = f2bf(cb);
                    row[3 + 6 * m + 5] = f2bf(cc);
                    float nsa = 2.f * sa * ca, nca = 1.f - 2.f * sa * sa;
                    float nsb = 2.f * sb * cb, ncb = 1.f - 2.f * sb * sb;
                    float nsc = 2.f * sc * cc, ncc = 1.f - 2.f * sc * sc;
                    sa = nsa; ca = nca; sb = nsb; cb = ncb; sc = nsc; cc = ncc;
                }
                float2 f;
                f = gather_level(tables + (size_t)3 * 2 * HMAP,  43, x0, x1, x2);
                row[45] = f2bf(f.x); row[46] = f2bf(f.y);
                f = gather_level(tables + (size_t)4 * 2 * HMAP,  59, x0, x1, x2);
                row[47] = f2bf(f.x); row[48] = f2bf(f.y);
                #pragma unroll
                for (int li = 0; li < 11; ++li) {
                    unsigned v = __builtin_nontemporal_load(feat + (size_t)li * N + gp);
                    row[49 + 2 * li] = (unsigned short)(v & 0xffffu);
                    row[50 + 2 * li] = (unsigned short)(v >> 16);
                }
            }
        }
        __syncthreads();

        f32x4 acc0[4][2];
        #pragma unroll
        for (int mt = 0; mt < 4; ++mt)
            #pragma unroll
            for (int nt = 0; nt < 2; ++nt) acc0[mt][nt] = (f32x4){0.f, 0.f, 0.f, 0.f};
        #pragma unroll
        for (int ks = 0; ks < 3; ++ks) {
            #pragma unroll
            for (int mt = 0; mt < 4; ++mt) {
                int m = mhalf + mt * 16 + lrow;
                bf16x8 afr = *(const bf16x8*)&smem[m * SA_STRIDE + ks * 32 + quad * 8];
                #pragma unroll
                for (int nt = 0; nt < 2; ++nt)
                    acc0[mt][nt] = __builtin_amdgcn_mfma_f32_16x16x32_bf16(afr, w0f[ks][nt], acc0[mt][nt], 0, 0, 0);
            }
        }
        __syncthreads();
        #pragma unroll
        for (int mt = 0; mt < 4; ++mt)
            #pragma unroll
            for (int nt = 0; nt < 2; ++nt) {
                int colg = nhalf * 32 + nt * 16 + lrow;
                #pragma unroll
                for (int r = 0; r < 4; ++r) {
                    int rowm = mhalf + mt * 16 + quad * 4 + r;
                    smem[rowm * SA_STRIDE + colg] = f2bf(softplus100(acc0[mt][nt][r] + b0v[nt]));
                }
            }
        __syncthreads();

        f32x4 acc1[4][2];
        #pragma unroll
        for (int mt = 0; mt < 4; ++mt)
            #pragma unroll
            for (int nt = 0; nt < 2; ++nt) acc1[mt][nt] = (f32x4){0.f, 0.f, 0.f, 0.f};
        #pragma unroll
        for (int ks = 0; ks < 2; ++ks) {
            #pragma unroll
            for (int mt = 0; mt < 4; ++mt) {
                int m = mhalf + mt * 16 + lrow;
                bf16x8 afr = *(const bf16x8*)&smem[m * SA_STRIDE + ks * 32 + quad * 8];
                #pragma unroll
                for (int nt = 0; nt < 2; ++nt)
                    acc1[mt][nt] = __builtin_amdgcn_mfma_f32_16x16x32_bf16(afr, w1f[ks][nt], acc1[mt][nt], 0, 0, 0);
            }
        }
        __syncthreads();
        #pragma unroll
        for (int mt = 0; mt < 4; ++mt)
            #pragma unroll
            for (int nt = 0; nt < 2; ++nt) {
                int colg = nhalf * 32 + nt * 16 + lrow;
                #pragma unroll
                for (int r = 0; r < 4; ++r) {
                    int rowm = mhalf + mt * 16 + quad * 4 + r;
                    smem[rowm * SA_STRIDE + colg] = f2bf(softplus100(acc1[mt][nt][r] + b1v[nt]));
                }
            }
        __syncthreads();

        f32x4 acc2[4];
        #pragma unroll
        for (int mt = 0; mt < 4; ++mt) acc2[mt] = (f32x4){0.f, 0.f, 0.f, 0.f};
        #pragma unroll
        for (int ks = 0; ks < 2; ++ks) {
            #pragma unroll
            for (int mt = 0; mt < 4; ++mt) {
                int m = mhalf + mt * 16 + lrow;
                bf16x8 afr = *(const bf16x8*)&smem[m * SA_STRIDE + ks * 32 + quad * 8];
                acc2[mt] = __builtin_amdgcn_mfma_f32_16x16x32_bf16(afr, w2f[ks], acc2[mt], 0, 0, 0);
            }
        }
        {
            int colg = nhalf * 16 + lrow;
            if (colg < 17) {
                #pragma unroll
                for (int mt = 0; mt < 4; ++mt)
                    #pragma unroll
                    for (int r = 0; r < 4; ++r) {
                        int rowm = mhalf + mt * 16 + quad * 4 + r;
                        __builtin_nontemporal_store(acc2[mt][r] + b2v,
                                                    out + (pb + rowm) * 17 + colg);
                    }
            }
        }
        __syncthreads();
    }
}

// ======================= Path B (verified round-3 kernels) =======================
__global__ __launch_bounds__(256, 6)
void gather_levels(const float* __restrict__ x, const float* __restrict__ tables,
                   unsigned* __restrict__ feat, int N, int C) {
    const int b = blockIdx.x;
    const int half = 8 * C;
    int r, level;
    if (b < half) { r = b; level = r & 7; }
    else          { r = b - half; level = 15 - (r & 7); }
    const size_t p0 = (size_t)(r >> 3) * 512 + 2u * threadIdx.x;
    const f32x2* xv = (const f32x2*)(x + 3 * p0);
    f32x2 u0 = __builtin_nontemporal_load(xv);
    f32x2 u1 = __builtin_nontemporal_load(xv + 1);
    f32x2 u2 = __builtin_nontemporal_load(xv + 2);
    float2 fA, fB;
    gather2(tables + (size_t)level * (2u * HMAP), c_res[level],
            u0[0], u0[1], u1[0],
            u1[1], u2[0], u2[1],
            fA, fB);
    u32x2 v;
    v[0] = (unsigned)f2bf(fA.x) | ((unsigned)f2bf(fA.y) << 16);
    v[1] = (unsigned)f2bf(fB.x) | ((unsigned)f2bf(fB.y) << 16);
    __builtin_nontemporal_store(v, (u32x2*)(feat + (size_t)level * N + p0));
}

__global__ __launch_bounds__(256, 4)
void mlp_tiled(const float* __restrict__ x, const unsigned* __restrict__ feat,
               const float* __restrict__ W0, const float* __restrict__ b0,
               const float* __restrict__ W1, const float* __restrict__ b1,
               const float* __restrict__ W2, const float* __restrict__ b2,
               float* __restrict__ out, int N) {
    __shared__ unsigned short smem[SMEM_SHORTS];
    const int tid  = threadIdx.x;
    const int blk  = blockIdx.x;
    const int wave = tid >> 6, lane = tid & 63;
    const int mhalf = (wave & 1) * 64;
    const int nhalf = (wave >> 1);
    const int lrow = lane & 15, quad = lane >> 4;

    for (int i = tid; i < 64 * 104; i += 256) {
        int n = i / 104, k = i - n * 104;
        smem[SW0_OFF + i] = (k < 71) ? f2bf(W0[n * 71 + k]) : (unsigned short)0;
    }
    for (int i = tid; i < 128 * 25; i += 256) {
        int p = i / 25, k = i - p * 25;
        smem[p * SA_STRIDE + 71 + k] = 0;
    }
    bf16x8 w1f[2][2];
    #pragma unroll
    for (int ks = 0; ks < 2; ++ks)
        #pragma unroll
        for (int nt = 0; nt < 2; ++nt) {
            int n = nhalf * 32 + nt * 16 + lrow;
            w1f[ks][nt] = cvt8(W1 + n * 64 + ks * 32 + quad * 8);
        }
    bf16x8 w2f[2];
    {
        int n2 = nhalf * 16 + lrow;
        #pragma unroll
        for (int ks = 0; ks < 2; ++ks) {
            if (n2 < 17) w2f[ks] = cvt8(W2 + n2 * 64 + ks * 32 + quad * 8);
            else { bf16x8 z = {0,0,0,0,0,0,0,0}; w2f[ks] = z; }
        }
    }
    float b0v[2], b1v[2], b2v;
    #pragma unroll
    for (int nt = 0; nt < 2; ++nt) {
        b0v[nt] = b0[nhalf * 32 + nt * 16 + lrow];
        b1v[nt] = b1[nhalf * 32 + nt * 16 + lrow];
    }
    { int c2 = nhalf * 16 + lrow; b2v = (c2 < 17) ? b2[c2] : 0.f; }
    __syncthreads();

    const size_t pbase0 = (size_t)blk * PTS_BLK;
    #pragma unroll 1
    for (int t = 0; t < TILES; ++t) {
        const size_t pb = pbase0 + (size_t)t * NPB;
        {
            const int p = tid & 127;
            const size_t gp = pb + p;
            unsigned short* row = &smem[p * SA_STRIDE];
            const float x0 = __builtin_nontemporal_load(x + 3 * gp);
            const float x1 = __builtin_nontemporal_load(x + 3 * gp + 1);
            const float x2 = __builtin_nontemporal_load(x + 3 * gp + 2);
            if (tid < 128) {
                row[0] = f2bf(x0); row[1] = f2bf(x1); row[2] = f2bf(x2);
                float fr = 1.f;
                #pragma unroll
                for (int m = 0; m < 6; ++m) {
                    row[3 + 6 * m + 0] = f2bf(__sinf(x0 * fr));
                    row[3 + 6 * m + 1] = f2bf(__sinf(x1 * fr));
                    row[3 + 6 * m + 2] = f2bf(__sinf(x2 * fr));
                    fr *= 2.f;
                }
            } else {
                float fr = 1.f;
                #pragma unroll
                for (int m = 0; m < 6; ++m) {
                    row[3 + 6 * m + 3] = f2bf(__cosf(x0 * fr));
                    row[3 + 6 * m + 4] = f2bf(__cosf(x1 * fr));
                    row[3 + 6 * m + 5] = f2bf(__cosf(x2 * fr));
                    fr *= 2.f;
                }
                #pragma unroll
                for (int l = 0; l < 16; ++l) {
                    unsigned v = __builtin_nontemporal_load(feat + (size_t)l * N + gp);
                    row[39 + 2 * l] = (unsigned short)(v & 0xffffu);
                    row[40 + 2 * l] = (unsigned short)(v >> 16);
                }
            }
        }
        __syncthreads();

        f32x4 acc0[4][2];
        #pragma unroll
        for (int mt = 0; mt < 4; ++mt)
            #pragma unroll
            for (int nt = 0; nt < 2; ++nt) acc0[mt][nt] = (f32x4){0.f, 0.f, 0.f, 0.f};
        #pragma unroll
        for (int ks = 0; ks < 3; ++ks) {
            bf16x8 bfr[2];
            #pragma unroll
            for (int nt = 0; nt < 2; ++nt) {
                int n = nhalf * 32 + nt * 16 + lrow;
                bfr[nt] = *(const bf16x8*)&smem[SW0_OFF + n * 104 + ks * 32 + quad * 8];
            }
            #pragma unroll
            for (int mt = 0; mt < 4; ++mt) {
                int m = mhalf + mt * 16 + lrow;
                bf16x8 afr = *(const bf16x8*)&smem[m * SA_STRIDE + ks * 32 + quad * 8];
                #pragma unroll
                for (int nt = 0; nt < 2; ++nt)
                    acc0[mt][nt] = __builtin_amdgcn_mfma_f32_16x16x32_bf16(afr, bfr[nt], acc0[mt][nt], 0, 0, 0);
            }
        }
        __syncthreads();
        #pragma unroll
        for (int mt = 0; mt < 4; ++mt)
            #pragma unroll
            for (int nt = 0; nt < 2; ++nt) {
                int colg = nhalf * 32 + nt * 16 + lrow;
                #pragma unroll
                for (int r = 0; r < 4; ++r) {
                    int rowm = mhalf + mt * 16 + quad * 4 + r;
                    smem[rowm * SA_STRIDE + colg] = f2bf(softplus100(acc0[mt][nt][r] + b0v[nt]));
                }
            }
        __syncthreads();

        f32x4 acc1[4][2];
        #pragma unroll
        for (int mt = 0; mt < 4; ++mt)
            #pragma unroll
            for (int nt = 0; nt < 2; ++nt) acc1[mt][nt] = (f32x4){0.f, 0.f, 0.f, 0.f};
        #pragma unroll
        for (int ks = 0; ks < 2; ++ks) {
            #pragma unroll
            for (int mt = 0; mt < 4; ++mt) {
                int m = mhalf + mt * 16 + lrow;
                bf16x8 afr = *(const bf16x8*)&smem[m * SA_STRIDE + ks * 32 + quad * 8];
                #pragma unroll
                for (int nt = 0; nt < 2; ++nt)
                    acc1[mt][nt] = __builtin_amdgcn_mfma_f32_16x16x32_bf16(afr, w1f[ks][nt], acc1[mt][nt], 0, 0, 0);
            }
        }
        __syncthreads();
        #pragma unroll
        for (int mt = 0; mt < 4; ++mt)
            #pragma unroll
            for (int nt = 0; nt < 2; ++nt) {
                int colg = nhalf * 32 + nt * 16 + lrow;
                #pragma unroll
                for (int r = 0; r < 4; ++r) {
                    int rowm = mhalf + mt * 16 + quad * 4 + r;
                    smem[rowm * SA_STRIDE + colg] = f2bf(softplus100(acc1[mt][nt][r] + b1v[nt]));
                }
            }
        __syncthreads();

        f32x4 acc2[4];
        #pragma unroll
        for (int mt = 0; mt < 4; ++mt) acc2[mt] = (f32x4){0.f, 0.f, 0.f, 0.f};
        #pragma unroll
        for (int ks = 0; ks < 2; ++ks) {
            #pragma unroll
            for (int mt = 0; mt < 4; ++mt) {
                int m = mhalf + mt * 16 + lrow;
                bf16x8 afr = *(const bf16x8*)&smem[m * SA_STRIDE + ks * 32 + quad * 8];
                acc2[mt] = __builtin_amdgcn_mfma_f32_16x16x32_bf16(afr, w2f[ks], acc2[mt], 0, 0, 0);
            }
        }
        {
            int colg = nhalf * 16 + lrow;
            if (colg < 17) {
                #pragma unroll
                for (int mt = 0; mt < 4; ++mt)
                    #pragma unroll
                    for (int r = 0; r < 4; ++r) {
                        int rowm = mhalf + mt * 16 + quad * 4 + r;
                        __builtin_nontemporal_store(acc2[mt][r] + b2v,
                                                    out + (pb + rowm) * 17 + colg);
                    }
            }
        }
        __syncthreads();
    }
}

// ======================= Fallback (ws too small): fully fused =======================
__global__ __launch_bounds__(256, 3)
void gn_fused(const float* __restrict__ x, const float* __restrict__ tables,
              const float* __restrict__ W0, const float* __restrict__ b0,
              const float* __restrict__ W1, const float* __restrict__ b1,
              const float* __restrict__ W2, const float* __restrict__ b2,
              float* __restrict__ out) {
    __shared__ unsigned short smem[SMEM_SHORTS];
    const int tid = threadIdx.x;
    const int blk = blockIdx.x;
    const int wave = tid >> 6, lane = tid & 63;
    const int mhalf = (wave & 1) * 64;
    const int nhalf = (wave >> 1);
    const int lrow = lane & 15, quad = lane >> 4;
    for (int i = tid; i < 64 * 104; i += 256) {
        int n = i / 104, k = i - n * 104;
        smem[SW0_OFF + i] = (k < 71) ? f2bf(W0[n * 71 + k]) : (unsigned short)0;
    }
    for (int i = tid; i < 128 * 25; i += 256) {
        int p = i / 25, k = i - p * 25;
        smem[p * SA_STRIDE + 71 + k] = 0;
    }
    bf16x8 w1f[2][2];
    #pragma unroll
    for (int ks = 0; ks < 2; ++ks)
        #pragma unroll
        for (int nt = 0; nt < 2; ++nt) {
            int n = nhalf * 32 + nt * 16 + lrow;
            w1f[ks][nt] = cvt8(W1 + n * 64 + ks * 32 + quad * 8);
        }
    bf16x8 w2f[2];
    {
        int n2 = nhalf * 16 + lrow;
        #pragma unroll
        for (int ks = 0; ks < 2; ++ks) {
            if (n2 < 17) w2f[ks] = cvt8(W2 + n2 * 64 + ks * 32 + quad * 8);
            else { bf16x8 z = {0,0,0,0,0,0,0,0}; w2f[ks] = z; }
        }
    }
    float b0v[2], b1v[2], b2v;
    #pragma unroll
    for (int nt = 0; nt < 2; ++nt) {
        b0v[nt] = b0[nhalf * 32 + nt * 16 + lrow];
        b1v[nt] = b1[nhalf * 32 + nt * 16 + lrow];
    }
    { int c2 = nhalf * 16 + lrow; b2v = (c2 < 17) ? b2[c2] : 0.f; }
    {
        const int p = tid & 127;
        const size_t gp = (size_t)blk * NPB + p;
        const float x0 = x[3 * gp], x1 = x[3 * gp + 1], x2 = x[3 * gp + 2];
        unsigned short* row = &smem[p * SA_STRIDE];
        if (tid < 128) {
            row[0] = f2bf(x0); row[1] = f2bf(x1); row[2] = f2bf(x2);
            float fr = 1.f;
            #pragma unroll
            for (int m = 0; m < 6; ++m) {
                row[3 + 6 * m + 0] = f2bf(__sinf(x0 * fr));
                row[3 + 6 * m + 1] = f2bf(__sinf(x1 * fr));
                row[3 + 6 * m + 2] = f2bf(__sinf(x2 * fr));
                fr *= 2.f;
            }
            #pragma unroll
            for (int li = 0; li < 8; ++li) {
                const int l = 2 * li;
                float2 f = gather_level(tables + (size_t)l * (2u * HMAP), c_res[l], x0, x1, x2);
                row[39 + 2 * l] = f2bf(f.x);
                row[40 + 2 * l] = f2bf(f.y);
            }
        } else {
            float fr = 1.f;
            #pragma unroll
            for (int m = 0; m < 6; ++m) {
                row[3 + 6 * m + 3] = f2bf(__cosf(x0 * fr));
                row[3 + 6 * m + 4] = f2bf(__cosf(x1 * fr));
                row[3 + 6 * m + 5] = f2bf(__cosf(x2 * fr));
                fr *= 2.f;
            }
            #pragma unroll
            for (int li = 0; li < 8; ++li) {
                const int l = 2 * li + 1;
                float2 f = gather_level(tables + (size_t)l * (2u * HMAP), c_res[l], x0, x1, x2);
                row[39 + 2 * l] = f2bf(f.x);
                row[40 + 2 * l] = f2bf(f.y);
            }
        }
    }
    __syncthreads();
    f32x4 acc0[4][2];
    #pragma unroll
    for (int mt = 0; mt < 4; ++mt)
        #pragma unroll
        for (int nt = 0; nt < 2; ++nt) acc0[mt][nt] = (f32x4){0.f, 0.f, 0.f, 0.f};
    #pragma unroll
    for (int ks = 0; ks < 3; ++ks) {
        bf16x8 bfr[2];
        #pragma unroll
        for (int nt = 0; nt < 2; ++nt) {
            int n = nhalf * 32 + nt * 16 + lrow;
            bfr[nt] = *(const bf16x8*)&smem[SW0_OFF + n * 104 + ks * 32 + quad * 8];
        }
        #pragma unroll
        for (int mt = 0; mt < 4; ++mt) {
            int m = mhalf + mt * 16 + lrow;
            bf16x8 afr = *(const bf16x8*)&smem[m * SA_STRIDE + ks * 32 + quad * 8];
            #pragma unroll
            for (int nt = 0; nt < 2; ++nt)
                acc0[mt][nt] = __builtin_amdgcn_mfma_f32_16x16x32_bf16(afr, bfr[nt], acc0[mt][nt], 0, 0, 0);
        }
    }
    __syncthreads();
    #pragma unroll
    for (int mt = 0; mt < 4; ++mt)
        #pragma unroll
        for (int nt = 0; nt < 2; ++nt) {
            int colg = nhalf * 32 + nt * 16 + lrow;
            #pragma unroll
            for (int r = 0; r < 4; ++r) {
                int rowm = mhalf + mt * 16 + quad * 4 + r;
                smem[rowm * SA_STRIDE + colg] = f2bf(softplus100(acc0[mt][nt][r] + b0v[nt]));
            }
        }
    __syncthreads();
    f32x4 acc1[4][2];
    #pragma unroll
    for (int mt = 0; mt < 4; ++mt)
        #pragma unroll
        for (int nt = 0; nt < 2; ++nt) acc1[mt][nt] = (f32x4){0.f, 0.f, 0.f, 0.f};
    #pragma unroll
    for (int ks = 0; ks < 2; ++ks) {
        #pragma unroll
        for (int mt = 0; mt < 4; ++mt) {
            int m = mhalf + mt * 16 + lrow;
            bf16x8 afr = *(const bf16x8*)&smem[m * SA_STRIDE + ks * 32 + quad * 8];
            #pragma unroll
            for (int nt = 0; nt < 2; ++nt)
                acc1[mt][nt] = __builtin_amdgcn_mfma_f32_16x16x32_bf16(afr, w1f[ks][nt], acc1[mt][nt], 0, 0, 0);
        }
    }
    __syncthreads();
    #pragma unroll
    for (int mt = 0; mt < 4; ++mt)
        #pragma unroll
        for (int nt = 0; nt < 2; ++nt) {
            int colg = nhalf * 32 + nt * 16 + lrow;
            #pragma unroll
            for (int r = 0; r < 4; ++r) {
                int rowm = mhalf + mt * 16 + quad * 4 + r;
                smem[rowm * SA_STRIDE + colg] = f2bf(softplus100(acc1[mt][nt][r] + b1v[nt]));
            }
        }
    __syncthreads();
    f32x4 acc2[4];
    #pragma unroll
    for (int mt = 0; mt < 4; ++mt) acc2[mt] = (f32x4){0.f, 0.f, 0.f, 0.f};
    #pragma unroll
    for (int ks = 0; ks < 2; ++ks) {
        #pragma unroll
        for (int mt = 0; mt < 4; ++mt) {
            int m = mhalf + mt * 16 + lrow;
            bf16x8 afr = *(const bf16x8*)&smem[m * SA_STRIDE + ks * 32 + quad * 8];
            acc2[mt] = __builtin_amdgcn_mfma_f32_16x16x32_bf16(afr, w2f[ks], acc2[mt], 0, 0, 0);
        }
    }
    {
        int colg = nhalf * 16 + lrow;
        if (colg < 17) {
            #pragma unroll
            for (int mt = 0; mt < 4; ++mt)
                #pragma unroll
                for (int r = 0; r < 4; ++r) {
                    int rowm = mhalf + mt * 16 + quad * 4 + r;
                    out[((size_t)blk * NPB + rowm) * 17 + colg] = acc2[mt][r] + b2v;
                }
        }
    }
}

extern "C" void kernel_launch(void* const* d_in, const int* in_sizes, int n_in,
                              void* d_out, int out_size, void* d_ws, size_t ws_size,
                              hipStream_t stream) {
    const float* x      = (const float*)d_in[0];
    const float* tables = (const float*)d_in[1];
    const float* W0     = (const float*)d_in[2];
    const float* b0     = (const float*)d_in[3];
    const float* W1     = (const float*)d_in[4];
    const float* b1     = (const float*)d_in[5];
    const float* W2     = (const float*)d_in[6];
    const float* b2     = (const float*)d_in[7];
    float* out = (float*)d_out;
    const int n = in_sizes[0] / 3;                           // 1048576
    const size_t featA_b = (size_t)11 * n * 4;               // 44 MB hashed feat staging
    const size_t tbf_b   = (size_t)11 * HMAP * 4;            // 22 MB bf16 tables
    const size_t wsB     = (size_t)16 * n * 4;               // 64 MB (path B)
    if (n == (1 << 20) && ws_size >= featA_b + tbf_b) {
        unsigned* feat = (unsigned*)d_ws;
        unsigned* tbf  = (unsigned*)((char*)d_ws + featA_b);
        cvt_tables<<<dim3(11 * HMAP / 256), dim3(256), 0, stream>>>(tables, tbf);
        gather_hashed<<<dim3(8 * 3072), dim3(256), 0, stream>>>(x, tbf, feat, n);
        mlp_tiled2<<<dim3(n / PTS_BLK), dim3(256), 0, stream>>>(x, tables, feat, W0, b0, W1, b1, W2, b2, out, n);
    } else if (ws_size >= wsB) {
        unsigned* feat = (unsigned*)d_ws;
        const int C = n / 512;
        gather_levels<<<dim3(16 * C), dim3(256), 0, stream>>>(x, tables, feat, n, C);
        mlp_tiled<<<dim3(n / PTS_BLK), dim3(256), 0, stream>>>(x, feat, W0, b0, W1, b1, W2, b2, out, n);
    } else {
        gn_fused<<<dim3(n / NPB), dim3(256), 0, stream>>>(x, tables, W0, b0, W1, b1, W2, b2, out);
    }
}

// Round 7
// 554.770 us; speedup vs baseline: 1.2993x; 1.1094x over previous
//
#include <hip/hip_runtime.h>
#include <stdint.h>

#define HMAP   (1u << 19)
#define HMASK  (HMAP - 1u)

typedef short bf16x8 __attribute__((ext_vector_type(8)));
typedef float f32x4  __attribute__((ext_vector_type(4)));
typedef float f32x2  __attribute__((ext_vector_type(2)));
typedef unsigned u32x2 __attribute__((ext_vector_type(2)));
typedef unsigned u32x4 __attribute__((ext_vector_type(4)));

// resolutions: ceil(16 * 2^(7l/15)); dense (R^3 <= 2^19) for levels 0..4
__device__ __constant__ const int c_res[16] = {16, 23, 31, 43, 59, 81, 112, 154, 213, 295, 407, 562, 777, 1073, 1483, 2048};

__device__ __forceinline__ unsigned short f2bf(float f) {
    unsigned u = __float_as_uint(f);
    u += 0x7fffu + ((u >> 16) & 1u);           // round-to-nearest-even
    return (unsigned short)(u >> 16);
}

// Exactly matches where(100v>20, v, log1p(exp(100v))/100):
__device__ __forceinline__ float softplus100(float v) {
    return fmaxf(v, 0.f) + 0.01f * __logf(1.f + __expf(-100.f * fabsf(v)));
}

__device__ __forceinline__ bf16x8 cvt8(const float* __restrict__ p) {
    f32x4 a = *(const f32x4*)p;
    f32x4 b = *(const f32x4*)(p + 4);
    bf16x8 r;
    r[0] = f2bf(a[0]); r[1] = f2bf(a[1]); r[2] = f2bf(a[2]); r[3] = f2bf(a[3]);
    r[4] = f2bf(b[0]); r[5] = f2bf(b[1]); r[6] = f2bf(b[2]); r[7] = f2bf(b[3]);
    return r;
}

__device__ __forceinline__ float2 upk(unsigned v) {   // bf16 pair -> f32 pair (exact)
    return make_float2(__uint_as_float(v << 16), __uint_as_float(v & 0xffff0000u));
}

__device__ __forceinline__ unsigned pkf2(float2 f) {
    return (unsigned)f2bf(f.x) | ((unsigned)f2bf(f.y) << 16);
}

// Single-point trilinear gather on f32 tables (dense fallback + gn_fused).
__device__ __forceinline__ float2 gather_level(const float* __restrict__ tab, int R,
                                               float x0, float x1, float x2) {
    const float Rm1 = (float)(R - 1);
    float px = x0 * Rm1, py = x1 * Rm1, pz = x2 * Rm1;
    float fx = floorf(px), fy = floorf(py), fz = floorf(pz);
    float wx = px - fx, wy = py - fy, wz = pz - fz;
    int ix = (int)fx, iy = (int)fy, iz = (int)fz;
    ix = max(0, min(ix, R - 1)); iy = max(0, min(iy, R - 1)); iz = max(0, min(iz, R - 1));
    int jx = min(ix + 1, R - 1), jy = min(iy + 1, R - 1), jz = min(iz + 1, R - 1);
    float ax = 1.f - wx, ay = 1.f - wy, az = 1.f - wz;
    float wyz0 = ay * az, wyz1 = wy * az, wyz2 = ay * wz, wyz3 = wy * wz;
    float2 lo[4], hi[4];
    const bool adj = (jx == ix + 1);
    if ((long long)R * R * R <= (long long)HMAP) {   // dense
        unsigned sy = (unsigned)R, sz = (unsigned)(R * R);
        unsigned bases[4] = {(unsigned)iy * sy + (unsigned)iz * sz,
                             (unsigned)jy * sy + (unsigned)iz * sz,
                             (unsigned)iy * sy + (unsigned)jz * sz,
                             (unsigned)jy * sy + (unsigned)jz * sz};
        const float2* t2 = (const float2*)tab;
        #pragma unroll
        for (int k = 0; k < 4; ++k) {
            unsigned i0 = bases[k] + (unsigned)ix;
            if (adj && !(i0 & 1u)) {
                f32x4 q = *(const f32x4*)(tab + ((size_t)i0 << 1));
                lo[k] = make_float2(q[0], q[1]);
                hi[k] = make_float2(q[2], q[3]);
            } else {
                lo[k] = t2[i0];
                hi[k] = t2[bases[k] + (unsigned)jx];
            }
        }
    } else {                                          // hashed
        unsigned hy0 = (unsigned)iy * 2654435761u, hy1 = (unsigned)jy * 2654435761u;
        unsigned hz0 = (unsigned)iz * 805459861u,  hz1 = (unsigned)jz * 805459861u;
        unsigned ms[4] = {hy0 ^ hz0, hy1 ^ hz0, hy0 ^ hz1, hy1 ^ hz1};
        if (adj && ((ix & 1) == 0)) {
            #pragma unroll
            for (int k = 0; k < 4; ++k) {
                unsigned h = ((unsigned)ix ^ ms[k]) & HMASK;
                f32x4 q = *(const f32x4*)(tab + ((size_t)(h & ~1u) << 1));
                float2 e0 = make_float2(q[0], q[1]);
                float2 e1 = make_float2(q[2], q[3]);
                bool sw = (h & 1u) != 0;
                lo[k] = sw ? e1 : e0;
                hi[k] = sw ? e0 : e1;
            }
        } else {
            const float2* t2 = (const float2*)tab;
            #pragma unroll
            for (int k = 0; k < 4; ++k) {
                unsigned hl = ((unsigned)ix ^ ms[k]) & HMASK;
                unsigned hh = ((unsigned)jx ^ ms[k]) & HMASK;
                lo[k] = t2[hl];
                hi[k] = t2[hh];
            }
        }
    }
    float2 r = make_float2(0.f, 0.f);
    float wyz[4] = {wyz0, wyz1, wyz2, wyz3};
    #pragma unroll
    for (int k = 0; k < 4; ++k) {
        float wl = ax * wyz[k], wh = wx * wyz[k];
        r.x += wl * lo[k].x + wh * hi[k].x;
        r.y += wl * lo[k].y + wh * hi[k].y;
    }
    return r;
}

// Dense gather on 2x2-xy-quad bf16 tables: one 16B quad = 4 corners at fixed z
// -> E[requests] = 4.5/level/pt vs 6 for pair-packed f32 (K2 is L2-request-bound).
__device__ __forceinline__ unsigned qel(u32x4 q, int sx, int sy) {
    unsigned a = sx ? q[1] : q[0];
    unsigned b = sx ? q[3] : q[2];
    return sy ? b : a;
}

__device__ __forceinline__ float2 gather_q(const unsigned* __restrict__ qt, int R, int nxq,
                                           float X0, float X1, float X2) {
    const float Rm1 = (float)(R - 1);
    float px = X0 * Rm1, py = X1 * Rm1, pz = X2 * Rm1;
    float fx = floorf(px), fy = floorf(py), fz = floorf(pz);
    float wx = px - fx, wy = py - fy, wz = pz - fz;
    int ix = (int)fx, iy = (int)fy, iz = (int)fz;
    ix = max(0, min(ix, R - 1)); iy = max(0, min(iy, R - 1)); iz = max(0, min(iz, R - 1));
    int jx = min(ix + 1, R - 1), jy = min(iy + 1, R - 1), jz = min(iz + 1, R - 1);
    float ax = 1.f - wx, ay = 1.f - wy, az = 1.f - wz;
    const int qx0 = ix >> 1, qy0 = iy >> 1;
    const bool hx = (jx >> 1) != qx0, hy = (jy >> 1) != qy0;
    const int sxi = ix & 1, syi = iy & 1, sxj = jx & 1, syj = jy & 1;
    const float w00 = ax * ay, w10 = wx * ay, w01 = ax * wy, w11 = wx * wy;
    const int zz[2] = {iz, jz};
    float2 pv[2];
    #pragma unroll
    for (int p = 0; p < 2; ++p) {
        const unsigned* base = qt + ((size_t)(zz[p] * nxq + qy0) * nxq + qx0) * 4;
        u32x4 q00 = *(const u32x4*)base;
        u32x4 q10 = q00, q01 = q00, q11;
        if (hx) q10 = *(const u32x4*)(base + 4);
        if (hy) q01 = *(const u32x4*)(base + 4 * nxq);
        if (hx && hy) q11 = *(const u32x4*)(base + 4 * nxq + 4);
        else          q11 = hx ? q10 : q01;
        float2 v00 = upk(qel(q00, sxi, syi));
        float2 v10 = upk(qel(q10, sxj, syi));
        float2 v01 = upk(qel(q01, sxi, syj));
        float2 v11 = upk(qel(q11, sxj, syj));
        pv[p].x = w00 * v00.x + w10 * v10.x + w01 * v01.x + w11 * v11.x;
        pv[p].y = w00 * v00.y + w10 * v10.y + w01 * v01.y + w11 * v11.y;
    }
    return make_float2(az * pv[0].x + wz * pv[1].x, az * pv[0].y + wz * pv[1].y);
}

// quad-table geometry: level l -> (R, nxq=(R+1)/2, quad offset). sizes nxq*nxq*R.
// L0: 8,1024@0  L1: 12,3312@1024  L2: 16,7936@4336  L3: 22,20812@12272  L4: 30,53100@33084
#define QD_TOTAL 86184

// Two-point gather on f32 tables (path-B fallback K1).
__device__ __forceinline__ void gather2(const float* __restrict__ tab, int R,
                                        float x0A, float x1A, float x2A,
                                        float x0B, float x1B, float x2B,
                                        float2& rA, float2& rB) {
    const float Rm1 = (float)(R - 1);
    float wxv[2], axv[2];
    float wyz[2][4];
    float2 lo[2][4], hi[2][4];
    int ixv[2], jxv[2];
    unsigned basev[2][4];
    const bool dense = (long long)R * R * R <= (long long)HMAP;
    #pragma unroll
    for (int t = 0; t < 2; ++t) {
        const float X0 = t ? x0B : x0A, X1 = t ? x1B : x1A, X2 = t ? x2B : x2A;
        float px = X0 * Rm1, py = X1 * Rm1, pz = X2 * Rm1;
        float fx = floorf(px), fy = floorf(py), fz = floorf(pz);
        float wx = px - fx, wy = py - fy, wz = pz - fz;
        int ix = (int)fx, iy = (int)fy, iz = (int)fz;
        ix = max(0, min(ix, R - 1)); iy = max(0, min(iy, R - 1)); iz = max(0, min(iz, R - 1));
        int jx = min(ix + 1, R - 1), jy = min(iy + 1, R - 1), jz = min(iz + 1, R - 1);
        float ax = 1.f - wx, ay = 1.f - wy, az = 1.f - wz;
        wyz[t][0] = ay * az; wyz[t][1] = wy * az; wyz[t][2] = ay * wz; wyz[t][3] = wy * wz;
        wxv[t] = wx; axv[t] = ax; ixv[t] = ix; jxv[t] = jx;
        if (dense) {
            unsigned sy = (unsigned)R, sz = (unsigned)(R * R);
            basev[t][0] = (unsigned)iy * sy + (unsigned)iz * sz;
            basev[t][1] = (unsigned)jy * sy + (unsigned)iz * sz;
            basev[t][2] = (unsigned)iy * sy + (unsigned)jz * sz;
            basev[t][3] = (unsigned)jy * sy + (unsigned)jz * sz;
        } else {
            unsigned hy0 = (unsigned)iy * 2654435761u, hy1 = (unsigned)jy * 2654435761u;
            unsigned hz0 = (unsigned)iz * 805459861u,  hz1 = (unsigned)jz * 805459861u;
            basev[t][0] = hy0 ^ hz0; basev[t][1] = hy1 ^ hz0;
            basev[t][2] = hy0 ^ hz1; basev[t][3] = hy1 ^ hz1;
        }
    }
    if (dense) {
        const float2* t2 = (const float2*)tab;
        #pragma unroll
        for (int t = 0; t < 2; ++t) {
            const bool adj = (jxv[t] == ixv[t] + 1);
            #pragma unroll
            for (int k = 0; k < 4; ++k) {
                unsigned i0 = basev[t][k] + (unsigned)ixv[t];
                if (adj && !(i0 & 1u)) {
                    f32x4 q = *(const f32x4*)(tab + ((size_t)i0 << 1));
                    lo[t][k] = make_float2(q[0], q[1]);
                    hi[t][k] = make_float2(q[2], q[3]);
                } else {
                    lo[t][k] = t2[i0];
                    hi[t][k] = t2[basev[t][k] + (unsigned)jxv[t]];
                }
            }
        }
    } else {
        const float2* t2 = (const float2*)tab;
        #pragma unroll
        for (int t = 0; t < 2; ++t) {
            const bool adj = (jxv[t] == ixv[t] + 1) && ((ixv[t] & 1) == 0);
            #pragma unroll
            for (int k = 0; k < 4; ++k) {
                if (adj) {
                    unsigned h = ((unsigned)ixv[t] ^ basev[t][k]) & HMASK;
                    f32x4 q = *(const f32x4*)(tab + ((size_t)(h & ~1u) << 1));
                    float2 e0 = make_float2(q[0], q[1]);
                    float2 e1 = make_float2(q[2], q[3]);
                    bool sw = (h & 1u) != 0;
                    lo[t][k] = sw ? e1 : e0;
                    hi[t][k] = sw ? e0 : e1;
                } else {
                    unsigned hl = ((unsigned)ixv[t] ^ basev[t][k]) & HMASK;
                    unsigned hh = ((unsigned)jxv[t] ^ basev[t][k]) & HMASK;
                    lo[t][k] = t2[hl];
                    hi[t][k] = t2[hh];
                }
            }
        }
    }
    float2 res[2];
    #pragma unroll
    for (int t = 0; t < 2; ++t) {
        float2 r = make_float2(0.f, 0.f);
        #pragma unroll
        for (int k = 0; k < 4; ++k) {
            float wl = axv[t] * wyz[t][k], wh = wxv[t] * wyz[t][k];
            r.x += wl * lo[t][k].x + wh * hi[t][k].x;
            r.y += wl * lo[t][k].y + wh * hi[t][k].y;
        }
        res[t] = r;
    }
    rA = res[0]; rB = res[1];
}

// Two-point HASHED gather on bf16-pair (u32) tables.
__device__ __forceinline__ void gather2h(const unsigned* __restrict__ tab, int R,
                                         float x0A, float x1A, float x2A,
                                         float x0B, float x1B, float x2B,
                                         float2& rA, float2& rB) {
    const float Rm1 = (float)(R - 1);
    float wxv[2], axv[2], wyz[2][4];
    int ixv[2], jxv[2];
    bool adjv[2];
    unsigned msv[2][4];
    #pragma unroll
    for (int t = 0; t < 2; ++t) {
        const float X0 = t ? x0B : x0A, X1 = t ? x1B : x1A, X2 = t ? x2B : x2A;
        float px = X0 * Rm1, py = X1 * Rm1, pz = X2 * Rm1;
        float fx = floorf(px), fy = floorf(py), fz = floorf(pz);
        float wx = px - fx, wy = py - fy, wz = pz - fz;
        int ix = (int)fx, iy = (int)fy, iz = (int)fz;
        ix = max(0, min(ix, R - 1)); iy = max(0, min(iy, R - 1)); iz = max(0, min(iz, R - 1));
        int jx = min(ix + 1, R - 1), jy = min(iy + 1, R - 1), jz = min(iz + 1, R - 1);
        float ax = 1.f - wx, ay = 1.f - wy, az = 1.f - wz;
        wyz[t][0] = ay * az; wyz[t][1] = wy * az; wyz[t][2] = ay * wz; wyz[t][3] = wy * wz;
        wxv[t] = wx; axv[t] = ax; ixv[t] = ix; jxv[t] = jx;
        adjv[t] = (jx == ix + 1) && ((ix & 1) == 0);
        unsigned hy0 = (unsigned)iy * 2654435761u, hy1 = (unsigned)jy * 2654435761u;
        unsigned hz0 = (unsigned)iz * 805459861u,  hz1 = (unsigned)jz * 805459861u;
        msv[t][0] = hy0 ^ hz0; msv[t][1] = hy1 ^ hz0;
        msv[t][2] = hy0 ^ hz1; msv[t][3] = hy1 ^ hz1;
    }
    float2 lo[2][4], hi[2][4];
    #pragma unroll
    for (int t = 0; t < 2; ++t) {
        #pragma unroll
        for (int k = 0; k < 4; ++k) {
            if (adjv[t]) {
                unsigned h = ((unsigned)ixv[t] ^ msv[t][k]) & HMASK;
                u32x2 q = *(const u32x2*)(tab + (h & ~1u));   // 8B aligned
                float2 e0 = upk(q[0]), e1 = upk(q[1]);
                bool sw = (h & 1u) != 0;
                lo[t][k] = sw ? e1 : e0;
                hi[t][k] = sw ? e0 : e1;
            } else {
                unsigned hl = ((unsigned)ixv[t] ^ msv[t][k]) & HMASK;
                unsigned hh = ((unsigned)jxv[t] ^ msv[t][k]) & HMASK;
                lo[t][k] = upk(tab[hl]);
                hi[t][k] = upk(tab[hh]);
            }
        }
    }
    float2 res[2];
    #pragma unroll
    for (int t = 0; t < 2; ++t) {
        float2 r = make_float2(0.f, 0.f);
        #pragma unroll
        for (int k = 0; k < 4; ++k) {
            float wl = axv[t] * wyz[t][k], wh = wxv[t] * wyz[t][k];
            r.x += wl * lo[t][k].x + wh * hi[t][k].x;
            r.y += wl * lo[t][k].y + wh * hi[t][k].y;
        }
        res[t] = r;
    }
    rA = res[0]; rB = res[1];
}

// =================== Kernel 0a: convert hashed tables (5..15) to bf16 pairs ===================
__global__ __launch_bounds__(256)
void cvt_tables(const float* __restrict__ tables, unsigned* __restrict__ tbf) {
    const size_t i = (size_t)blockIdx.x * 256 + threadIdx.x;   // < 11 * HMAP
    const f32x2* src = (const f32x2*)(tables + (size_t)5 * 2 * HMAP);
    f32x2 f = __builtin_nontemporal_load(src + i);
    unsigned v = (unsigned)f2bf(f[0]) | ((unsigned)f2bf(f[1]) << 16);
    __builtin_nontemporal_store(v, tbf + i);
}

// =================== Kernel 0b: build 2x2-xy-quad bf16 dense tables (levels 0..4) ===================
__global__ __launch_bounds__(256)
void cvt_dense(const float* __restrict__ tables, unsigned* __restrict__ qd) {
    const int i = blockIdx.x * 256 + threadIdx.x;
    if (i >= QD_TOTAL) return;
    int l, R, nx, base;
    if      (i < 1024)  { l = 0; R = 16; nx = 8;  base = 0; }
    else if (i < 4336)  { l = 1; R = 23; nx = 12; base = 1024; }
    else if (i < 12272) { l = 2; R = 31; nx = 16; base = 4336; }
    else if (i < 33084) { l = 3; R = 43; nx = 22; base = 12272; }
    else                { l = 4; R = 59; nx = 30; base = 33084; }
    int lq = i - base;
    int qx = lq % nx; int t = lq / nx; int qy = t % nx; int z = t / nx;
    int x0 = 2 * qx, x1 = min(x0 + 1, R - 1);
    int y0 = 2 * qy, y1 = min(y0 + 1, R - 1);
    const float2* src = (const float2*)(tables + (size_t)l * 2 * HMAP);
    const int zb = R * R * z;
    float2 a = src[x0 + R * y0 + zb];
    float2 b = src[x1 + R * y0 + zb];
    float2 c = src[x0 + R * y1 + zb];
    float2 d = src[x1 + R * y1 + zb];
    u32x4 v;
    v[0] = pkf2(a); v[1] = pkf2(b); v[2] = pkf2(c); v[3] = pkf2(d);
    *(u32x4*)(qd + 4 * (size_t)i) = v;
}

// =================== Kernel 1: hashed-level gather, XCD-balanced (verified 277-280us) ===================
__global__ __launch_bounds__(256, 8)
void gather_hashed(const float* __restrict__ x, const unsigned* __restrict__ tbf,
                   unsigned* __restrict__ feat, int N) {
    const int j = blockIdx.x & 7;
    const int i = blockIdx.x >> 3;
    int level, chunk;
    if (i < 2048) {
        level = 5 + j; chunk = i;
    } else {
        const int r = i - 2048;
        if (j < 3) {
            const int share = (j == 2) ? 682 : 683;
            if (r >= share) return;
            level = 13; chunk = j * 683 + r;
        } else if (j < 6) {
            const int jj = j - 3;
            const int share = (jj == 2) ? 682 : 683;
            if (r >= share) return;
            level = 14; chunk = jj * 683 + r;
        } else {
            if (r >= 1024) return;
            level = 15; chunk = (j - 6) * 1024 + r;
        }
    }
    const size_t p0 = (size_t)chunk * 512 + 2u * threadIdx.x;
    const f32x2* xv = (const f32x2*)(x + 3 * p0);     // 12*p0 bytes, p0 even -> 8B aligned
    f32x2 u0 = __builtin_nontemporal_load(xv);
    f32x2 u1 = __builtin_nontemporal_load(xv + 1);
    f32x2 u2 = __builtin_nontemporal_load(xv + 2);
    float2 fA, fB;
    gather2h(tbf + (size_t)(level - 5) * HMAP, c_res[level],
             u0[0], u0[1], u1[0],
             u1[1], u2[0], u2[1],
             fA, fB);
    u32x2 v;
    v[0] = (unsigned)f2bf(fA.x) | ((unsigned)f2bf(fA.y) << 16);
    v[1] = (unsigned)f2bf(fB.x) | ((unsigned)f2bf(fB.y) << 16);
    __builtin_nontemporal_store(v, (u32x2*)(feat + (size_t)(level - 5) * N + p0));
}

// ======================= Kernel 2: tiled embed + dense gathers + MFMA MLP =======================
// Round-4 structure (W0 in LDS, launch_bounds(256,4) — verified 549us total); the
// only change: dense gathers go through quad tables when qd != nullptr.
#define NPB       128                     // points per tile
#define TILES     8
#define PTS_BLK   (NPB * TILES)           // 1024 points per block
#define SA_STRIDE 104                     // shorts; 208B row stride
#define SW0_OFF   (128 * 104)             // W0 bf16 [64][104], cols 71..95 zero
#define SMEM_SHORTS (SW0_OFF + 64 * 104)  // 39936 B -> 4 blocks/CU

__global__ __launch_bounds__(256, 4)
void mlp_tiled2(const float* __restrict__ x, const float* __restrict__ tables,
                const unsigned* __restrict__ qd, const unsigned* __restrict__ feat,
                const float* __restrict__ W0, const float* __restrict__ b0,
                const float* __restrict__ W1, const float* __restrict__ b1,
                const float* __restrict__ W2, const float* __restrict__ b2,
                float* __restrict__ out, int N) {
    __shared__ unsigned short smem[SMEM_SHORTS];
    const int tid  = threadIdx.x;
    const int blk  = blockIdx.x;
    const int wave = tid >> 6, lane = tid & 63;
    const int mhalf = (wave & 1) * 64;
    const int nhalf = (wave >> 1);
    const int lrow = lane & 15, quad = lane >> 4;

    for (int i = tid; i < 64 * 104; i += 256) {
        int n = i / 104, k = i - n * 104;
        smem[SW0_OFF + i] = (k < 71) ? f2bf(W0[n * 71 + k]) : (unsigned short)0;
    }
    for (int i = tid; i < 128 * 25; i += 256) {
        int p = i / 25, k = i - p * 25;
        smem[p * SA_STRIDE + 71 + k] = 0;
    }
    bf16x8 w1f[2][2];
    #pragma unroll
    for (int ks = 0; ks < 2; ++ks)
        #pragma unroll
        for (int nt = 0; nt < 2; ++nt) {
            int n = nhalf * 32 + nt * 16 + lrow;
            w1f[ks][nt] = cvt8(W1 + n * 64 + ks * 32 + quad * 8);
        }
    bf16x8 w2f[2];
    {
        int n2 = nhalf * 16 + lrow;
        #pragma unroll
        for (int ks = 0; ks < 2; ++ks) {
            if (n2 < 17) w2f[ks] = cvt8(W2 + n2 * 64 + ks * 32 + quad * 8);
            else { bf16x8 z = {0,0,0,0,0,0,0,0}; w2f[ks] = z; }
        }
    }
    float b0v[2], b1v[2], b2v;
    #pragma unroll
    for (int nt = 0; nt < 2; ++nt) {
        b0v[nt] = b0[nhalf * 32 + nt * 16 + lrow];
        b1v[nt] = b1[nhalf * 32 + nt * 16 + lrow];
    }
    { int c2 = nhalf * 16 + lrow; b2v = (c2 < 17) ? b2[c2] : 0.f; }
    __syncthreads();

    const size_t pbase0 = (size_t)blk * PTS_BLK;
    #pragma unroll 1
    for (int t = 0; t < TILES; ++t) {
        const size_t pb = pbase0 + (size_t)t * NPB;
        {
            const int p = tid & 127;
            const size_t gp = pb + p;
            unsigned short* row = &smem[p * SA_STRIDE];
            const float x0 = __builtin_nontemporal_load(x + 3 * gp);
            const float x1 = __builtin_nontemporal_load(x + 3 * gp + 1);
            const float x2 = __builtin_nontemporal_load(x + 3 * gp + 2);
            // sin/cos of x*2^m via one sincos + double-angle recurrence
            float sa, ca, sb, cb, sc, cc;
            __sincosf(x0, &sa, &ca);
            __sincosf(x1, &sb, &cb);
            __sincosf(x2, &sc, &cc);
            if (tid < 128) {
                row[0] = f2bf(x0); row[1] = f2bf(x1); row[2] = f2bf(x2);
                #pragma unroll
                for (int m = 0; m < 6; ++m) {
                    row[3 + 6 * m + 0] = f2bf(sa);
                    row[3 + 6 * m + 1] = f2bf(sb);
                    row[3 + 6 * m + 2] = f2bf(sc);
                    float nsa = 2.f * sa * ca, nca = 1.f - 2.f * sa * sa;
                    float nsb = 2.f * sb * cb, ncb = 1.f - 2.f * sb * sb;
                    float nsc = 2.f * sc * cc, ncc = 1.f - 2.f * sc * sc;
                    sa = nsa; ca = nca; sb = nsb; cb = ncb; sc = nsc; cc = ncc;
                }
                float2 f;
                if (qd) {
                    f = gather_q(qd,              16,  8, x0, x1, x2);
                    row[39] = f2bf(f.x); row[40] = f2bf(f.y);
                    f = gather_q(qd + 4 * 1024,   23, 12, x0, x1, x2);
                    row[41] = f2bf(f.x); row[42] = f2bf(f.y);
                    f = gather_q(qd + 4 * 4336,   31, 16, x0, x1, x2);
                    row[43] = f2bf(f.x); row[44] = f2bf(f.y);
                } else {
                    f = gather_level(tables,                        16, x0, x1, x2);
                    row[39] = f2bf(f.x); row[40] = f2bf(f.y);
                    f = gather_level(tables + (size_t)1 * 2 * HMAP, 23, x0, x1, x2);
                    row[41] = f2bf(f.x); row[42] = f2bf(f.y);
                    f = gather_level(tables + (size_t)2 * 2 * HMAP, 31, x0, x1, x2);
                    row[43] = f2bf(f.x); row[44] = f2bf(f.y);
                }
            } else {
                #pragma unroll
                for (int m = 0; m < 6; ++m) {
                    row[3 + 6 * m + 3] = f2bf(ca);
                    row[3 + 6 * m + 4] = f2bf(cb);
                    row[3 + 6 * m + 5] = f2bf(cc);
                    float nsa = 2.f * sa * ca, nca = 1.f - 2.f * sa * sa;
                    float nsb = 2.f * sb * cb, ncb = 1.f - 2.f * sb * sb;
                    float nsc = 2.f * sc * cc, ncc = 1.f - 2.f * sc * sc;
                    sa = nsa; ca = nca; sb = nsb; cb = ncb; sc = nsc; cc = ncc;
                }
                float2 f;
                if (qd) {
                    f = gather_q(qd + 4 * 12272,  43, 22, x0, x1, x2);
                    row[45] = f2bf(f.x); row[46] = f2bf(f.y);
                    f = gather_q(qd + 4 * 33084,  59, 30, x0, x1, x2);
                    row[47] = f2bf(f.x); row[48] = f2bf(f.y);
                } else {
                    f = gather_level(tables + (size_t)3 * 2 * HMAP, 43, x0, x1, x2);
                    row[45] = f2bf(f.x); row[46] = f2bf(f.y);
                    f = gather_level(tables + (size_t)4 * 2 * HMAP, 59, x0, x1, x2);
                    row[47] = f2bf(f.x); row[48] = f2bf(f.y);
                }
                #pragma unroll
                for (int li = 0; li < 11; ++li) {
                    unsigned v = __builtin_nontemporal_load(feat + (size_t)li * N + gp);
                    row[49 + 2 * li] = (unsigned short)(v & 0xffffu);
                    row[50 + 2 * li] = (unsigned short)(v >> 16);
                }
            }
        }
        __syncthreads();

        f32x4 acc0[4][2];
        #pragma unroll
        for (int mt = 0; mt < 4; ++mt)
            #pragma unroll
            for (int nt = 0; nt < 2; ++nt) acc0[mt][nt] = (f32x4){0.f, 0.f, 0.f, 0.f};
        #pragma unroll
        for (int ks = 0; ks < 3; ++ks) {
            bf16x8 bfr[2];
            #pragma unroll
            for (int nt = 0; nt < 2; ++nt) {
                int n = nhalf * 32 + nt * 16 + lrow;
                bfr[nt] = *(const bf16x8*)&smem[SW0_OFF + n * 104 + ks * 32 + quad * 8];
            }
            #pragma unroll
            for (int mt = 0; mt < 4; ++mt) {
                int m = mhalf + mt * 16 + lrow;
                bf16x8 afr = *(const bf16x8*)&smem[m * SA_STRIDE + ks * 32 + quad * 8];
                #pragma unroll
                for (int nt = 0; nt < 2; ++nt)
                    acc0[mt][nt] = __builtin_amdgcn_mfma_f32_16x16x32_bf16(afr, bfr[nt], acc0[mt][nt], 0, 0, 0);
            }
        }
        __syncthreads();
        #pragma unroll
        for (int mt = 0; mt < 4; ++mt)
            #pragma unroll
            for (int nt = 0; nt < 2; ++nt) {
                int colg = nhalf * 32 + nt * 16 + lrow;
                #pragma unroll
                for (int r = 0; r < 4; ++r) {
                    int rowm = mhalf + mt * 16 + quad * 4 + r;
                    smem[rowm * SA_STRIDE + colg] = f2bf(softplus100(acc0[mt][nt][r] + b0v[nt]));
                }
            }
        __syncthreads();

        f32x4 acc1[4][2];
        #pragma unroll
        for (int mt = 0; mt < 4; ++mt)
            #pragma unroll
            for (int nt = 0; nt < 2; ++nt) acc1[mt][nt] = (f32x4){0.f, 0.f, 0.f, 0.f};
        #pragma unroll
        for (int ks = 0; ks < 2; ++ks) {
            #pragma unroll
            for (int mt = 0; mt < 4; ++mt) {
                int m = mhalf + mt * 16 + lrow;
                bf16x8 afr = *(const bf16x8*)&smem[m * SA_STRIDE + ks * 32 + quad * 8];
                #pragma unroll
                for (int nt = 0; nt < 2; ++nt)
                    acc1[mt][nt] = __builtin_amdgcn_mfma_f32_16x16x32_bf16(afr, w1f[ks][nt], acc1[mt][nt], 0, 0, 0);
            }
        }
        __syncthreads();
        #pragma unroll
        for (int mt = 0; mt < 4; ++mt)
            #pragma unroll
            for (int nt = 0; nt < 2; ++nt) {
                int colg = nhalf * 32 + nt * 16 + lrow;
                #pragma unroll
                for (int r = 0; r < 4; ++r) {
                    int rowm = mhalf + mt * 16 + quad * 4 + r;
                    smem[rowm * SA_STRIDE + colg] = f2bf(softplus100(acc1[mt][nt][r] + b1v[nt]));
                }
            }
        __syncthreads();

        f32x4 acc2[4];
        #pragma unroll
        for (int mt = 0; mt < 4; ++mt) acc2[mt] = (f32x4){0.f, 0.f, 0.f, 0.f};
        #pragma unroll
        for (int ks = 0; ks < 2; ++ks) {
            #pragma unroll
            for (int mt = 0; mt < 4; ++mt) {
                int m = mhalf + mt * 16 + lrow;
                bf16x8 afr = *(const bf16x8*)&smem[m * SA_STRIDE + ks * 32 + quad * 8];
                acc2[mt] = __builtin_amdgcn_mfma_f32_16x16x32_bf16(afr, w2f[ks], acc2[mt], 0, 0, 0);
            }
        }
        {
            int colg = nhalf * 16 + lrow;
            if (colg < 17) {
                #pragma unroll
                for (int mt = 0; mt < 4; ++mt)
                    #pragma unroll
                    for (int r = 0; r < 4; ++r) {
                        int rowm = mhalf + mt * 16 + quad * 4 + r;
                        __builtin_nontemporal_store(acc2[mt][r] + b2v,
                                                    out + (pb + rowm) * 17 + colg);
                    }
            }
        }
        __syncthreads();
    }
}

// ======================= Path B (verified round-3 kernels) =======================
__global__ __launch_bounds__(256, 6)
void gather_levels(const float* __restrict__ x, const float* __restrict__ tables,
                   unsigned* __restrict__ feat, int N, int C) {
    const int b = blockIdx.x;
    const int half = 8 * C;
    int r, level;
    if (b < half) { r = b; level = r & 7; }
    else          { r = b - half; level = 15 - (r & 7); }
    const size_t p0 = (size_t)(r >> 3) * 512 + 2u * threadIdx.x;
    const f32x2* xv = (const f32x2*)(x + 3 * p0);
    f32x2 u0 = __builtin_nontemporal_load(xv);
    f32x2 u1 = __builtin_nontemporal_load(xv + 1);
    f32x2 u2 = __builtin_nontemporal_load(xv + 2);
    float2 fA, fB;
    gather2(tables + (size_t)level * (2u * HMAP), c_res[level],
            u0[0], u0[1], u1[0],
            u1[1], u2[0], u2[1],
            fA, fB);
    u32x2 v;
    v[0] = (unsigned)f2bf(fA.x) | ((unsigned)f2bf(fA.y) << 16);
    v[1] = (unsigned)f2bf(fB.x) | ((unsigned)f2bf(fB.y) << 16);
    __builtin_nontemporal_store(v, (u32x2*)(feat + (size_t)level * N + p0));
}

__global__ __launch_bounds__(256, 4)
void mlp_tiled(const float* __restrict__ x, const unsigned* __restrict__ feat,
               const float* __restrict__ W0, const float* __restrict__ b0,
               const float* __restrict__ W1, const float* __restrict__ b1,
               const float* __restrict__ W2, const float* __restrict__ b2,
               float* __restrict__ out, int N) {
    __shared__ unsigned short smem[SMEM_SHORTS];
    const int tid  = threadIdx.x;
    const int blk  = blockIdx.x;
    const int wave = tid >> 6, lane = tid & 63;
    const int mhalf = (wave & 1) * 64;
    const int nhalf = (wave >> 1);
    const int lrow = lane & 15, quad = lane >> 4;

    for (int i = tid; i < 64 * 104; i += 256) {
        int n = i / 104, k = i - n * 104;
        smem[SW0_OFF + i] = (k < 71) ? f2bf(W0[n * 71 + k]) : (unsigned short)0;
    }
    for (int i = tid; i < 128 * 25; i += 256) {
        int p = i / 25, k = i - p * 25;
        smem[p * SA_STRIDE + 71 + k] = 0;
    }
    bf16x8 w1f[2][2];
    #pragma unroll
    for (int ks = 0; ks < 2; ++ks)
        #pragma unroll
        for (int nt = 0; nt < 2; ++nt) {
            int n = nhalf * 32 + nt * 16 + lrow;
            w1f[ks][nt] = cvt8(W1 + n * 64 + ks * 32 + quad * 8);
        }
    bf16x8 w2f[2];
    {
        int n2 = nhalf * 16 + lrow;
        #pragma unroll
        for (int ks = 0; ks < 2; ++ks) {
            if (n2 < 17) w2f[ks] = cvt8(W2 + n2 * 64 + ks * 32 + quad * 8);
            else { bf16x8 z = {0,0,0,0,0,0,0,0}; w2f[ks] = z; }
        }
    }
    float b0v[2], b1v[2], b2v;
    #pragma unroll
    for (int nt = 0; nt < 2; ++nt) {
        b0v[nt] = b0[nhalf * 32 + nt * 16 + lrow];
        b1v[nt] = b1[nhalf * 32 + nt * 16 + lrow];
    }
    { int c2 = nhalf * 16 + lrow; b2v = (c2 < 17) ? b2[c2] : 0.f; }
    __syncthreads();

    const size_t pbase0 = (size_t)blk * PTS_BLK;
    #pragma unroll 1
    for (int t = 0; t < TILES; ++t) {
        const size_t pb = pbase0 + (size_t)t * NPB;
        {
            const int p = tid & 127;
            const size_t gp = pb + p;
            unsigned short* row = &smem[p * SA_STRIDE];
            const float x0 = __builtin_nontemporal_load(x + 3 * gp);
            const float x1 = __builtin_nontemporal_load(x + 3 * gp + 1);
            const float x2 = __builtin_nontemporal_load(x + 3 * gp + 2);
            if (tid < 128) {
                row[0] = f2bf(x0); row[1] = f2bf(x1); row[2] = f2bf(x2);
                float fr = 1.f;
                #pragma unroll
                for (int m = 0; m < 6; ++m) {
                    row[3 + 6 * m + 0] = f2bf(__sinf(x0 * fr));
                    row[3 + 6 * m + 1] = f2bf(__sinf(x1 * fr));
                    row[3 + 6 * m + 2] = f2bf(__sinf(x2 * fr));
                    fr *= 2.f;
                }
            } else {
                float fr = 1.f;
                #pragma unroll
                for (int m = 0; m < 6; ++m) {
                    row[3 + 6 * m + 3] = f2bf(__cosf(x0 * fr));
                    row[3 + 6 * m + 4] = f2bf(__cosf(x1 * fr));
                    row[3 + 6 * m + 5] = f2bf(__cosf(x2 * fr));
                    fr *= 2.f;
                }
                #pragma unroll
                for (int l = 0; l < 16; ++l) {
                    unsigned v = __builtin_nontemporal_load(feat + (size_t)l * N + gp);
                    row[39 + 2 * l] = (unsigned short)(v & 0xffffu);
                    row[40 + 2 * l] = (unsigned short)(v >> 16);
                }
            }
        }
        __syncthreads();

        f32x4 acc0[4][2];
        #pragma unroll
        for (int mt = 0; mt < 4; ++mt)
            #pragma unroll
            for (int nt = 0; nt < 2; ++nt) acc0[mt][nt] = (f32x4){0.f, 0.f, 0.f, 0.f};
        #pragma unroll
        for (int ks = 0; ks < 3; ++ks) {
            bf16x8 bfr[2];
            #pragma unroll
            for (int nt = 0; nt < 2; ++nt) {
                int n = nhalf * 32 + nt * 16 + lrow;
                bfr[nt] = *(const bf16x8*)&smem[SW0_OFF + n * 104 + ks * 32 + quad * 8];
            }
            #pragma unroll
            for (int mt = 0; mt < 4; ++mt) {
                int m = mhalf + mt * 16 + lrow;
                bf16x8 afr = *(const bf16x8*)&smem[m * SA_STRIDE + ks * 32 + quad * 8];
                #pragma unroll
                for (int nt = 0; nt < 2; ++nt)
                    acc0[mt][nt] = __builtin_amdgcn_mfma_f32_16x16x32_bf16(afr, bfr[nt], acc0[mt][nt], 0, 0, 0);
            }
        }
        __syncthreads();
        #pragma unroll
        for (int mt = 0; mt < 4; ++mt)
            #pragma unroll
            for (int nt = 0; nt < 2; ++nt) {
                int colg = nhalf * 32 + nt * 16 + lrow;
                #pragma unroll
                for (int r = 0; r < 4; ++r) {
                    int rowm = mhalf + mt * 16 + quad * 4 + r;
                    smem[rowm * SA_STRIDE + colg] = f2bf(softplus100(acc0[mt][nt][r] + b0v[nt]));
                }
            }
        __syncthreads();

        f32x4 acc1[4][2];
        #pragma unroll
        for (int mt = 0; mt < 4; ++mt)
            #pragma unroll
            for (int nt = 0; nt < 2; ++nt) acc1[mt][nt] = (f32x4){0.f, 0.f, 0.f, 0.f};
        #pragma unroll
        for (int ks = 0; ks < 2; ++ks) {
            #pragma unroll
            for (int mt = 0; mt < 4; ++mt) {
                int m = mhalf + mt * 16 + lrow;
                bf16x8 afr = *(const bf16x8*)&smem[m * SA_STRIDE + ks * 32 + quad * 8];
                #pragma unroll
                for (int nt = 0; nt < 2; ++nt)
                    acc1[mt][nt] = __builtin_amdgcn_mfma_f32_16x16x32_bf16(afr, w1f[ks][nt], acc1[mt][nt], 0, 0, 0);
            }
        }
        __syncthreads();
        #pragma unroll
        for (int mt = 0; mt < 4; ++mt)
            #pragma unroll
            for (int nt = 0; nt < 2; ++nt) {
                int colg = nhalf * 32 + nt * 16 + lrow;
                #pragma unroll
                for (int r = 0; r < 4; ++r) {
                    int rowm = mhalf + mt * 16 + quad * 4 + r;
                    smem[rowm * SA_STRIDE + colg] = f2bf(softplus100(acc1[mt][nt][r] + b1v[nt]));
                }
            }
        __syncthreads();

        f32x4 acc2[4];
        #pragma unroll
        for (int mt = 0; mt < 4; ++mt) acc2[mt] = (f32x4){0.f, 0.f, 0.f, 0.f};
        #pragma unroll
        for (int ks = 0; ks < 2; ++ks) {
            #pragma unroll
            for (int mt = 0; mt < 4; ++mt) {
                int m = mhalf + mt * 16 + lrow;
                bf16x8 afr = *(const bf16x8*)&smem[m * SA_STRIDE + ks * 32 + quad * 8];
                acc2[mt] = __builtin_amdgcn_mfma_f32_16x16x32_bf16(afr, w2f[ks], acc2[mt], 0, 0, 0);
            }
        }
        {
            int colg = nhalf * 16 + lrow;
            if (colg < 17) {
                #pragma unroll
                for (int mt = 0; mt < 4; ++mt)
                    #pragma unroll
                    for (int r = 0; r < 4; ++r) {
                        int rowm = mhalf + mt * 16 + quad * 4 + r;
                        __builtin_nontemporal_store(acc2[mt][r] + b2v,
                                                    out + (pb + rowm) * 17 + colg);
                    }
            }
        }
        __syncthreads();
    }
}

// ======================= Fallback (ws too small): fully fused =======================
__global__ __launch_bounds__(256, 3)
void gn_fused(const float* __restrict__ x, const float* __restrict__ tables,
              const float* __restrict__ W0, const float* __restrict__ b0,
              const float* __restrict__ W1, const float* __restrict__ b1,
              const float* __restrict__ W2, const float* __restrict__ b2,
              float* __restrict__ out) {
    __shared__ unsigned short smem[SMEM_SHORTS];
    const int tid = threadIdx.x;
    const int blk = blockIdx.x;
    const int wave = tid >> 6, lane = tid & 63;
    const int mhalf = (wave & 1) * 64;
    const int nhalf = (wave >> 1);
    const int lrow = lane & 15, quad = lane >> 4;
    for (int i = tid; i < 64 * 104; i += 256) {
        int n = i / 104, k = i - n * 104;
        smem[SW0_OFF + i] = (k < 71) ? f2bf(W0[n * 71 + k]) : (unsigned short)0;
    }
    for (int i = tid; i < 128 * 25; i += 256) {
        int p = i / 25, k = i - p * 25;
        smem[p * SA_STRIDE + 71 + k] = 0;
    }
    bf16x8 w1f[2][2];
    #pragma unroll
    for (int ks = 0; ks < 2; ++ks)
        #pragma unroll
        for (int nt = 0; nt < 2; ++nt) {
            int n = nhalf * 32 + nt * 16 + lrow;
            w1f[ks][nt] = cvt8(W1 + n * 64 + ks * 32 + quad * 8);
        }
    bf16x8 w2f[2];
    {
        int n2 = nhalf * 16 + lrow;
        #pragma unroll
        for (int ks = 0; ks < 2; ++ks) {
            if (n2 < 17) w2f[ks] = cvt8(W2 + n2 * 64 + ks * 32 + quad * 8);
            else { bf16x8 z = {0,0,0,0,0,0,0,0}; w2f[ks] = z; }
        }
    }
    float b0v[2], b1v[2], b2v;
    #pragma unroll
    for (int nt = 0; nt < 2; ++nt) {
        b0v[nt] = b0[nhalf * 32 + nt * 16 + lrow];
        b1v[nt] = b1[nhalf * 32 + nt * 16 + lrow];
    }
    { int c2 = nhalf * 16 + lrow; b2v = (c2 < 17) ? b2[c2] : 0.f; }
    {
        const int p = tid & 127;
        const size_t gp = (size_t)blk * NPB + p;
        const float x0 = x[3 * gp], x1 = x[3 * gp + 1], x2 = x[3 * gp + 2];
        unsigned short* row = &smem[p * SA_STRIDE];
        if (tid < 128) {
            row[0] = f2bf(x0); row[1] = f2bf(x1); row[2] = f2bf(x2);
            float fr = 1.f;
            #pragma unroll
            for (int m = 0; m < 6; ++m) {
                row[3 + 6 * m + 0] = f2bf(__sinf(x0 * fr));
                row[3 + 6 * m + 1] = f2bf(__sinf(x1 * fr));
                row[3 + 6 * m + 2] = f2bf(__sinf(x2 * fr));
                fr *= 2.f;
            }
            #pragma unroll
            for (int li = 0; li < 8; ++li) {
                const int l = 2 * li;
                float2 f = gather_level(tables + (size_t)l * (2u * HMAP), c_res[l], x0, x1, x2);
                row[39 + 2 * l] = f2bf(f.x);
                row[40 + 2 * l] = f2bf(f.y);
            }
        } else {
            float fr = 1.f;
            #pragma unroll
            for (int m = 0; m < 6; ++m) {
                row[3 + 6 * m + 3] = f2bf(__cosf(x0 * fr));
                row[3 + 6 * m + 4] = f2bf(__cosf(x1 * fr));
                row[3 + 6 * m + 5] = f2bf(__cosf(x2 * fr));
                fr *= 2.f;
            }
            #pragma unroll
            for (int li = 0; li < 8; ++li) {
                const int l = 2 * li + 1;
                float2 f = gather_level(tables + (size_t)l * (2u * HMAP), c_res[l], x0, x1, x2);
                row[39 + 2 * l] = f2bf(f.x);
                row[40 + 2 * l] = f2bf(f.y);
            }
        }
    }
    __syncthreads();
    f32x4 acc0[4][2];
    #pragma unroll
    for (int mt = 0; mt < 4; ++mt)
        #pragma unroll
        for (int nt = 0; nt < 2; ++nt) acc0[mt][nt] = (f32x4){0.f, 0.f, 0.f, 0.f};
    #pragma unroll
    for (int ks = 0; ks < 3; ++ks) {
        bf16x8 bfr[2];
        #pragma unroll
        for (int nt = 0; nt < 2; ++nt) {
            int n = nhalf * 32 + nt * 16 + lrow;
            bfr[nt] = *(const bf16x8*)&smem[SW0_OFF + n * 104 + ks * 32 + quad * 8];
        }
        #pragma unroll
        for (int mt = 0; mt < 4; ++mt) {
            int m = mhalf + mt * 16 + lrow;
            bf16x8 afr = *(const bf16x8*)&smem[m * SA_STRIDE + ks * 32 + quad * 8];
            #pragma unroll
            for (int nt = 0; nt < 2; ++nt)
                acc0[mt][nt] = __builtin_amdgcn_mfma_f32_16x16x32_bf16(afr, bfr[nt], acc0[mt][nt], 0, 0, 0);
        }
    }
    __syncthreads();
    #pragma unroll
    for (int mt = 0; mt < 4; ++mt)
        #pragma unroll
        for (int nt = 0; nt < 2; ++nt) {
            int colg = nhalf * 32 + nt * 16 + lrow;
            #pragma unroll
            for (int r = 0; r < 4; ++r) {
                int rowm = mhalf + mt * 16 + quad * 4 + r;
                smem[rowm * SA_STRIDE + colg] = f2bf(softplus100(acc0[mt][nt][r] + b0v[nt]));
            }
        }
    __syncthreads();
    f32x4 acc1[4][2];
    #pragma unroll
    for (int mt = 0; mt < 4; ++mt)
        #pragma unroll
        for (int nt = 0; nt < 2; ++nt) acc1[mt][nt] = (f32x4){0.f, 0.f, 0.f, 0.f};
    #pragma unroll
    for (int ks = 0; ks < 2; ++ks) {
        #pragma unroll
        for (int mt = 0; mt < 4; ++mt) {
            int m = mhalf + mt * 16 + lrow;
            bf16x8 afr = *(const bf16x8*)&smem[m * SA_STRIDE + ks * 32 + quad * 8];
            #pragma unroll
            for (int nt = 0; nt < 2; ++nt)
                acc1[mt][nt] = __builtin_amdgcn_mfma_f32_16x16x32_bf16(afr, w1f[ks][nt], acc1[mt][nt], 0, 0, 0);
        }
    }
    __syncthreads();
    #pragma unroll
    for (int mt = 0; mt < 4; ++mt)
        #pragma unroll
        for (int nt = 0; nt < 2; ++nt) {
            int colg = nhalf * 32 + nt * 16 + lrow;
            #pragma unroll
            for (int r = 0; r < 4; ++r) {
                int rowm = mhalf + mt * 16 + quad * 4 + r;
                smem[rowm * SA_STRIDE + colg] = f2bf(softplus100(acc1[mt][nt][r] + b1v[nt]));
            }
        }
    __syncthreads();
    f32x4 acc2[4];
    #pragma unroll
    for (int mt = 0; mt < 4; ++mt) acc2[mt] = (f32x4){0.f, 0.f, 0.f, 0.f};
    #pragma unroll
    for (int ks = 0; ks < 2; ++ks) {
        #pragma unroll
        for (int mt = 0; mt < 4; ++mt) {
            int m = mhalf + mt * 16 + lrow;
            bf16x8 afr = *(const bf16x8*)&smem[m * SA_STRIDE + ks * 32 + quad * 8];
            acc2[mt] = __builtin_amdgcn_mfma_f32_16x16x32_bf16(afr, w2f[ks], acc2[mt], 0, 0, 0);
        }
    }
    {
        int colg = nhalf * 16 + lrow;
        if (colg < 17) {
            #pragma unroll
            for (int mt = 0; mt < 4; ++mt)
                #pragma unroll
                for (int r = 0; r < 4; ++r) {
                    int rowm = mhalf + mt * 16 + quad * 4 + r;
                    out[((size_t)blk * NPB + rowm) * 17 + colg] = acc2[mt][r] + b2v;
                }
        }
    }
}

extern "C" void kernel_launch(void* const* d_in, const int* in_sizes, int n_in,
                              void* d_out, int out_size, void* d_ws, size_t ws_size,
                              hipStream_t stream) {
    const float* x      = (const float*)d_in[0];
    const float* tables = (const float*)d_in[1];
    const float* W0     = (const float*)d_in[2];
    const float* b0     = (const float*)d_in[3];
    const float* W1     = (const float*)d_in[4];
    const float* b1     = (const float*)d_in[5];
    const float* W2     = (const float*)d_in[6];
    const float* b2     = (const float*)d_in[7];
    float* out = (float*)d_out;
    const int n = in_sizes[0] / 3;                           // 1048576
    const size_t featA_b = (size_t)11 * n * 4;               // 44 MB hashed feat staging
    const size_t tbf_b   = (size_t)11 * HMAP * 4;            // 22 MB bf16 hashed tables
    const size_t qd_b    = (size_t)QD_TOTAL * 16;            // 1.38 MB quad dense tables
    const size_t wsB     = (size_t)16 * n * 4;               // 64 MB (path B)
    if (n == (1 << 20) && ws_size >= featA_b + tbf_b + qd_b) {
        unsigned* feat = (unsigned*)d_ws;
        unsigned* tbf  = (unsigned*)((char*)d_ws + featA_b);
        unsigned* qd   = (unsigned*)((char*)d_ws + featA_b + tbf_b);
        cvt_tables<<<dim3(11 * HMAP / 256), dim3(256), 0, stream>>>(tables, tbf);
        cvt_dense<<<dim3((QD_TOTAL + 255) / 256), dim3(256), 0, stream>>>(tables, qd);
        gather_hashed<<<dim3(8 * 3072), dim3(256), 0, stream>>>(x, tbf, feat, n);
        mlp_tiled2<<<dim3(n / PTS_BLK), dim3(256), 0, stream>>>(x, tables, qd, feat, W0, b0, W1, b1, W2, b2, out, n);
    } else if (n == (1 << 20) && ws_size >= featA_b + tbf_b) {
        unsigned* feat = (unsigned*)d_ws;
        unsigned* tbf  = (unsigned*)((char*)d_ws + featA_b);
        cvt_tables<<<dim3(11 * HMAP / 256), dim3(256), 0, stream>>>(tables, tbf);
        gather_hashed<<<dim3(8 * 3072), dim3(256), 0, stream>>>(x, tbf, feat, n);
        mlp_tiled2<<<dim3(n / PTS_BLK), dim3(256), 0, stream>>>(x, tables, (const unsigned*)nullptr, feat, W0, b0, W1, b1, W2, b2, out, n);
    } else if (ws_size >= wsB) {
        unsigned* feat = (unsigned*)d_ws;
        const int C = n / 512;
        gather_levels<<<dim3(16 * C), dim3(256), 0, stream>>>(x, tables, feat, n, C);
        mlp_tiled<<<dim3(n / PTS_BLK), dim3(256), 0, stream>>>(x, feat, W0, b0, W1, b1, W2, b2, out, n);
    } else {
        gn_fused<<<dim3(n / NPB), dim3(256), 0, stream>>>(x, tables, W0, b0, W1, b1, W2, b2, out);
    }
}

// Round 8
// 554.592 us; speedup vs baseline: 1.2997x; 1.0003x over previous
//
#include <hip/hip_runtime.h>
#include <stdint.h>

#define HMAP   (1u << 19)
#define HMASK  (HMAP - 1u)

typedef short bf16x8 __attribute__((ext_vector_type(8)));
typedef float f32x4  __attribute__((ext_vector_type(4)));
typedef float f32x2  __attribute__((ext_vector_type(2)));
typedef unsigned u32x2 __attribute__((ext_vector_type(2)));

// resolutions: ceil(16 * 2^(7l/15)); dense (R^3 <= 2^19) for levels 0..4
__device__ __constant__ const int c_res[16] = {16, 23, 31, 43, 59, 81, 112, 154, 213, 295, 407, 562, 777, 1073, 1483, 2048};

__device__ __forceinline__ unsigned short f2bf(float f) {
    unsigned u = __float_as_uint(f);
    u += 0x7fffu + ((u >> 16) & 1u);           // round-to-nearest-even
    return (unsigned short)(u >> 16);
}

// Exactly matches where(100v>20, v, log1p(exp(100v))/100):
__device__ __forceinline__ float softplus100(float v) {
    return fmaxf(v, 0.f) + 0.01f * __logf(1.f + __expf(-100.f * fabsf(v)));
}

__device__ __forceinline__ bf16x8 cvt8(const float* __restrict__ p) {
    f32x4 a = *(const f32x4*)p;
    f32x4 b = *(const f32x4*)(p + 4);
    bf16x8 r;
    r[0] = f2bf(a[0]); r[1] = f2bf(a[1]); r[2] = f2bf(a[2]); r[3] = f2bf(a[3]);
    r[4] = f2bf(b[0]); r[5] = f2bf(b[1]); r[6] = f2bf(b[2]); r[7] = f2bf(b[3]);
    return r;
}

__device__ __forceinline__ float2 upk(unsigned v) {   // bf16 pair -> f32 pair (exact)
    return make_float2(__uint_as_float(v << 16), __uint_as_float(v & 0xffff0000u));
}

// Single-point trilinear gather on f32 tables (dense levels + fallbacks).
__device__ __forceinline__ float2 gather_level(const float* __restrict__ tab, int R,
                                               float x0, float x1, float x2) {
    const float Rm1 = (float)(R - 1);
    float px = x0 * Rm1, py = x1 * Rm1, pz = x2 * Rm1;
    float fx = floorf(px), fy = floorf(py), fz = floorf(pz);
    float wx = px - fx, wy = py - fy, wz = pz - fz;
    int ix = (int)fx, iy = (int)fy, iz = (int)fz;
    ix = max(0, min(ix, R - 1)); iy = max(0, min(iy, R - 1)); iz = max(0, min(iz, R - 1));
    int jx = min(ix + 1, R - 1), jy = min(iy + 1, R - 1), jz = min(iz + 1, R - 1);
    float ax = 1.f - wx, ay = 1.f - wy, az = 1.f - wz;
    float wyz0 = ay * az, wyz1 = wy * az, wyz2 = ay * wz, wyz3 = wy * wz;
    float2 lo[4], hi[4];
    const bool adj = (jx == ix + 1);
    if ((long long)R * R * R <= (long long)HMAP) {   // dense
        unsigned sy = (unsigned)R, sz = (unsigned)(R * R);
        unsigned bases[4] = {(unsigned)iy * sy + (unsigned)iz * sz,
                             (unsigned)jy * sy + (unsigned)iz * sz,
                             (unsigned)iy * sy + (unsigned)jz * sz,
                             (unsigned)jy * sy + (unsigned)jz * sz};
        const float2* t2 = (const float2*)tab;
        #pragma unroll
        for (int k = 0; k < 4; ++k) {
            unsigned i0 = bases[k] + (unsigned)ix;
            if (adj && !(i0 & 1u)) {
                f32x4 q = *(const f32x4*)(tab + ((size_t)i0 << 1));
                lo[k] = make_float2(q[0], q[1]);
                hi[k] = make_float2(q[2], q[3]);
            } else {
                lo[k] = t2[i0];
                hi[k] = t2[bases[k] + (unsigned)jx];
            }
        }
    } else {                                          // hashed
        unsigned hy0 = (unsigned)iy * 2654435761u, hy1 = (unsigned)jy * 2654435761u;
        unsigned hz0 = (unsigned)iz * 805459861u,  hz1 = (unsigned)jz * 805459861u;
        unsigned ms[4] = {hy0 ^ hz0, hy1 ^ hz0, hy0 ^ hz1, hy1 ^ hz1};
        if (adj && ((ix & 1) == 0)) {
            #pragma unroll
            for (int k = 0; k < 4; ++k) {
                unsigned h = ((unsigned)ix ^ ms[k]) & HMASK;
                f32x4 q = *(const f32x4*)(tab + ((size_t)(h & ~1u) << 1));
                float2 e0 = make_float2(q[0], q[1]);
                float2 e1 = make_float2(q[2], q[3]);
                bool sw = (h & 1u) != 0;
                lo[k] = sw ? e1 : e0;
                hi[k] = sw ? e0 : e1;
            }
        } else {
            const float2* t2 = (const float2*)tab;
            #pragma unroll
            for (int k = 0; k < 4; ++k) {
                unsigned hl = ((unsigned)ix ^ ms[k]) & HMASK;
                unsigned hh = ((unsigned)jx ^ ms[k]) & HMASK;
                lo[k] = t2[hl];
                hi[k] = t2[hh];
            }
        }
    }
    float2 r = make_float2(0.f, 0.f);
    float wyz[4] = {wyz0, wyz1, wyz2, wyz3};
    #pragma unroll
    for (int k = 0; k < 4; ++k) {
        float wl = ax * wyz[k], wh = wx * wyz[k];
        r.x += wl * lo[k].x + wh * hi[k].x;
        r.y += wl * lo[k].y + wh * hi[k].y;
    }
    return r;
}

// Two-point gather on f32 tables (path-B fallback K1).
__device__ __forceinline__ void gather2(const float* __restrict__ tab, int R,
                                        float x0A, float x1A, float x2A,
                                        float x0B, float x1B, float x2B,
                                        float2& rA, float2& rB) {
    const float Rm1 = (float)(R - 1);
    float wxv[2], axv[2];
    float wyz[2][4];
    float2 lo[2][4], hi[2][4];
    int ixv[2], jxv[2];
    unsigned basev[2][4];
    const bool dense = (long long)R * R * R <= (long long)HMAP;
    #pragma unroll
    for (int t = 0; t < 2; ++t) {
        const float X0 = t ? x0B : x0A, X1 = t ? x1B : x1A, X2 = t ? x2B : x2A;
        float px = X0 * Rm1, py = X1 * Rm1, pz = X2 * Rm1;
        float fx = floorf(px), fy = floorf(py), fz = floorf(pz);
        float wx = px - fx, wy = py - fy, wz = pz - fz;
        int ix = (int)fx, iy = (int)fy, iz = (int)fz;
        ix = max(0, min(ix, R - 1)); iy = max(0, min(iy, R - 1)); iz = max(0, min(iz, R - 1));
        int jx = min(ix + 1, R - 1), jy = min(iy + 1, R - 1), jz = min(iz + 1, R - 1);
        float ax = 1.f - wx, ay = 1.f - wy, az = 1.f - wz;
        wyz[t][0] = ay * az; wyz[t][1] = wy * az; wyz[t][2] = ay * wz; wyz[t][3] = wy * wz;
        wxv[t] = wx; axv[t] = ax; ixv[t] = ix; jxv[t] = jx;
        if (dense) {
            unsigned sy = (unsigned)R, sz = (unsigned)(R * R);
            basev[t][0] = (unsigned)iy * sy + (unsigned)iz * sz;
            basev[t][1] = (unsigned)jy * sy + (unsigned)iz * sz;
            basev[t][2] = (unsigned)iy * sy + (unsigned)jz * sz;
            basev[t][3] = (unsigned)jy * sy + (unsigned)jz * sz;
        } else {
            unsigned hy0 = (unsigned)iy * 2654435761u, hy1 = (unsigned)jy * 2654435761u;
            unsigned hz0 = (unsigned)iz * 805459861u,  hz1 = (unsigned)jz * 805459861u;
            basev[t][0] = hy0 ^ hz0; basev[t][1] = hy1 ^ hz0;
            basev[t][2] = hy0 ^ hz1; basev[t][3] = hy1 ^ hz1;
        }
    }
    if (dense) {
        const float2* t2 = (const float2*)tab;
        #pragma unroll
        for (int t = 0; t < 2; ++t) {
            const bool adj = (jxv[t] == ixv[t] + 1);
            #pragma unroll
            for (int k = 0; k < 4; ++k) {
                unsigned i0 = basev[t][k] + (unsigned)ixv[t];
                if (adj && !(i0 & 1u)) {
                    f32x4 q = *(const f32x4*)(tab + ((size_t)i0 << 1));
                    lo[t][k] = make_float2(q[0], q[1]);
                    hi[t][k] = make_float2(q[2], q[3]);
                } else {
                    lo[t][k] = t2[i0];
                    hi[t][k] = t2[basev[t][k] + (unsigned)jxv[t]];
                }
            }
        }
    } else {
        const float2* t2 = (const float2*)tab;
        #pragma unroll
        for (int t = 0; t < 2; ++t) {
            const bool adj = (jxv[t] == ixv[t] + 1) && ((ixv[t] & 1) == 0);
            #pragma unroll
            for (int k = 0; k < 4; ++k) {
                if (adj) {
                    unsigned h = ((unsigned)ixv[t] ^ basev[t][k]) & HMASK;
                    f32x4 q = *(const f32x4*)(tab + ((size_t)(h & ~1u) << 1));
                    float2 e0 = make_float2(q[0], q[1]);
                    float2 e1 = make_float2(q[2], q[3]);
                    bool sw = (h & 1u) != 0;
                    lo[t][k] = sw ? e1 : e0;
                    hi[t][k] = sw ? e0 : e1;
                } else {
                    unsigned hl = ((unsigned)ixv[t] ^ basev[t][k]) & HMASK;
                    unsigned hh = ((unsigned)jxv[t] ^ basev[t][k]) & HMASK;
                    lo[t][k] = t2[hl];
                    hi[t][k] = t2[hh];
                }
            }
        }
    }
    float2 res[2];
    #pragma unroll
    for (int t = 0; t < 2; ++t) {
        float2 r = make_float2(0.f, 0.f);
        #pragma unroll
        for (int k = 0; k < 4; ++k) {
            float wl = axv[t] * wyz[t][k], wh = wxv[t] * wyz[t][k];
            r.x += wl * lo[t][k].x + wh * hi[t][k].x;
            r.y += wl * lo[t][k].y + wh * hi[t][k].y;
        }
        res[t] = r;
    }
    rA = res[0]; rB = res[1];
}

// Two-point HASHED gather on bf16-pair (u32) tables.
__device__ __forceinline__ void gather2h(const unsigned* __restrict__ tab, int R,
                                         float x0A, float x1A, float x2A,
                                         float x0B, float x1B, float x2B,
                                         float2& rA, float2& rB) {
    const float Rm1 = (float)(R - 1);
    float wxv[2], axv[2], wyz[2][4];
    int ixv[2], jxv[2];
    bool adjv[2];
    unsigned msv[2][4];
    #pragma unroll
    for (int t = 0; t < 2; ++t) {
        const float X0 = t ? x0B : x0A, X1 = t ? x1B : x1A, X2 = t ? x2B : x2A;
        float px = X0 * Rm1, py = X1 * Rm1, pz = X2 * Rm1;
        float fx = floorf(px), fy = floorf(py), fz = floorf(pz);
        float wx = px - fx, wy = py - fy, wz = pz - fz;
        int ix = (int)fx, iy = (int)fy, iz = (int)fz;
        ix = max(0, min(ix, R - 1)); iy = max(0, min(iy, R - 1)); iz = max(0, min(iz, R - 1));
        int jx = min(ix + 1, R - 1), jy = min(iy + 1, R - 1), jz = min(iz + 1, R - 1);
        float ax = 1.f - wx, ay = 1.f - wy, az = 1.f - wz;
        wyz[t][0] = ay * az; wyz[t][1] = wy * az; wyz[t][2] = ay * wz; wyz[t][3] = wy * wz;
        wxv[t] = wx; axv[t] = ax; ixv[t] = ix; jxv[t] = jx;
        adjv[t] = (jx == ix + 1) && ((ix & 1) == 0);
        unsigned hy0 = (unsigned)iy * 2654435761u, hy1 = (unsigned)jy * 2654435761u;
        unsigned hz0 = (unsigned)iz * 805459861u,  hz1 = (unsigned)jz * 805459861u;
        msv[t][0] = hy0 ^ hz0; msv[t][1] = hy1 ^ hz0;
        msv[t][2] = hy0 ^ hz1; msv[t][3] = hy1 ^ hz1;
    }
    float2 lo[2][4], hi[2][4];
    #pragma unroll
    for (int t = 0; t < 2; ++t) {
        #pragma unroll
        for (int k = 0; k < 4; ++k) {
            if (adjv[t]) {
                unsigned h = ((unsigned)ixv[t] ^ msv[t][k]) & HMASK;
                u32x2 q = *(const u32x2*)(tab + (h & ~1u));   // 8B aligned
                float2 e0 = upk(q[0]), e1 = upk(q[1]);
                bool sw = (h & 1u) != 0;
                lo[t][k] = sw ? e1 : e0;
                hi[t][k] = sw ? e0 : e1;
            } else {
                unsigned hl = ((unsigned)ixv[t] ^ msv[t][k]) & HMASK;
                unsigned hh = ((unsigned)jxv[t] ^ msv[t][k]) & HMASK;
                lo[t][k] = upk(tab[hl]);
                hi[t][k] = upk(tab[hh]);
            }
        }
    }
    float2 res[2];
    #pragma unroll
    for (int t = 0; t < 2; ++t) {
        float2 r = make_float2(0.f, 0.f);
        #pragma unroll
        for (int k = 0; k < 4; ++k) {
            float wl = axv[t] * wyz[t][k], wh = wxv[t] * wyz[t][k];
            r.x += wl * lo[t][k].x + wh * hi[t][k].x;
            r.y += wl * lo[t][k].y + wh * hi[t][k].y;
        }
        res[t] = r;
    }
    rA = res[0]; rB = res[1];
}

// =================== Kernel 0: convert hashed tables (5..15) to bf16 pairs ===================
__global__ __launch_bounds__(256)
void cvt_tables(const float* __restrict__ tables, unsigned* __restrict__ tbf) {
    const size_t i = (size_t)blockIdx.x * 256 + threadIdx.x;   // < 11 * HMAP
    const f32x2* src = (const f32x2*)(tables + (size_t)5 * 2 * HMAP);
    f32x2 f = __builtin_nontemporal_load(src + i);
    unsigned v = (unsigned)f2bf(f[0]) | ((unsigned)f2bf(f[1]) << 16);
    __builtin_nontemporal_store(v, tbf + i);
}

// =================== Kernel 1: hashed-level gather, XCD-balanced, HALF of the points ===================
// Same verified level->XCD pinning as the 277us round-4 kernel (fulls L5..L12 on
// XCD 0..7; L13 on {0,1,2}, L14 on {3,4,5}, L15 on {6,7}; max per-XCD 1.5 units).
// Split into two point-half dispatches (half=0,1): tables stay L2-resident across
// the back-to-back launches, so combined time should equal the single launch —
// and each half (~140us) drops below mlp_tiled2 (~257us), making K2's counters
// visible in the top-5 for the first time. Instrumentation round.
__global__ __launch_bounds__(256, 8)
void gather_hashed(const float* __restrict__ x, const unsigned* __restrict__ tbf,
                   unsigned* __restrict__ feat, int N, int half) {
    const int j = blockIdx.x & 7;
    const int i = blockIdx.x >> 3;
    int level, chunk;                      // chunk: 0..1023 within this half, per level
    if (i < 1024) {
        level = 5 + j; chunk = i;
    } else {
        const int r = i - 1024;            // [0,512)
        if (j < 3) {
            const int share = (j == 0) ? 342 : 341;
            const int base  = (j == 0) ? 0 : (j == 1 ? 342 : 683);
            if (r >= share) return;
            level = 13; chunk = base + r;
        } else if (j < 6) {
            const int jj = j - 3;
            const int share = (jj == 0) ? 342 : 341;
            const int base  = (jj == 0) ? 0 : (jj == 1 ? 342 : 683);
            if (r >= share) return;
            level = 14; chunk = base + r;
        } else {
            if (r >= 512) return;
            level = 15; chunk = (j - 6) * 512 + r;
        }
    }
    const size_t p0 = ((size_t)half * 1024 + (size_t)chunk) * 512 + 2u * threadIdx.x;
    const f32x2* xv = (const f32x2*)(x + 3 * p0);     // 12*p0 bytes, p0 even -> 8B aligned
    f32x2 u0 = __builtin_nontemporal_load(xv);
    f32x2 u1 = __builtin_nontemporal_load(xv + 1);
    f32x2 u2 = __builtin_nontemporal_load(xv + 2);
    float2 fA, fB;
    gather2h(tbf + (size_t)(level - 5) * HMAP, c_res[level],
             u0[0], u0[1], u1[0],
             u1[1], u2[0], u2[1],
             fA, fB);
    u32x2 v;
    v[0] = (unsigned)f2bf(fA.x) | ((unsigned)f2bf(fA.y) << 16);
    v[1] = (unsigned)f2bf(fB.x) | ((unsigned)f2bf(fB.y) << 16);
    __builtin_nontemporal_store(v, (u32x2*)(feat + (size_t)(level - 5) * N + p0));
}

// ======================= Kernel 2: tiled embed + dense gathers + MFMA MLP =======================
// Round-4 verified form (549us total): W0 in LDS, launch_bounds(256,4), dense f32
// gathers, sincos + double-angle recurrence.
#define NPB       128                     // points per tile
#define TILES     8
#define PTS_BLK   (NPB * TILES)           // 1024 points per block
#define SA_STRIDE 104                     // shorts; 208B row stride
#define SW0_OFF   (128 * 104)             // W0 bf16 [64][104], cols 71..95 zero
#define SMEM_SHORTS (SW0_OFF + 64 * 104)  // 39936 B -> 4 blocks/CU

__global__ __launch_bounds__(256, 4)
void mlp_tiled2(const float* __restrict__ x, const float* __restrict__ tables,
                const unsigned* __restrict__ feat,
                const float* __restrict__ W0, const float* __restrict__ b0,
                const float* __restrict__ W1, const float* __restrict__ b1,
                const float* __restrict__ W2, const float* __restrict__ b2,
                float* __restrict__ out, int N) {
    __shared__ unsigned short smem[SMEM_SHORTS];
    const int tid  = threadIdx.x;
    const int blk  = blockIdx.x;
    const int wave = tid >> 6, lane = tid & 63;
    const int mhalf = (wave & 1) * 64;
    const int nhalf = (wave >> 1);
    const int lrow = lane & 15, quad = lane >> 4;

    for (int i = tid; i < 64 * 104; i += 256) {
        int n = i / 104, k = i - n * 104;
        smem[SW0_OFF + i] = (k < 71) ? f2bf(W0[n * 71 + k]) : (unsigned short)0;
    }
    for (int i = tid; i < 128 * 25; i += 256) {
        int p = i / 25, k = i - p * 25;
        smem[p * SA_STRIDE + 71 + k] = 0;
    }
    bf16x8 w1f[2][2];
    #pragma unroll
    for (int ks = 0; ks < 2; ++ks)
        #pragma unroll
        for (int nt = 0; nt < 2; ++nt) {
            int n = nhalf * 32 + nt * 16 + lrow;
            w1f[ks][nt] = cvt8(W1 + n * 64 + ks * 32 + quad * 8);
        }
    bf16x8 w2f[2];
    {
        int n2 = nhalf * 16 + lrow;
        #pragma unroll
        for (int ks = 0; ks < 2; ++ks) {
            if (n2 < 17) w2f[ks] = cvt8(W2 + n2 * 64 + ks * 32 + quad * 8);
            else { bf16x8 z = {0,0,0,0,0,0,0,0}; w2f[ks] = z; }
        }
    }
    float b0v[2], b1v[2], b2v;
    #pragma unroll
    for (int nt = 0; nt < 2; ++nt) {
        b0v[nt] = b0[nhalf * 32 + nt * 16 + lrow];
        b1v[nt] = b1[nhalf * 32 + nt * 16 + lrow];
    }
    { int c2 = nhalf * 16 + lrow; b2v = (c2 < 17) ? b2[c2] : 0.f; }
    __syncthreads();

    const size_t pbase0 = (size_t)blk * PTS_BLK;
    #pragma unroll 1
    for (int t = 0; t < TILES; ++t) {
        const size_t pb = pbase0 + (size_t)t * NPB;
        {
            const int p = tid & 127;
            const size_t gp = pb + p;
            unsigned short* row = &smem[p * SA_STRIDE];
            const float x0 = __builtin_nontemporal_load(x + 3 * gp);
            const float x1 = __builtin_nontemporal_load(x + 3 * gp + 1);
            const float x2 = __builtin_nontemporal_load(x + 3 * gp + 2);
            // sin/cos of x*2^m via one sincos + double-angle recurrence
            float sa, ca, sb, cb, sc, cc;
            __sincosf(x0, &sa, &ca);
            __sincosf(x1, &sb, &cb);
            __sincosf(x2, &sc, &cc);
            if (tid < 128) {
                row[0] = f2bf(x0); row[1] = f2bf(x1); row[2] = f2bf(x2);
                #pragma unroll
                for (int m = 0; m < 6; ++m) {
                    row[3 + 6 * m + 0] = f2bf(sa);
                    row[3 + 6 * m + 1] = f2bf(sb);
                    row[3 + 6 * m + 2] = f2bf(sc);
                    float nsa = 2.f * sa * ca, nca = 1.f - 2.f * sa * sa;
                    float nsb = 2.f * sb * cb, ncb = 1.f - 2.f * sb * sb;
                    float nsc = 2.f * sc * cc, ncc = 1.f - 2.f * sc * sc;
                    sa = nsa; ca = nca; sb = nsb; cb = ncb; sc = nsc; cc = ncc;
                }
                float2 f;
                f = gather_level(tables,                         16, x0, x1, x2);
                row[39] = f2bf(f.x); row[40] = f2bf(f.y);
                f = gather_level(tables + (size_t)1 * 2 * HMAP,  23, x0, x1, x2);
                row[41] = f2bf(f.x); row[42] = f2bf(f.y);
                f = gather_level(tables + (size_t)2 * 2 * HMAP,  31, x0, x1, x2);
                row[43] = f2bf(f.x); row[44] = f2bf(f.y);
            } else {
                #pragma unroll
                for (int m = 0; m < 6; ++m) {
                    row[3 + 6 * m + 3] = f2bf(ca);
                    row[3 + 6 * m + 4] = f2bf(cb);
                    row[3 + 6 * m + 5] = f2bf(cc);
                    float nsa = 2.f * sa * ca, nca = 1.f - 2.f * sa * sa;
                    float nsb = 2.f * sb * cb, ncb = 1.f - 2.f * sb * sb;
                    float nsc = 2.f * sc * cc, ncc = 1.f - 2.f * sc * sc;
                    sa = nsa; ca = nca; sb = nsb; cb = ncb; sc = nsc; cc = ncc;
                }
                float2 f;
                f = gather_level(tables + (size_t)3 * 2 * HMAP,  43, x0, x1, x2);
                row[45] = f2bf(f.x); row[46] = f2bf(f.y);
                f = gather_level(tables + (size_t)4 * 2 * HMAP,  59, x0, x1, x2);
                row[47] = f2bf(f.x); row[48] = f2bf(f.y);
                #pragma unroll
                for (int li = 0; li < 11; ++li) {
                    unsigned v = __builtin_nontemporal_load(feat + (size_t)li * N + gp);
                    row[49 + 2 * li] = (unsigned short)(v & 0xffffu);
                    row[50 + 2 * li] = (unsigned short)(v >> 16);
                }
            }
        }
        __syncthreads();

        f32x4 acc0[4][2];
        #pragma unroll
        for (int mt = 0; mt < 4; ++mt)
            #pragma unroll
            for (int nt = 0; nt < 2; ++nt) acc0[mt][nt] = (f32x4){0.f, 0.f, 0.f, 0.f};
        #pragma unroll
        for (int ks = 0; ks < 3; ++ks) {
            bf16x8 bfr[2];
            #pragma unroll
            for (int nt = 0; nt < 2; ++nt) {
                int n = nhalf * 32 + nt * 16 + lrow;
                bfr[nt] = *(const bf16x8*)&smem[SW0_OFF + n * 104 + ks * 32 + quad * 8];
            }
            #pragma unroll
            for (int mt = 0; mt < 4; ++mt) {
                int m = mhalf + mt * 16 + lrow;
                bf16x8 afr = *(const bf16x8*)&smem[m * SA_STRIDE + ks * 32 + quad * 8];
                #pragma unroll
                for (int nt = 0; nt < 2; ++nt)
                    acc0[mt][nt] = __builtin_amdgcn_mfma_f32_16x16x32_bf16(afr, bfr[nt], acc0[mt][nt], 0, 0, 0);
            }
        }
        __syncthreads();
        #pragma unroll
        for (int mt = 0; mt < 4; ++mt)
            #pragma unroll
            for (int nt = 0; nt < 2; ++nt) {
                int colg = nhalf * 32 + nt * 16 + lrow;
                #pragma unroll
                for (int r = 0; r < 4; ++r) {
                    int rowm = mhalf + mt * 16 + quad * 4 + r;
                    smem[rowm * SA_STRIDE + colg] = f2bf(softplus100(acc0[mt][nt][r] + b0v[nt]));
                }
            }
        __syncthreads();

        f32x4 acc1[4][2];
        #pragma unroll
        for (int mt = 0; mt < 4; ++mt)
            #pragma unroll
            for (int nt = 0; nt < 2; ++nt) acc1[mt][nt] = (f32x4){0.f, 0.f, 0.f, 0.f};
        #pragma unroll
        for (int ks = 0; ks < 2; ++ks) {
            #pragma unroll
            for (int mt = 0; mt < 4; ++mt) {
                int m = mhalf + mt * 16 + lrow;
                bf16x8 afr = *(const bf16x8*)&smem[m * SA_STRIDE + ks * 32 + quad * 8];
                #pragma unroll
                for (int nt = 0; nt < 2; ++nt)
                    acc1[mt][nt] = __builtin_amdgcn_mfma_f32_16x16x32_bf16(afr, w1f[ks][nt], acc1[mt][nt], 0, 0, 0);
            }
        }
        __syncthreads();
        #pragma unroll
        for (int mt = 0; mt < 4; ++mt)
            #pragma unroll
            for (int nt = 0; nt < 2; ++nt) {
                int colg = nhalf * 32 + nt * 16 + lrow;
                #pragma unroll
                for (int r = 0; r < 4; ++r) {
                    int rowm = mhalf + mt * 16 + quad * 4 + r;
                    smem[rowm * SA_STRIDE + colg] = f2bf(softplus100(acc1[mt][nt][r] + b1v[nt]));
                }
            }
        __syncthreads();

        f32x4 acc2[4];
        #pragma unroll
        for (int mt = 0; mt < 4; ++mt) acc2[mt] = (f32x4){0.f, 0.f, 0.f, 0.f};
        #pragma unroll
        for (int ks = 0; ks < 2; ++ks) {
            #pragma unroll
            for (int mt = 0; mt < 4; ++mt) {
                int m = mhalf + mt * 16 + lrow;
                bf16x8 afr = *(const bf16x8*)&smem[m * SA_STRIDE + ks * 32 + quad * 8];
                acc2[mt] = __builtin_amdgcn_mfma_f32_16x16x32_bf16(afr, w2f[ks], acc2[mt], 0, 0, 0);
            }
        }
        {
            int colg = nhalf * 16 + lrow;
            if (colg < 17) {
                #pragma unroll
                for (int mt = 0; mt < 4; ++mt)
                    #pragma unroll
                    for (int r = 0; r < 4; ++r) {
                        int rowm = mhalf + mt * 16 + quad * 4 + r;
                        __builtin_nontemporal_store(acc2[mt][r] + b2v,
                                                    out + (pb + rowm) * 17 + colg);
                    }
            }
        }
        __syncthreads();
    }
}

// ======================= Path B (verified round-3 kernels) =======================
__global__ __launch_bounds__(256, 6)
void gather_levels(const float* __restrict__ x, const float* __restrict__ tables,
                   unsigned* __restrict__ feat, int N, int C) {
    const int b = blockIdx.x;
    const int half = 8 * C;
    int r, level;
    if (b < half) { r = b; level = r & 7; }
    else          { r = b - half; level = 15 - (r & 7); }
    const size_t p0 = (size_t)(r >> 3) * 512 + 2u * threadIdx.x;
    const f32x2* xv = (const f32x2*)(x + 3 * p0);
    f32x2 u0 = __builtin_nontemporal_load(xv);
    f32x2 u1 = __builtin_nontemporal_load(xv + 1);
    f32x2 u2 = __builtin_nontemporal_load(xv + 2);
    float2 fA, fB;
    gather2(tables + (size_t)level * (2u * HMAP), c_res[level],
            u0[0], u0[1], u1[0],
            u1[1], u2[0], u2[1],
            fA, fB);
    u32x2 v;
    v[0] = (unsigned)f2bf(fA.x) | ((unsigned)f2bf(fA.y) << 16);
    v[1] = (unsigned)f2bf(fB.x) | ((unsigned)f2bf(fB.y) << 16);
    __builtin_nontemporal_store(v, (u32x2*)(feat + (size_t)level * N + p0));
}

__global__ __launch_bounds__(256, 4)
void mlp_tiled(const float* __restrict__ x, const unsigned* __restrict__ feat,
               const float* __restrict__ W0, const float* __restrict__ b0,
               const float* __restrict__ W1, const float* __restrict__ b1,
               const float* __restrict__ W2, const float* __restrict__ b2,
               float* __restrict__ out, int N) {
    __shared__ unsigned short smem[SMEM_SHORTS];
    const int tid  = threadIdx.x;
    const int blk  = blockIdx.x;
    const int wave = tid >> 6, lane = tid & 63;
    const int mhalf = (wave & 1) * 64;
    const int nhalf = (wave >> 1);
    const int lrow = lane & 15, quad = lane >> 4;

    for (int i = tid; i < 64 * 104; i += 256) {
        int n = i / 104, k = i - n * 104;
        smem[SW0_OFF + i] = (k < 71) ? f2bf(W0[n * 71 + k]) : (unsigned short)0;
    }
    for (int i = tid; i < 128 * 25; i += 256) {
        int p = i / 25, k = i - p * 25;
        smem[p * SA_STRIDE + 71 + k] = 0;
    }
    bf16x8 w1f[2][2];
    #pragma unroll
    for (int ks = 0; ks < 2; ++ks)
        #pragma unroll
        for (int nt = 0; nt < 2; ++nt) {
            int n = nhalf * 32 + nt * 16 + lrow;
            w1f[ks][nt] = cvt8(W1 + n * 64 + ks * 32 + quad * 8);
        }
    bf16x8 w2f[2];
    {
        int n2 = nhalf * 16 + lrow;
        #pragma unroll
        for (int ks = 0; ks < 2; ++ks) {
            if (n2 < 17) w2f[ks] = cvt8(W2 + n2 * 64 + ks * 32 + quad * 8);
            else { bf16x8 z = {0,0,0,0,0,0,0,0}; w2f[ks] = z; }
        }
    }
    float b0v[2], b1v[2], b2v;
    #pragma unroll
    for (int nt = 0; nt < 2; ++nt) {
        b0v[nt] = b0[nhalf * 32 + nt * 16 + lrow];
        b1v[nt] = b1[nhalf * 32 + nt * 16 + lrow];
    }
    { int c2 = nhalf * 16 + lrow; b2v = (c2 < 17) ? b2[c2] : 0.f; }
    __syncthreads();

    const size_t pbase0 = (size_t)blk * PTS_BLK;
    #pragma unroll 1
    for (int t = 0; t < TILES; ++t) {
        const size_t pb = pbase0 + (size_t)t * NPB;
        {
            const int p = tid & 127;
            const size_t gp = pb + p;
            unsigned short* row = &smem[p * SA_STRIDE];
            const float x0 = __builtin_nontemporal_load(x + 3 * gp);
            const float x1 = __builtin_nontemporal_load(x + 3 * gp + 1);
            const float x2 = __builtin_nontemporal_load(x + 3 * gp + 2);
            if (tid < 128) {
                row[0] = f2bf(x0); row[1] = f2bf(x1); row[2] = f2bf(x2);
                float fr = 1.f;
                #pragma unroll
                for (int m = 0; m < 6; ++m) {
                    row[3 + 6 * m + 0] = f2bf(__sinf(x0 * fr));
                    row[3 + 6 * m + 1] = f2bf(__sinf(x1 * fr));
                    row[3 + 6 * m + 2] = f2bf(__sinf(x2 * fr));
                    fr *= 2.f;
                }
            } else {
                float fr = 1.f;
                #pragma unroll
                for (int m = 0; m < 6; ++m) {
                    row[3 + 6 * m + 3] = f2bf(__cosf(x0 * fr));
                    row[3 + 6 * m + 4] = f2bf(__cosf(x1 * fr));
                    row[3 + 6 * m + 5] = f2bf(__cosf(x2 * fr));
                    fr *= 2.f;
                }
                #pragma unroll
                for (int l = 0; l < 16; ++l) {
                    unsigned v = __builtin_nontemporal_load(feat + (size_t)l * N + gp);
                    row[39 + 2 * l] = (unsigned short)(v & 0xffffu);
                    row[40 + 2 * l] = (unsigned short)(v >> 16);
                }
            }
        }
        __syncthreads();

        f32x4 acc0[4][2];
        #pragma unroll
        for (int mt = 0; mt < 4; ++mt)
            #pragma unroll
            for (int nt = 0; nt < 2; ++nt) acc0[mt][nt] = (f32x4){0.f, 0.f, 0.f, 0.f};
        #pragma unroll
        for (int ks = 0; ks < 3; ++ks) {
            bf16x8 bfr[2];
            #pragma unroll
            for (int nt = 0; nt < 2; ++nt) {
                int n = nhalf * 32 + nt * 16 + lrow;
                bfr[nt] = *(const bf16x8*)&smem[SW0_OFF + n * 104 + ks * 32 + quad * 8];
            }
            #pragma unroll
            for (int mt = 0; mt < 4; ++mt) {
                int m = mhalf + mt * 16 + lrow;
                bf16x8 afr = *(const bf16x8*)&smem[m * SA_STRIDE + ks * 32 + quad * 8];
                #pragma unroll
                for (int nt = 0; nt < 2; ++nt)
                    acc0[mt][nt] = __builtin_amdgcn_mfma_f32_16x16x32_bf16(afr, bfr[nt], acc0[mt][nt], 0, 0, 0);
            }
        }
        __syncthreads();
        #pragma unroll
        for (int mt = 0; mt < 4; ++mt)
            #pragma unroll
            for (int nt = 0; nt < 2; ++nt) {
                int colg = nhalf * 32 + nt * 16 + lrow;
                #pragma unroll
                for (int r = 0; r < 4; ++r) {
                    int rowm = mhalf + mt * 16 + quad * 4 + r;
                    smem[rowm * SA_STRIDE + colg] = f2bf(softplus100(acc0[mt][nt][r] + b0v[nt]));
                }
            }
        __syncthreads();

        f32x4 acc1[4][2];
        #pragma unroll
        for (int mt = 0; mt < 4; ++mt)
            #pragma unroll
            for (int nt = 0; nt < 2; ++nt) acc1[mt][nt] = (f32x4){0.f, 0.f, 0.f, 0.f};
        #pragma unroll
        for (int ks = 0; ks < 2; ++ks) {
            #pragma unroll
            for (int mt = 0; mt < 4; ++mt) {
                int m = mhalf + mt * 16 + lrow;
                bf16x8 afr = *(const bf16x8*)&smem[m * SA_STRIDE + ks * 32 + quad * 8];
                #pragma unroll
                for (int nt = 0; nt < 2; ++nt)
                    acc1[mt][nt] = __builtin_amdgcn_mfma_f32_16x16x32_bf16(afr, w1f[ks][nt], acc1[mt][nt], 0, 0, 0);
            }
        }
        __syncthreads();
        #pragma unroll
        for (int mt = 0; mt < 4; ++mt)
            #pragma unroll
            for (int nt = 0; nt < 2; ++nt) {
                int colg = nhalf * 32 + nt * 16 + lrow;
                #pragma unroll
                for (int r = 0; r < 4; ++r) {
                    int rowm = mhalf + mt * 16 + quad * 4 + r;
                    smem[rowm * SA_STRIDE + colg] = f2bf(softplus100(acc1[mt][nt][r] + b1v[nt]));
                }
            }
        __syncthreads();

        f32x4 acc2[4];
        #pragma unroll
        for (int mt = 0; mt < 4; ++mt) acc2[mt] = (f32x4){0.f, 0.f, 0.f, 0.f};
        #pragma unroll
        for (int ks = 0; ks < 2; ++ks) {
            #pragma unroll
            for (int mt = 0; mt < 4; ++mt) {
                int m = mhalf + mt * 16 + lrow;
                bf16x8 afr = *(const bf16x8*)&smem[m * SA_STRIDE + ks * 32 + quad * 8];
                acc2[mt] = __builtin_amdgcn_mfma_f32_16x16x32_bf16(afr, w2f[ks], acc2[mt], 0, 0, 0);
            }
        }
        {
            int colg = nhalf * 16 + lrow;
            if (colg < 17) {
                #pragma unroll
                for (int mt = 0; mt < 4; ++mt)
                    #pragma unroll
                    for (int r = 0; r < 4; ++r) {
                        int rowm = mhalf + mt * 16 + quad * 4 + r;
                        __builtin_nontemporal_store(acc2[mt][r] + b2v,
                                                    out + (pb + rowm) * 17 + colg);
                    }
            }
        }
        __syncthreads();
    }
}

// ======================= Fallback (ws too small): fully fused =======================
__global__ __launch_bounds__(256, 3)
void gn_fused(const float* __restrict__ x, const float* __restrict__ tables,
              const float* __restrict__ W0, const float* __restrict__ b0,
              const float* __restrict__ W1, const float* __restrict__ b1,
              const float* __restrict__ W2, const float* __restrict__ b2,
              float* __restrict__ out) {
    __shared__ unsigned short smem[SMEM_SHORTS];
    const int tid = threadIdx.x;
    const int blk = blockIdx.x;
    const int wave = tid >> 6, lane = tid & 63;
    const int mhalf = (wave & 1) * 64;
    const int nhalf = (wave >> 1);
    const int lrow = lane & 15, quad = lane >> 4;
    for (int i = tid; i < 64 * 104; i += 256) {
        int n = i / 104, k = i - n * 104;
        smem[SW0_OFF + i] = (k < 71) ? f2bf(W0[n * 71 + k]) : (unsigned short)0;
    }
    for (int i = tid; i < 128 * 25; i += 256) {
        int p = i / 25, k = i - p * 25;
        smem[p * SA_STRIDE + 71 + k] = 0;
    }
    bf16x8 w1f[2][2];
    #pragma unroll
    for (int ks = 0; ks < 2; ++ks)
        #pragma unroll
        for (int nt = 0; nt < 2; ++nt) {
            int n = nhalf * 32 + nt * 16 + lrow;
            w1f[ks][nt] = cvt8(W1 + n * 64 + ks * 32 + quad * 8);
        }
    bf16x8 w2f[2];
    {
        int n2 = nhalf * 16 + lrow;
        #pragma unroll
        for (int ks = 0; ks < 2; ++ks) {
            if (n2 < 17) w2f[ks] = cvt8(W2 + n2 * 64 + ks * 32 + quad * 8);
            else { bf16x8 z = {0,0,0,0,0,0,0,0}; w2f[ks] = z; }
        }
    }
    float b0v[2], b1v[2], b2v;
    #pragma unroll
    for (int nt = 0; nt < 2; ++nt) {
        b0v[nt] = b0[nhalf * 32 + nt * 16 + lrow];
        b1v[nt] = b1[nhalf * 32 + nt * 16 + lrow];
    }
    { int c2 = nhalf * 16 + lrow; b2v = (c2 < 17) ? b2[c2] : 0.f; }
    {
        const int p = tid & 127;
        const size_t gp = (size_t)blk * NPB + p;
        const float x0 = x[3 * gp], x1 = x[3 * gp + 1], x2 = x[3 * gp + 2];
        unsigned short* row = &smem[p * SA_STRIDE];
        if (tid < 128) {
            row[0] = f2bf(x0); row[1] = f2bf(x1); row[2] = f2bf(x2);
            float fr = 1.f;
            #pragma unroll
            for (int m = 0; m < 6; ++m) {
                row[3 + 6 * m + 0] = f2bf(__sinf(x0 * fr));
                row[3 + 6 * m + 1] = f2bf(__sinf(x1 * fr));
                row[3 + 6 * m + 2] = f2bf(__sinf(x2 * fr));
                fr *= 2.f;
            }
            #pragma unroll
            for (int li = 0; li < 8; ++li) {
                const int l = 2 * li;
                float2 f = gather_level(tables + (size_t)l * (2u * HMAP), c_res[l], x0, x1, x2);
                row[39 + 2 * l] = f2bf(f.x);
                row[40 + 2 * l] = f2bf(f.y);
            }
        } else {
            float fr = 1.f;
            #pragma unroll
            for (int m = 0; m < 6; ++m) {
                row[3 + 6 * m + 3] = f2bf(__cosf(x0 * fr));
                row[3 + 6 * m + 4] = f2bf(__cosf(x1 * fr));
                row[3 + 6 * m + 5] = f2bf(__cosf(x2 * fr));
                fr *= 2.f;
            }
            #pragma unroll
            for (int li = 0; li < 8; ++li) {
                const int l = 2 * li + 1;
                float2 f = gather_level(tables + (size_t)l * (2u * HMAP), c_res[l], x0, x1, x2);
                row[39 + 2 * l] = f2bf(f.x);
                row[40 + 2 * l] = f2bf(f.y);
            }
        }
    }
    __syncthreads();
    f32x4 acc0[4][2];
    #pragma unroll
    for (int mt = 0; mt < 4; ++mt)
        #pragma unroll
        for (int nt = 0; nt < 2; ++nt) acc0[mt][nt] = (f32x4){0.f, 0.f, 0.f, 0.f};
    #pragma unroll
    for (int ks = 0; ks < 3; ++ks) {
        bf16x8 bfr[2];
        #pragma unroll
        for (int nt = 0; nt < 2; ++nt) {
            int n = nhalf * 32 + nt * 16 + lrow;
            bfr[nt] = *(const bf16x8*)&smem[SW0_OFF + n * 104 + ks * 32 + quad * 8];
        }
        #pragma unroll
        for (int mt = 0; mt < 4; ++mt) {
            int m = mhalf + mt * 16 + lrow;
            bf16x8 afr = *(const bf16x8*)&smem[m * SA_STRIDE + ks * 32 + quad * 8];
            #pragma unroll
            for (int nt = 0; nt < 2; ++nt)
                acc0[mt][nt] = __builtin_amdgcn_mfma_f32_16x16x32_bf16(afr, bfr[nt], acc0[mt][nt], 0, 0, 0);
        }
    }
    __syncthreads();
    #pragma unroll
    for (int mt = 0; mt < 4; ++mt)
        #pragma unroll
        for (int nt = 0; nt < 2; ++nt) {
            int colg = nhalf * 32 + nt * 16 + lrow;
            #pragma unroll
            for (int r = 0; r < 4; ++r) {
                int rowm = mhalf + mt * 16 + quad * 4 + r;
                smem[rowm * SA_STRIDE + colg] = f2bf(softplus100(acc0[mt][nt][r] + b0v[nt]));
            }
        }
    __syncthreads();
    f32x4 acc1[4][2];
    #pragma unroll
    for (int mt = 0; mt < 4; ++mt)
        #pragma unroll
        for (int nt = 0; nt < 2; ++nt) acc1[mt][nt] = (f32x4){0.f, 0.f, 0.f, 0.f};
    #pragma unroll
    for (int ks = 0; ks < 2; ++ks) {
        #pragma unroll
        for (int mt = 0; mt < 4; ++mt) {
            int m = mhalf + mt * 16 + lrow;
            bf16x8 afr = *(const bf16x8*)&smem[m * SA_STRIDE + ks * 32 + quad * 8];
            #pragma unroll
            for (int nt = 0; nt < 2; ++nt)
                acc1[mt][nt] = __builtin_amdgcn_mfma_f32_16x16x32_bf16(afr, w1f[ks][nt], acc1[mt][nt], 0, 0, 0);
        }
    }
    __syncthreads();
    #pragma unroll
    for (int mt = 0; mt < 4; ++mt)
        #pragma unroll
        for (int nt = 0; nt < 2; ++nt) {
            int colg = nhalf * 32 + nt * 16 + lrow;
            #pragma unroll
            for (int r = 0; r < 4; ++r) {
                int rowm = mhalf + mt * 16 + quad * 4 + r;
                smem[rowm * SA_STRIDE + colg] = f2bf(softplus100(acc1[mt][nt][r] + b1v[nt]));
            }
        }
    __syncthreads();
    f32x4 acc2[4];
    #pragma unroll
    for (int mt = 0; mt < 4; ++mt) acc2[mt] = (f32x4){0.f, 0.f, 0.f, 0.f};
    #pragma unroll
    for (int ks = 0; ks < 2; ++ks) {
        #pragma unroll
        for (int mt = 0; mt < 4; ++mt) {
            int m = mhalf + mt * 16 + lrow;
            bf16x8 afr = *(const bf16x8*)&smem[m * SA_STRIDE + ks * 32 + quad * 8];
            acc2[mt] = __builtin_amdgcn_mfma_f32_16x16x32_bf16(afr, w2f[ks], acc2[mt], 0, 0, 0);
        }
    }
    {
        int colg = nhalf * 16 + lrow;
        if (colg < 17) {
            #pragma unroll
            for (int mt = 0; mt < 4; ++mt)
                #pragma unroll
                for (int r = 0; r < 4; ++r) {
                    int rowm = mhalf + mt * 16 + quad * 4 + r;
                    out[((size_t)blk * NPB + rowm) * 17 + colg] = acc2[mt][r] + b2v;
                }
        }
    }
}

extern "C" void kernel_launch(void* const* d_in, const int* in_sizes, int n_in,
                              void* d_out, int out_size, void* d_ws, size_t ws_size,
                              hipStream_t stream) {
    const float* x      = (const float*)d_in[0];
    const float* tables = (const float*)d_in[1];
    const float* W0     = (const float*)d_in[2];
    const float* b0     = (const float*)d_in[3];
    const float* W1     = (const float*)d_in[4];
    const float* b1     = (const float*)d_in[5];
    const float* W2     = (const float*)d_in[6];
    const float* b2     = (const float*)d_in[7];
    float* out = (float*)d_out;
    const int n = in_sizes[0] / 3;                           // 1048576
    const size_t featA_b = (size_t)11 * n * 4;               // 44 MB hashed feat staging
    const size_t tbf_b   = (size_t)11 * HMAP * 4;            // 22 MB bf16 hashed tables
    const size_t wsB     = (size_t)16 * n * 4;               // 64 MB (path B)
    if (n == (1 << 20) && ws_size >= featA_b + tbf_b) {
        unsigned* feat = (unsigned*)d_ws;
        unsigned* tbf  = (unsigned*)((char*)d_ws + featA_b);
        cvt_tables<<<dim3(11 * HMAP / 256), dim3(256), 0, stream>>>(tables, tbf);
        // two point-half dispatches: same pinning, tables stay L2-resident across
        // the boundary; each half ~140us < mlp_tiled2 -> K2 counters visible.
        gather_hashed<<<dim3(8 * 1536), dim3(256), 0, stream>>>(x, tbf, feat, n, 0);
        gather_hashed<<<dim3(8 * 1536), dim3(256), 0, stream>>>(x, tbf, feat, n, 1);
        mlp_tiled2<<<dim3(n / PTS_BLK), dim3(256), 0, stream>>>(x, tables, feat, W0, b0, W1, b1, W2, b2, out, n);
    } else if (ws_size >= wsB) {
        unsigned* feat = (unsigned*)d_ws;
        const int C = n / 512;
        gather_levels<<<dim3(16 * C), dim3(256), 0, stream>>>(x, tables, feat, n, C);
        mlp_tiled<<<dim3(n / PTS_BLK), dim3(256), 0, stream>>>(x, feat, W0, b0, W1, b1, W2, b2, out, n);
    } else {
        gn_fused<<<dim3(n / NPB), dim3(256), 0, stream>>>(x, tables, W0, b0, W1, b1, W2, b2, out);
    }
}

// Round 9
// 553.246 us; speedup vs baseline: 1.3029x; 1.0024x over previous
//
#include <hip/hip_runtime.h>
#include <stdint.h>

#define HMAP   (1u << 19)
#define HMASK  (HMAP - 1u)

typedef short bf16x8 __attribute__((ext_vector_type(8)));
typedef float f32x4  __attribute__((ext_vector_type(4)));
typedef float f32x2  __attribute__((ext_vector_type(2)));
typedef unsigned u32x2 __attribute__((ext_vector_type(2)));

// resolutions: ceil(16 * 2^(7l/15)); dense (R^3 <= 2^19) for levels 0..4
__device__ __constant__ const int c_res[16] = {16, 23, 31, 43, 59, 81, 112, 154, 213, 295, 407, 562, 777, 1073, 1483, 2048};

__device__ __forceinline__ unsigned short f2bf(float f) {
    unsigned u = __float_as_uint(f);
    u += 0x7fffu + ((u >> 16) & 1u);           // round-to-nearest-even
    return (unsigned short)(u >> 16);
}

// HW packed f32->bf16 (RNE), 1 inst for 2 values (K2 is VALU-issue-bound: 65%).
__device__ __forceinline__ unsigned pk_bf16(float a, float b) {
    unsigned r;
    asm("v_cvt_pk_bf16_f32 %0, %1, %2" : "=v"(r) : "v"(a), "v"(b));
    return r;
}

// Exactly matches where(100v>20, v, log1p(exp(100v))/100):
__device__ __forceinline__ float softplus100(float v) {
    return fmaxf(v, 0.f) + 0.01f * __logf(1.f + __expf(-100.f * fabsf(v)));
}

__device__ __forceinline__ bf16x8 cvt8(const float* __restrict__ p) {
    f32x4 a = *(const f32x4*)p;
    f32x4 b = *(const f32x4*)(p + 4);
    bf16x8 r;
    r[0] = f2bf(a[0]); r[1] = f2bf(a[1]); r[2] = f2bf(a[2]); r[3] = f2bf(a[3]);
    r[4] = f2bf(b[0]); r[5] = f2bf(b[1]); r[6] = f2bf(b[2]); r[7] = f2bf(b[3]);
    return r;
}

__device__ __forceinline__ float2 upk(unsigned v) {   // bf16 pair -> f32 pair (exact)
    return make_float2(__uint_as_float(v << 16), __uint_as_float(v & 0xffff0000u));
}

// Single-point trilinear gather on f32 tables (dense levels + fallbacks).
__device__ __forceinline__ float2 gather_level(const float* __restrict__ tab, int R,
                                               float x0, float x1, float x2) {
    const float Rm1 = (float)(R - 1);
    float px = x0 * Rm1, py = x1 * Rm1, pz = x2 * Rm1;
    float fx = floorf(px), fy = floorf(py), fz = floorf(pz);
    float wx = px - fx, wy = py - fy, wz = pz - fz;
    int ix = (int)fx, iy = (int)fy, iz = (int)fz;
    ix = max(0, min(ix, R - 1)); iy = max(0, min(iy, R - 1)); iz = max(0, min(iz, R - 1));
    int jx = min(ix + 1, R - 1), jy = min(iy + 1, R - 1), jz = min(iz + 1, R - 1);
    float ax = 1.f - wx, ay = 1.f - wy, az = 1.f - wz;
    float wyz0 = ay * az, wyz1 = wy * az, wyz2 = ay * wz, wyz3 = wy * wz;
    float2 lo[4], hi[4];
    const bool adj = (jx == ix + 1);
    if ((long long)R * R * R <= (long long)HMAP) {   // dense
        unsigned sy = (unsigned)R, sz = (unsigned)(R * R);
        unsigned bases[4] = {(unsigned)iy * sy + (unsigned)iz * sz,
                             (unsigned)jy * sy + (unsigned)iz * sz,
                             (unsigned)iy * sy + (unsigned)jz * sz,
                             (unsigned)jy * sy + (unsigned)jz * sz};
        const float2* t2 = (const float2*)tab;
        #pragma unroll
        for (int k = 0; k < 4; ++k) {
            unsigned i0 = bases[k] + (unsigned)ix;
            if (adj && !(i0 & 1u)) {
                f32x4 q = *(const f32x4*)(tab + ((size_t)i0 << 1));
                lo[k] = make_float2(q[0], q[1]);
                hi[k] = make_float2(q[2], q[3]);
            } else {
                lo[k] = t2[i0];
                hi[k] = t2[bases[k] + (unsigned)jx];
            }
        }
    } else {                                          // hashed
        unsigned hy0 = (unsigned)iy * 2654435761u, hy1 = (unsigned)jy * 2654435761u;
        unsigned hz0 = (unsigned)iz * 805459861u,  hz1 = (unsigned)jz * 805459861u;
        unsigned ms[4] = {hy0 ^ hz0, hy1 ^ hz0, hy0 ^ hz1, hy1 ^ hz1};
        if (adj && ((ix & 1) == 0)) {
            #pragma unroll
            for (int k = 0; k < 4; ++k) {
                unsigned h = ((unsigned)ix ^ ms[k]) & HMASK;
                f32x4 q = *(const f32x4*)(tab + ((size_t)(h & ~1u) << 1));
                float2 e0 = make_float2(q[0], q[1]);
                float2 e1 = make_float2(q[2], q[3]);
                bool sw = (h & 1u) != 0;
                lo[k] = sw ? e1 : e0;
                hi[k] = sw ? e0 : e1;
            }
        } else {
            const float2* t2 = (const float2*)tab;
            #pragma unroll
            for (int k = 0; k < 4; ++k) {
                unsigned hl = ((unsigned)ix ^ ms[k]) & HMASK;
                unsigned hh = ((unsigned)jx ^ ms[k]) & HMASK;
                lo[k] = t2[hl];
                hi[k] = t2[hh];
            }
        }
    }
    float2 r = make_float2(0.f, 0.f);
    float wyz[4] = {wyz0, wyz1, wyz2, wyz3};
    #pragma unroll
    for (int k = 0; k < 4; ++k) {
        float wl = ax * wyz[k], wh = wx * wyz[k];
        r.x += wl * lo[k].x + wh * hi[k].x;
        r.y += wl * lo[k].y + wh * hi[k].y;
    }
    return r;
}

// Two-point gather on f32 tables (path-B fallback K1).
__device__ __forceinline__ void gather2(const float* __restrict__ tab, int R,
                                        float x0A, float x1A, float x2A,
                                        float x0B, float x1B, float x2B,
                                        float2& rA, float2& rB) {
    const float Rm1 = (float)(R - 1);
    float wxv[2], axv[2];
    float wyz[2][4];
    float2 lo[2][4], hi[2][4];
    int ixv[2], jxv[2];
    unsigned basev[2][4];
    const bool dense = (long long)R * R * R <= (long long)HMAP;
    #pragma unroll
    for (int t = 0; t < 2; ++t) {
        const float X0 = t ? x0B : x0A, X1 = t ? x1B : x1A, X2 = t ? x2B : x2A;
        float px = X0 * Rm1, py = X1 * Rm1, pz = X2 * Rm1;
        float fx = floorf(px), fy = floorf(py), fz = floorf(pz);
        float wx = px - fx, wy = py - fy, wz = pz - fz;
        int ix = (int)fx, iy = (int)fy, iz = (int)fz;
        ix = max(0, min(ix, R - 1)); iy = max(0, min(iy, R - 1)); iz = max(0, min(iz, R - 1));
        int jx = min(ix + 1, R - 1), jy = min(iy + 1, R - 1), jz = min(iz + 1, R - 1);
        float ax = 1.f - wx, ay = 1.f - wy, az = 1.f - wz;
        wyz[t][0] = ay * az; wyz[t][1] = wy * az; wyz[t][2] = ay * wz; wyz[t][3] = wy * wz;
        wxv[t] = wx; axv[t] = ax; ixv[t] = ix; jxv[t] = jx;
        if (dense) {
            unsigned sy = (unsigned)R, sz = (unsigned)(R * R);
            basev[t][0] = (unsigned)iy * sy + (unsigned)iz * sz;
            basev[t][1] = (unsigned)jy * sy + (unsigned)iz * sz;
            basev[t][2] = (unsigned)iy * sy + (unsigned)jz * sz;
            basev[t][3] = (unsigned)jy * sy + (unsigned)jz * sz;
        } else {
            unsigned hy0 = (unsigned)iy * 2654435761u, hy1 = (unsigned)jy * 2654435761u;
            unsigned hz0 = (unsigned)iz * 805459861u,  hz1 = (unsigned)jz * 805459861u;
            basev[t][0] = hy0 ^ hz0; basev[t][1] = hy1 ^ hz0;
            basev[t][2] = hy0 ^ hz1; basev[t][3] = hy1 ^ hz1;
        }
    }
    if (dense) {
        const float2* t2 = (const float2*)tab;
        #pragma unroll
        for (int t = 0; t < 2; ++t) {
            const bool adj = (jxv[t] == ixv[t] + 1);
            #pragma unroll
            for (int k = 0; k < 4; ++k) {
                unsigned i0 = basev[t][k] + (unsigned)ixv[t];
                if (adj && !(i0 & 1u)) {
                    f32x4 q = *(const f32x4*)(tab + ((size_t)i0 << 1));
                    lo[t][k] = make_float2(q[0], q[1]);
                    hi[t][k] = make_float2(q[2], q[3]);
                } else {
                    lo[t][k] = t2[i0];
                    hi[t][k] = t2[basev[t][k] + (unsigned)jxv[t]];
                }
            }
        }
    } else {
        const float2* t2 = (const float2*)tab;
        #pragma unroll
        for (int t = 0; t < 2; ++t) {
            const bool adj = (jxv[t] == ixv[t] + 1) && ((ixv[t] & 1) == 0);
            #pragma unroll
            for (int k = 0; k < 4; ++k) {
                if (adj) {
                    unsigned h = ((unsigned)ixv[t] ^ basev[t][k]) & HMASK;
                    f32x4 q = *(const f32x4*)(tab + ((size_t)(h & ~1u) << 1));
                    float2 e0 = make_float2(q[0], q[1]);
                    float2 e1 = make_float2(q[2], q[3]);
                    bool sw = (h & 1u) != 0;
                    lo[t][k] = sw ? e1 : e0;
                    hi[t][k] = sw ? e0 : e1;
                } else {
                    unsigned hl = ((unsigned)ixv[t] ^ basev[t][k]) & HMASK;
                    unsigned hh = ((unsigned)jxv[t] ^ basev[t][k]) & HMASK;
                    lo[t][k] = t2[hl];
                    hi[t][k] = t2[hh];
                }
            }
        }
    }
    float2 res[2];
    #pragma unroll
    for (int t = 0; t < 2; ++t) {
        float2 r = make_float2(0.f, 0.f);
        #pragma unroll
        for (int k = 0; k < 4; ++k) {
            float wl = axv[t] * wyz[t][k], wh = wxv[t] * wyz[t][k];
            r.x += wl * lo[t][k].x + wh * hi[t][k].x;
            r.y += wl * lo[t][k].y + wh * hi[t][k].y;
        }
        res[t] = r;
    }
    rA = res[0]; rB = res[1];
}

// Two-point HASHED gather on bf16-pair (u32) tables.
__device__ __forceinline__ void gather2h(const unsigned* __restrict__ tab, int R,
                                         float x0A, float x1A, float x2A,
                                         float x0B, float x1B, float x2B,
                                         float2& rA, float2& rB) {
    const float Rm1 = (float)(R - 1);
    float wxv[2], axv[2], wyz[2][4];
    int ixv[2], jxv[2];
    bool adjv[2];
    unsigned msv[2][4];
    #pragma unroll
    for (int t = 0; t < 2; ++t) {
        const float X0 = t ? x0B : x0A, X1 = t ? x1B : x1A, X2 = t ? x2B : x2A;
        float px = X0 * Rm1, py = X1 * Rm1, pz = X2 * Rm1;
        float fx = floorf(px), fy = floorf(py), fz = floorf(pz);
        float wx = px - fx, wy = py - fy, wz = pz - fz;
        int ix = (int)fx, iy = (int)fy, iz = (int)fz;
        ix = max(0, min(ix, R - 1)); iy = max(0, min(iy, R - 1)); iz = max(0, min(iz, R - 1));
        int jx = min(ix + 1, R - 1), jy = min(iy + 1, R - 1), jz = min(iz + 1, R - 1);
        float ax = 1.f - wx, ay = 1.f - wy, az = 1.f - wz;
        wyz[t][0] = ay * az; wyz[t][1] = wy * az; wyz[t][2] = ay * wz; wyz[t][3] = wy * wz;
        wxv[t] = wx; axv[t] = ax; ixv[t] = ix; jxv[t] = jx;
        adjv[t] = (jx == ix + 1) && ((ix & 1) == 0);
        unsigned hy0 = (unsigned)iy * 2654435761u, hy1 = (unsigned)jy * 2654435761u;
        unsigned hz0 = (unsigned)iz * 805459861u,  hz1 = (unsigned)jz * 805459861u;
        msv[t][0] = hy0 ^ hz0; msv[t][1] = hy1 ^ hz0;
        msv[t][2] = hy0 ^ hz1; msv[t][3] = hy1 ^ hz1;
    }
    float2 lo[2][4], hi[2][4];
    #pragma unroll
    for (int t = 0; t < 2; ++t) {
        #pragma unroll
        for (int k = 0; k < 4; ++k) {
            if (adjv[t]) {
                unsigned h = ((unsigned)ixv[t] ^ msv[t][k]) & HMASK;
                u32x2 q = *(const u32x2*)(tab + (h & ~1u));   // 8B aligned
                float2 e0 = upk(q[0]), e1 = upk(q[1]);
                bool sw = (h & 1u) != 0;
                lo[t][k] = sw ? e1 : e0;
                hi[t][k] = sw ? e0 : e1;
            } else {
                unsigned hl = ((unsigned)ixv[t] ^ msv[t][k]) & HMASK;
                unsigned hh = ((unsigned)jxv[t] ^ msv[t][k]) & HMASK;
                lo[t][k] = upk(tab[hl]);
                hi[t][k] = upk(tab[hh]);
            }
        }
    }
    float2 res[2];
    #pragma unroll
    for (int t = 0; t < 2; ++t) {
        float2 r = make_float2(0.f, 0.f);
        #pragma unroll
        for (int k = 0; k < 4; ++k) {
            float wl = axv[t] * wyz[t][k], wh = wxv[t] * wyz[t][k];
            r.x += wl * lo[t][k].x + wh * hi[t][k].x;
            r.y += wl * lo[t][k].y + wh * hi[t][k].y;
        }
        res[t] = r;
    }
    rA = res[0]; rB = res[1];
}

// =================== Kernel 0: convert hashed tables (5..15) to bf16 pairs ===================
__global__ __launch_bounds__(256)
void cvt_tables(const float* __restrict__ tables, unsigned* __restrict__ tbf) {
    const size_t i = (size_t)blockIdx.x * 256 + threadIdx.x;   // < 11 * HMAP
    const f32x2* src = (const f32x2*)(tables + (size_t)5 * 2 * HMAP);
    f32x2 f = __builtin_nontemporal_load(src + i);
    unsigned v = (unsigned)f2bf(f[0]) | ((unsigned)f2bf(f[1]) << 16);
    __builtin_nontemporal_store(v, tbf + i);
}

// =================== Kernel 1: hashed-level gather, XCD-balanced (verified 277us) ===================
__global__ __launch_bounds__(256, 8)
void gather_hashed(const float* __restrict__ x, const unsigned* __restrict__ tbf,
                   unsigned* __restrict__ feat, int N) {
    const int j = blockIdx.x & 7;
    const int i = blockIdx.x >> 3;
    int level, chunk;
    if (i < 2048) {
        level = 5 + j; chunk = i;
    } else {
        const int r = i - 2048;
        if (j < 3) {
            const int share = (j == 2) ? 682 : 683;
            if (r >= share) return;
            level = 13; chunk = j * 683 + r;
        } else if (j < 6) {
            const int jj = j - 3;
            const int share = (jj == 2) ? 682 : 683;
            if (r >= share) return;
            level = 14; chunk = jj * 683 + r;
        } else {
            if (r >= 1024) return;
            level = 15; chunk = (j - 6) * 1024 + r;
        }
    }
    const size_t p0 = (size_t)chunk * 512 + 2u * threadIdx.x;
    const f32x2* xv = (const f32x2*)(x + 3 * p0);     // 12*p0 bytes, p0 even -> 8B aligned
    f32x2 u0 = __builtin_nontemporal_load(xv);
    f32x2 u1 = __builtin_nontemporal_load(xv + 1);
    f32x2 u2 = __builtin_nontemporal_load(xv + 2);
    float2 fA, fB;
    gather2h(tbf + (size_t)(level - 5) * HMAP, c_res[level],
             u0[0], u0[1], u1[0],
             u1[1], u2[0], u2[1],
             fA, fB);
    u32x2 v;
    v[0] = (unsigned)f2bf(fA.x) | ((unsigned)f2bf(fA.y) << 16);
    v[1] = (unsigned)f2bf(fB.x) | ((unsigned)f2bf(fB.y) << 16);
    __builtin_nontemporal_store(v, (u32x2*)(feat + (size_t)(level - 5) * N + p0));
}

// ======================= Kernel 2: tiled embed + dense gathers + MFMA MLP =======================
// K2 is VALU-issue-bound (measured: VALUBusy 65%, MfmaUtil 6%, HBM 9%). This
// round cuts conversion/packing VALU: v_cvt_pk_bf16_f32 (1 inst / 2 values) +
// a column PERMUTATION of the input row so every staging write is an aligned
// u32 ds_write (hashed feat words stored verbatim, zero unpack). W0 is staged
// with the same permutation -> numerically identical output.
// New row layout (cols): 0-2 x | 3 pad | 4-21 sines (m-major) | 22-39 cosines
// | 40-49 dense feats L0-4 | 50-71 hashed feats L5-15 | 72-95 zero pad.
#define NPB       128                     // points per tile
#define TILES     8
#define PTS_BLK   (NPB * TILES)           // 1024 points per block
#define SA_STRIDE 104                     // shorts; 208B row stride (16B-aligned b128 reads)
#define SW0_OFF   (128 * 104)             // W0 bf16 [64][104] (permuted cols)
#define SMEM_SHORTS (SW0_OFF + 64 * 104)  // 39936 B -> 4 blocks/CU

__global__ __launch_bounds__(256, 4)
void mlp_tiled2(const float* __restrict__ x, const float* __restrict__ tables,
                const unsigned* __restrict__ feat,
                const float* __restrict__ W0, const float* __restrict__ b0,
                const float* __restrict__ W1, const float* __restrict__ b1,
                const float* __restrict__ W2, const float* __restrict__ b2,
                float* __restrict__ out, int N) {
    __shared__ unsigned short smem[SMEM_SHORTS];
    const int tid  = threadIdx.x;
    const int blk  = blockIdx.x;
    const int wave = tid >> 6, lane = tid & 63;
    const int mhalf = (wave & 1) * 64;
    const int nhalf = (wave >> 1);
    const int lrow = lane & 15, quad = lane >> 4;

    // W0 staged with the row permutation (exact: same permutation both sides)
    for (int i = tid; i < 64 * 104; i += 256) {
        int n = i / 104, c = i - n * 104;
        float w = 0.f;
        if (c < 3)                 w = W0[n * 71 + c];
        else if (c >= 4 && c < 22) { int q = c - 4;  w = W0[n * 71 + 3 + 6 * (q / 3) + (q % 3)]; }
        else if (c >= 22 && c < 40){ int q = c - 22; w = W0[n * 71 + 6 + 6 * (q / 3) + (q % 3)]; }
        else if (c >= 40 && c < 72) w = W0[n * 71 + 39 + (c - 40)];
        smem[SW0_OFF + i] = f2bf(w);
    }
    // zero pad cols 72..95 of the A tile (never overwritten; layer0 reads k<96)
    for (int i = tid; i < 128 * 24; i += 256) {
        int p = i / 24, k = i - p * 24;
        smem[p * SA_STRIDE + 72 + k] = 0;
    }
    bf16x8 w1f[2][2];
    #pragma unroll
    for (int ks = 0; ks < 2; ++ks)
        #pragma unroll
        for (int nt = 0; nt < 2; ++nt) {
            int n = nhalf * 32 + nt * 16 + lrow;
            w1f[ks][nt] = cvt8(W1 + n * 64 + ks * 32 + quad * 8);
        }
    bf16x8 w2f[2];
    {
        int n2 = nhalf * 16 + lrow;
        #pragma unroll
        for (int ks = 0; ks < 2; ++ks) {
            if (n2 < 17) w2f[ks] = cvt8(W2 + n2 * 64 + ks * 32 + quad * 8);
            else { bf16x8 z = {0,0,0,0,0,0,0,0}; w2f[ks] = z; }
        }
    }
    float b0v[2], b1v[2], b2v;
    #pragma unroll
    for (int nt = 0; nt < 2; ++nt) {
        b0v[nt] = b0[nhalf * 32 + nt * 16 + lrow];
        b1v[nt] = b1[nhalf * 32 + nt * 16 + lrow];
    }
    { int c2 = nhalf * 16 + lrow; b2v = (c2 < 17) ? b2[c2] : 0.f; }
    __syncthreads();

    const size_t pbase0 = (size_t)blk * PTS_BLK;
    #pragma unroll 1
    for (int t = 0; t < TILES; ++t) {
        const size_t pb = pbase0 + (size_t)t * NPB;
        {
            const int p = tid & 127;
            const size_t gp = pb + p;
            unsigned short* row = &smem[p * SA_STRIDE];
            unsigned* row32 = (unsigned*)row;            // stride 208B -> u32-aligned
            const float x0 = __builtin_nontemporal_load(x + 3 * gp);
            const float x1 = __builtin_nontemporal_load(x + 3 * gp + 1);
            const float x2 = __builtin_nontemporal_load(x + 3 * gp + 2);
            float sa, ca, sb, cb, sc, cc;
            __sincosf(x0, &sa, &ca);
            __sincosf(x1, &sb, &cb);
            __sincosf(x2, &sc, &cc);
            if (tid < 128) {
                row32[0] = pk_bf16(x0, x1);              // cols 0,1
                row32[1] = pk_bf16(x2, 0.f);             // cols 2,3 (3 = pad)
                float sv[18];
                #pragma unroll
                for (int m = 0; m < 6; ++m) {
                    sv[3 * m] = sa; sv[3 * m + 1] = sb; sv[3 * m + 2] = sc;
                    float nsa = 2.f * sa * ca, nca = 1.f - 2.f * sa * sa;
                    float nsb = 2.f * sb * cb, ncb = 1.f - 2.f * sb * sb;
                    float nsc = 2.f * sc * cc, ncc = 1.f - 2.f * sc * sc;
                    sa = nsa; ca = nca; sb = nsb; cb = ncb; sc = nsc; cc = ncc;
                }
                #pragma unroll
                for (int j = 0; j < 9; ++j)
                    row32[2 + j] = pk_bf16(sv[2 * j], sv[2 * j + 1]);   // cols 4..21
                float2 f;
                f = gather_level(tables,                         16, x0, x1, x2);
                row32[20] = pk_bf16(f.x, f.y);
                f = gather_level(tables + (size_t)1 * 2 * HMAP,  23, x0, x1, x2);
                row32[21] = pk_bf16(f.x, f.y);
                f = gather_level(tables + (size_t)2 * 2 * HMAP,  31, x0, x1, x2);
                row32[22] = pk_bf16(f.x, f.y);
            } else {
                float cv[18];
                #pragma unroll
                for (int m = 0; m < 6; ++m) {
                    cv[3 * m] = ca; cv[3 * m + 1] = cb; cv[3 * m + 2] = cc;
                    float nsa = 2.f * sa * ca, nca = 1.f - 2.f * sa * sa;
                    float nsb = 2.f * sb * cb, ncb = 1.f - 2.f * sb * sb;
                    float nsc = 2.f * sc * cc, ncc = 1.f - 2.f * sc * sc;
                    sa = nsa; ca = nca; sb = nsb; cb = ncb; sc = nsc; cc = ncc;
                }
                #pragma unroll
                for (int j = 0; j < 9; ++j)
                    row32[11 + j] = pk_bf16(cv[2 * j], cv[2 * j + 1]);  // cols 22..39
                float2 f;
                f = gather_level(tables + (size_t)3 * 2 * HMAP,  43, x0, x1, x2);
                row32[23] = pk_bf16(f.x, f.y);
                f = gather_level(tables + (size_t)4 * 2 * HMAP,  59, x0, x1, x2);
                row32[24] = pk_bf16(f.x, f.y);
                #pragma unroll
                for (int li = 0; li < 11; ++li)          // hashed feats: store verbatim
                    row32[25 + li] = __builtin_nontemporal_load(feat + (size_t)li * N + gp);
            }
        }
        __syncthreads();

        f32x4 acc0[4][2];
        #pragma unroll
        for (int mt = 0; mt < 4; ++mt)
            #pragma unroll
            for (int nt = 0; nt < 2; ++nt) acc0[mt][nt] = (f32x4){0.f, 0.f, 0.f, 0.f};
        #pragma unroll
        for (int ks = 0; ks < 3; ++ks) {
            bf16x8 bfr[2];
            #pragma unroll
            for (int nt = 0; nt < 2; ++nt) {
                int n = nhalf * 32 + nt * 16 + lrow;
                bfr[nt] = *(const bf16x8*)&smem[SW0_OFF + n * 104 + ks * 32 + quad * 8];
            }
            #pragma unroll
            for (int mt = 0; mt < 4; ++mt) {
                int m = mhalf + mt * 16 + lrow;
                bf16x8 afr = *(const bf16x8*)&smem[m * SA_STRIDE + ks * 32 + quad * 8];
                #pragma unroll
                for (int nt = 0; nt < 2; ++nt)
                    acc0[mt][nt] = __builtin_amdgcn_mfma_f32_16x16x32_bf16(afr, bfr[nt], acc0[mt][nt], 0, 0, 0);
            }
        }
        __syncthreads();
        #pragma unroll
        for (int mt = 0; mt < 4; ++mt)
            #pragma unroll
            for (int r = 0; r < 4; ++r) {
                int rowm = mhalf + mt * 16 + quad * 4 + r;
                float v0 = softplus100(acc0[mt][0][r] + b0v[0]);
                float v1 = softplus100(acc0[mt][1][r] + b0v[1]);
                unsigned pk = pk_bf16(v0, v1);
                int c0 = nhalf * 32 + lrow;
                smem[rowm * SA_STRIDE + c0]      = (unsigned short)pk;
                smem[rowm * SA_STRIDE + c0 + 16] = (unsigned short)(pk >> 16);
            }
        __syncthreads();

        f32x4 acc1[4][2];
        #pragma unroll
        for (int mt = 0; mt < 4; ++mt)
            #pragma unroll
            for (int nt = 0; nt < 2; ++nt) acc1[mt][nt] = (f32x4){0.f, 0.f, 0.f, 0.f};
        #pragma unroll
        for (int ks = 0; ks < 2; ++ks) {
            #pragma unroll
            for (int mt = 0; mt < 4; ++mt) {
                int m = mhalf + mt * 16 + lrow;
                bf16x8 afr = *(const bf16x8*)&smem[m * SA_STRIDE + ks * 32 + quad * 8];
                #pragma unroll
                for (int nt = 0; nt < 2; ++nt)
                    acc1[mt][nt] = __builtin_amdgcn_mfma_f32_16x16x32_bf16(afr, w1f[ks][nt], acc1[mt][nt], 0, 0, 0);
            }
        }
        __syncthreads();
        #pragma unroll
        for (int mt = 0; mt < 4; ++mt)
            #pragma unroll
            for (int r = 0; r < 4; ++r) {
                int rowm = mhalf + mt * 16 + quad * 4 + r;
                float v0 = softplus100(acc1[mt][0][r] + b1v[0]);
                float v1 = softplus100(acc1[mt][1][r] + b1v[1]);
                unsigned pk = pk_bf16(v0, v1);
                int c0 = nhalf * 32 + lrow;
                smem[rowm * SA_STRIDE + c0]      = (unsigned short)pk;
                smem[rowm * SA_STRIDE + c0 + 16] = (unsigned short)(pk >> 16);
            }
        __syncthreads();

        f32x4 acc2[4];
        #pragma unroll
        for (int mt = 0; mt < 4; ++mt) acc2[mt] = (f32x4){0.f, 0.f, 0.f, 0.f};
        #pragma unroll
        for (int ks = 0; ks < 2; ++ks) {
            #pragma unroll
            for (int mt = 0; mt < 4; ++mt) {
                int m = mhalf + mt * 16 + lrow;
                bf16x8 afr = *(const bf16x8*)&smem[m * SA_STRIDE + ks * 32 + quad * 8];
                acc2[mt] = __builtin_amdgcn_mfma_f32_16x16x32_bf16(afr, w2f[ks], acc2[mt], 0, 0, 0);
            }
        }
        {
            int colg = nhalf * 16 + lrow;
            if (colg < 17) {
                #pragma unroll
                for (int mt = 0; mt < 4; ++mt)
                    #pragma unroll
                    for (int r = 0; r < 4; ++r) {
                        int rowm = mhalf + mt * 16 + quad * 4 + r;
                        __builtin_nontemporal_store(acc2[mt][r] + b2v,
                                                    out + (pb + rowm) * 17 + colg);
                    }
            }
        }
        __syncthreads();
    }
}

// ======================= Path B (verified round-3 kernels) =======================
#define SW0B_OFF   (128 * 104)
#define SMEMB_SHORTS (SW0B_OFF + 64 * 104)

__global__ __launch_bounds__(256, 6)
void gather_levels(const float* __restrict__ x, const float* __restrict__ tables,
                   unsigned* __restrict__ feat, int N, int C) {
    const int b = blockIdx.x;
    const int half = 8 * C;
    int r, level;
    if (b < half) { r = b; level = r & 7; }
    else          { r = b - half; level = 15 - (r & 7); }
    const size_t p0 = (size_t)(r >> 3) * 512 + 2u * threadIdx.x;
    const f32x2* xv = (const f32x2*)(x + 3 * p0);
    f32x2 u0 = __builtin_nontemporal_load(xv);
    f32x2 u1 = __builtin_nontemporal_load(xv + 1);
    f32x2 u2 = __builtin_nontemporal_load(xv + 2);
    float2 fA, fB;
    gather2(tables + (size_t)level * (2u * HMAP), c_res[level],
            u0[0], u0[1], u1[0],
            u1[1], u2[0], u2[1],
            fA, fB);
    u32x2 v;
    v[0] = (unsigned)f2bf(fA.x) | ((unsigned)f2bf(fA.y) << 16);
    v[1] = (unsigned)f2bf(fB.x) | ((unsigned)f2bf(fB.y) << 16);
    __builtin_nontemporal_store(v, (u32x2*)(feat + (size_t)level * N + p0));
}

__global__ __launch_bounds__(256, 4)
void mlp_tiled(const float* __restrict__ x, const unsigned* __restrict__ feat,
               const float* __restrict__ W0, const float* __restrict__ b0,
               const float* __restrict__ W1, const float* __restrict__ b1,
               const float* __restrict__ W2, const float* __restrict__ b2,
               float* __restrict__ out, int N) {
    __shared__ unsigned short smem[SMEMB_SHORTS];
    const int tid  = threadIdx.x;
    const int blk  = blockIdx.x;
    const int wave = tid >> 6, lane = tid & 63;
    const int mhalf = (wave & 1) * 64;
    const int nhalf = (wave >> 1);
    const int lrow = lane & 15, quad = lane >> 4;

    for (int i = tid; i < 64 * 104; i += 256) {
        int n = i / 104, k = i - n * 104;
        smem[SW0B_OFF + i] = (k < 71) ? f2bf(W0[n * 71 + k]) : (unsigned short)0;
    }
    for (int i = tid; i < 128 * 25; i += 256) {
        int p = i / 25, k = i - p * 25;
        smem[p * SA_STRIDE + 71 + k] = 0;
    }
    bf16x8 w1f[2][2];
    #pragma unroll
    for (int ks = 0; ks < 2; ++ks)
        #pragma unroll
        for (int nt = 0; nt < 2; ++nt) {
            int n = nhalf * 32 + nt * 16 + lrow;
            w1f[ks][nt] = cvt8(W1 + n * 64 + ks * 32 + quad * 8);
        }
    bf16x8 w2f[2];
    {
        int n2 = nhalf * 16 + lrow;
        #pragma unroll
        for (int ks = 0; ks < 2; ++ks) {
            if (n2 < 17) w2f[ks] = cvt8(W2 + n2 * 64 + ks * 32 + quad * 8);
            else { bf16x8 z = {0,0,0,0,0,0,0,0}; w2f[ks] = z; }
        }
    }
    float b0v[2], b1v[2], b2v;
    #pragma unroll
    for (int nt = 0; nt < 2; ++nt) {
        b0v[nt] = b0[nhalf * 32 + nt * 16 + lrow];
        b1v[nt] = b1[nhalf * 32 + nt * 16 + lrow];
    }
    { int c2 = nhalf * 16 + lrow; b2v = (c2 < 17) ? b2[c2] : 0.f; }
    __syncthreads();

    const size_t pbase0 = (size_t)blk * PTS_BLK;
    #pragma unroll 1
    for (int t = 0; t < TILES; ++t) {
        const size_t pb = pbase0 + (size_t)t * NPB;
        {
            const int p = tid & 127;
            const size_t gp = pb + p;
            unsigned short* row = &smem[p * SA_STRIDE];
            const float x0 = __builtin_nontemporal_load(x + 3 * gp);
            const float x1 = __builtin_nontemporal_load(x + 3 * gp + 1);
            const float x2 = __builtin_nontemporal_load(x + 3 * gp + 2);
            if (tid < 128) {
                row[0] = f2bf(x0); row[1] = f2bf(x1); row[2] = f2bf(x2);
                float fr = 1.f;
                #pragma unroll
                for (int m = 0; m < 6; ++m) {
                    row[3 + 6 * m + 0] = f2bf(__sinf(x0 * fr));
                    row[3 + 6 * m + 1] = f2bf(__sinf(x1 * fr));
                    row[3 + 6 * m + 2] = f2bf(__sinf(x2 * fr));
                    fr *= 2.f;
                }
            } else {
                float fr = 1.f;
                #pragma unroll
                for (int m = 0; m < 6; ++m) {
                    row[3 + 6 * m + 3] = f2bf(__cosf(x0 * fr));
                    row[3 + 6 * m + 4] = f2bf(__cosf(x1 * fr));
                    row[3 + 6 * m + 5] = f2bf(__cosf(x2 * fr));
                    fr *= 2.f;
                }
                #pragma unroll
                for (int l = 0; l < 16; ++l) {
                    unsigned v = __builtin_nontemporal_load(feat + (size_t)l * N + gp);
                    row[39 + 2 * l] = (unsigned short)(v & 0xffffu);
                    row[40 + 2 * l] = (unsigned short)(v >> 16);
                }
            }
        }
        __syncthreads();

        f32x4 acc0[4][2];
        #pragma unroll
        for (int mt = 0; mt < 4; ++mt)
            #pragma unroll
            for (int nt = 0; nt < 2; ++nt) acc0[mt][nt] = (f32x4){0.f, 0.f, 0.f, 0.f};
        #pragma unroll
        for (int ks = 0; ks < 3; ++ks) {
            bf16x8 bfr[2];
            #pragma unroll
            for (int nt = 0; nt < 2; ++nt) {
                int n = nhalf * 32 + nt * 16 + lrow;
                bfr[nt] = *(const bf16x8*)&smem[SW0B_OFF + n * 104 + ks * 32 + quad * 8];
            }
            #pragma unroll
            for (int mt = 0; mt < 4; ++mt) {
                int m = mhalf + mt * 16 + lrow;
                bf16x8 afr = *(const bf16x8*)&smem[m * SA_STRIDE + ks * 32 + quad * 8];
                #pragma unroll
                for (int nt = 0; nt < 2; ++nt)
                    acc0[mt][nt] = __builtin_amdgcn_mfma_f32_16x16x32_bf16(afr, bfr[nt], acc0[mt][nt], 0, 0, 0);
            }
        }
        __syncthreads();
        #pragma unroll
        for (int mt = 0; mt < 4; ++mt)
            #pragma unroll
            for (int nt = 0; nt < 2; ++nt) {
                int colg = nhalf * 32 + nt * 16 + lrow;
                #pragma unroll
                for (int r = 0; r < 4; ++r) {
                    int rowm = mhalf + mt * 16 + quad * 4 + r;
                    smem[rowm * SA_STRIDE + colg] = f2bf(softplus100(acc0[mt][nt][r] + b0v[nt]));
                }
            }
        __syncthreads();

        f32x4 acc1[4][2];
        #pragma unroll
        for (int mt = 0; mt < 4; ++mt)
            #pragma unroll
            for (int nt = 0; nt < 2; ++nt) acc1[mt][nt] = (f32x4){0.f, 0.f, 0.f, 0.f};
        #pragma unroll
        for (int ks = 0; ks < 2; ++ks) {
            #pragma unroll
            for (int mt = 0; mt < 4; ++mt) {
                int m = mhalf + mt * 16 + lrow;
                bf16x8 afr = *(const bf16x8*)&smem[m * SA_STRIDE + ks * 32 + quad * 8];
                #pragma unroll
                for (int nt = 0; nt < 2; ++nt)
                    acc1[mt][nt] = __builtin_amdgcn_mfma_f32_16x16x32_bf16(afr, w1f[ks][nt], acc1[mt][nt], 0, 0, 0);
            }
        }
        __syncthreads();
        #pragma unroll
        for (int mt = 0; mt < 4; ++mt)
            #pragma unroll
            for (int nt = 0; nt < 2; ++nt) {
                int colg = nhalf * 32 + nt * 16 + lrow;
                #pragma unroll
                for (int r = 0; r < 4; ++r) {
                    int rowm = mhalf + mt * 16 + quad * 4 + r;
                    smem[rowm * SA_STRIDE + colg] = f2bf(softplus100(acc1[mt][nt][r] + b1v[nt]));
                }
            }
        __syncthreads();

        f32x4 acc2[4];
        #pragma unroll
        for (int mt = 0; mt < 4; ++mt) acc2[mt] = (f32x4){0.f, 0.f, 0.f, 0.f};
        #pragma unroll
        for (int ks = 0; ks < 2; ++ks) {
            #pragma unroll
            for (int mt = 0; mt < 4; ++mt) {
                int m = mhalf + mt * 16 + lrow;
                bf16x8 afr = *(const bf16x8*)&smem[m * SA_STRIDE + ks * 32 + quad * 8];
                acc2[mt] = __builtin_amdgcn_mfma_f32_16x16x32_bf16(afr, w2f[ks], acc2[mt], 0, 0, 0);
            }
        }
        {
            int colg = nhalf * 16 + lrow;
            if (colg < 17) {
                #pragma unroll
                for (int mt = 0; mt < 4; ++mt)
                    #pragma unroll
                    for (int r = 0; r < 4; ++r) {
                        int rowm = mhalf + mt * 16 + quad * 4 + r;
                        __builtin_nontemporal_store(acc2[mt][r] + b2v,
                                                    out + (pb + rowm) * 17 + colg);
                    }
            }
        }
        __syncthreads();
    }
}

// ======================= Fallback (ws too small): fully fused =======================
__global__ __launch_bounds__(256, 3)
void gn_fused(const float* __restrict__ x, const float* __restrict__ tables,
              const float* __restrict__ W0, const float* __restrict__ b0,
              const float* __restrict__ W1, const float* __restrict__ b1,
              const float* __restrict__ W2, const float* __restrict__ b2,
              float* __restrict__ out) {
    __shared__ unsigned short smem[SMEMB_SHORTS];
    const int tid = threadIdx.x;
    const int blk = blockIdx.x;
    const int wave = tid >> 6, lane = tid & 63;
    const int mhalf = (wave & 1) * 64;
    const int nhalf = (wave >> 1);
    const int lrow = lane & 15, quad = lane >> 4;
    for (int i = tid; i < 64 * 104; i += 256) {
        int n = i / 104, k = i - n * 104;
        smem[SW0B_OFF + i] = (k < 71) ? f2bf(W0[n * 71 + k]) : (unsigned short)0;
    }
    for (int i = tid; i < 128 * 25; i += 256) {
        int p = i / 25, k = i - p * 25;
        smem[p * SA_STRIDE + 71 + k] = 0;
    }
    bf16x8 w1f[2][2];
    #pragma unroll
    for (int ks = 0; ks < 2; ++ks)
        #pragma unroll
        for (int nt = 0; nt < 2; ++nt) {
            int n = nhalf * 32 + nt * 16 + lrow;
            w1f[ks][nt] = cvt8(W1 + n * 64 + ks * 32 + quad * 8);
        }
    bf16x8 w2f[2];
    {
        int n2 = nhalf * 16 + lrow;
        #pragma unroll
        for (int ks = 0; ks < 2; ++ks) {
            if (n2 < 17) w2f[ks] = cvt8(W2 + n2 * 64 + ks * 32 + quad * 8);
            else { bf16x8 z = {0,0,0,0,0,0,0,0}; w2f[ks] = z; }
        }
    }
    float b0v[2], b1v[2], b2v;
    #pragma unroll
    for (int nt = 0; nt < 2; ++nt) {
        b0v[nt] = b0[nhalf * 32 + nt * 16 + lrow];
        b1v[nt] = b1[nhalf * 32 + nt * 16 + lrow];
    }
    { int c2 = nhalf * 16 + lrow; b2v = (c2 < 17) ? b2[c2] : 0.f; }
    {
        const int p = tid & 127;
        const size_t gp = (size_t)blk * NPB + p;
        const float x0 = x[3 * gp], x1 = x[3 * gp + 1], x2 = x[3 * gp + 2];
        unsigned short* row = &smem[p * SA_STRIDE];
        if (tid < 128) {
            row[0] = f2bf(x0); row[1] = f2bf(x1); row[2] = f2bf(x2);
            float fr = 1.f;
            #pragma unroll
            for (int m = 0; m < 6; ++m) {
                row[3 + 6 * m + 0] = f2bf(__sinf(x0 * fr));
                row[3 + 6 * m + 1] = f2bf(__sinf(x1 * fr));
                row[3 + 6 * m + 2] = f2bf(__sinf(x2 * fr));
                fr *= 2.f;
            }
            #pragma unroll
            for (int li = 0; li < 8; ++li) {
                const int l = 2 * li;
                float2 f = gather_level(tables + (size_t)l * (2u * HMAP), c_res[l], x0, x1, x2);
                row[39 + 2 * l] = f2bf(f.x);
                row[40 + 2 * l] = f2bf(f.y);
            }
        } else {
            float fr = 1.f;
            #pragma unroll
            for (int m = 0; m < 6; ++m) {
                row[3 + 6 * m + 3] = f2bf(__cosf(x0 * fr));
                row[3 + 6 * m + 4] = f2bf(__cosf(x1 * fr));
                row[3 + 6 * m + 5] = f2bf(__cosf(x2 * fr));
                fr *= 2.f;
            }
            #pragma unroll
            for (int li = 0; li < 8; ++li) {
                const int l = 2 * li + 1;
                float2 f = gather_level(tables + (size_t)l * (2u * HMAP), c_res[l], x0, x1, x2);
                row[39 + 2 * l] = f2bf(f.x);
                row[40 + 2 * l] = f2bf(f.y);
            }
        }
    }
    __syncthreads();
    f32x4 acc0[4][2];
    #pragma unroll
    for (int mt = 0; mt < 4; ++mt)
        #pragma unroll
        for (int nt = 0; nt < 2; ++nt) acc0[mt][nt] = (f32x4){0.f, 0.f, 0.f, 0.f};
    #pragma unroll
    for (int ks = 0; ks < 3; ++ks) {
        bf16x8 bfr[2];
        #pragma unroll
        for (int nt = 0; nt < 2; ++nt) {
            int n = nhalf * 32 + nt * 16 + lrow;
            bfr[nt] = *(const bf16x8*)&smem[SW0B_OFF + n * 104 + ks * 32 + quad * 8];
        }
        #pragma unroll
        for (int mt = 0; mt < 4; ++mt) {
            int m = mhalf + mt * 16 + lrow;
            bf16x8 afr = *(const bf16x8*)&smem[m * SA_STRIDE + ks * 32 + quad * 8];
            #pragma unroll
            for (int nt = 0; nt < 2; ++nt)
                acc0[mt][nt] = __builtin_amdgcn_mfma_f32_16x16x32_bf16(afr, bfr[nt], acc0[mt][nt], 0, 0, 0);
        }
    }
    __syncthreads();
    #pragma unroll
    for (int mt = 0; mt < 4; ++mt)
        #pragma unroll
        for (int nt = 0; nt < 2; ++nt) {
            int colg = nhalf * 32 + nt * 16 + lrow;
            #pragma unroll
            for (int r = 0; r < 4; ++r) {
                int rowm = mhalf + mt * 16 + quad * 4 + r;
                smem[rowm * SA_STRIDE + colg] = f2bf(softplus100(acc0[mt][nt][r] + b0v[nt]));
            }
        }
    __syncthreads();
    f32x4 acc1[4][2];
    #pragma unroll
    for (int mt = 0; mt < 4; ++mt)
        #pragma unroll
        for (int nt = 0; nt < 2; ++nt) acc1[mt][nt] = (f32x4){0.f, 0.f, 0.f, 0.f};
    #pragma unroll
    for (int ks = 0; ks < 2; ++ks) {
        #pragma unroll
        for (int mt = 0; mt < 4; ++mt) {
            int m = mhalf + mt * 16 + lrow;
            bf16x8 afr = *(const bf16x8*)&smem[m * SA_STRIDE + ks * 32 + quad * 8];
            #pragma unroll
            for (int nt = 0; nt < 2; ++nt)
                acc1[mt][nt] = __builtin_amdgcn_mfma_f32_16x16x32_bf16(afr, w1f[ks][nt], acc1[mt][nt], 0, 0, 0);
        }
    }
    __syncthreads();
    #pragma unroll
    for (int mt = 0; mt < 4; ++mt)
        #pragma unroll
        for (int nt = 0; nt < 2; ++nt) {
            int colg = nhalf * 32 + nt * 16 + lrow;
            #pragma unroll
            for (int r = 0; r < 4; ++r) {
                int rowm = mhalf + mt * 16 + quad * 4 + r;
                smem[rowm * SA_STRIDE + colg] = f2bf(softplus100(acc1[mt][nt][r] + b1v[nt]));
            }
        }
    __syncthreads();
    f32x4 acc2[4];
    #pragma unroll
    for (int mt = 0; mt < 4; ++mt) acc2[mt] = (f32x4){0.f, 0.f, 0.f, 0.f};
    #pragma unroll
    for (int ks = 0; ks < 2; ++ks) {
        #pragma unroll
        for (int mt = 0; mt < 4; ++mt) {
            int m = mhalf + mt * 16 + lrow;
            bf16x8 afr = *(const bf16x8*)&smem[m * SA_STRIDE + ks * 32 + quad * 8];
            acc2[mt] = __builtin_amdgcn_mfma_f32_16x16x32_bf16(afr, w2f[ks], acc2[mt], 0, 0, 0);
        }
    }
    {
        int colg = nhalf * 16 + lrow;
        if (colg < 17) {
            #pragma unroll
            for (int mt = 0; mt < 4; ++mt)
                #pragma unroll
                for (int r = 0; r < 4; ++r) {
                    int rowm = mhalf + mt * 16 + quad * 4 + r;
                    out[((size_t)blk * NPB + rowm) * 17 + colg] = acc2[mt][r] + b2v;
                }
        }
    }
}

extern "C" void kernel_launch(void* const* d_in, const int* in_sizes, int n_in,
                              void* d_out, int out_size, void* d_ws, size_t ws_size,
                              hipStream_t stream) {
    const float* x      = (const float*)d_in[0];
    const float* tables = (const float*)d_in[1];
    const float* W0     = (const float*)d_in[2];
    const float* b0     = (const float*)d_in[3];
    const float* W1     = (const float*)d_in[4];
    const float* b1     = (const float*)d_in[5];
    const float* W2     = (const float*)d_in[6];
    const float* b2     = (const float*)d_in[7];
    float* out = (float*)d_out;
    const int n = in_sizes[0] / 3;                           // 1048576
    const size_t featA_b = (size_t)11 * n * 4;               // 44 MB hashed feat staging
    const size_t tbf_b   = (size_t)11 * HMAP * 4;            // 22 MB bf16 hashed tables
    const size_t wsB     = (size_t)16 * n * 4;               // 64 MB (path B)
    if (n == (1 << 20) && ws_size >= featA_b + tbf_b) {
        unsigned* feat = (unsigned*)d_ws;
        unsigned* tbf  = (unsigned*)((char*)d_ws + featA_b);
        cvt_tables<<<dim3(11 * HMAP / 256), dim3(256), 0, stream>>>(tables, tbf);
        gather_hashed<<<dim3(8 * 3072), dim3(256), 0, stream>>>(x, tbf, feat, n);
        mlp_tiled2<<<dim3(n / PTS_BLK), dim3(256), 0, stream>>>(x, tables, feat, W0, b0, W1, b1, W2, b2, out, n);
    } else if (ws_size >= wsB) {
        unsigned* feat = (unsigned*)d_ws;
        const int C = n / 512;
        gather_levels<<<dim3(16 * C), dim3(256), 0, stream>>>(x, tables, feat, n, C);
        mlp_tiled<<<dim3(n / PTS_BLK), dim3(256), 0, stream>>>(x, feat, W0, b0, W1, b1, W2, b2, out, n);
    } else {
        gn_fused<<<dim3(n / NPB), dim3(256), 0, stream>>>(x, tables, W0, b0, W1, b1, W2, b2, out);
    }
}